// Round 1
// baseline (652.823 us; speedup 1.0000x reference)
//
#include <hip/hip_runtime.h>
#include <hip/hip_bf16.h>
#include <math.h>

#define L_SEQ 4096
#define CDIM 96
#define DIN 192
#define NST 16
#define XPW 416
#define NCHUNK 32
#define CHLEN 128
#define MROWS 8192

__device__ __forceinline__ float gelu_exact(float x) {
    return 0.5f * x * (1.0f + erff(x * 0.70710678118654752f));
}

// ---------------- LayerNorm over last dim 96, one wave per row ----------------
__global__ __launch_bounds__(256) void ln96_kernel(const float* __restrict__ in,
                                                   const float* __restrict__ g,
                                                   const float* __restrict__ b,
                                                   float* __restrict__ out, int rows) {
    int wave = threadIdx.x >> 6;
    int lane = threadIdx.x & 63;
    int row = blockIdx.x * 4 + wave;
    if (row >= rows) return;
    const float* p = in + (size_t)row * CDIM;
    float x0 = p[lane];
    float x1 = (lane < 32) ? p[64 + lane] : 0.f;
    float s = x0 + x1, sq = x0 * x0 + x1 * x1;
#pragma unroll
    for (int o = 32; o >= 1; o >>= 1) { s += __shfl_xor(s, o); sq += __shfl_xor(sq, o); }
    float mean = s * (1.f / 96.f);
    float var = sq * (1.f / 96.f) - mean * mean;
    float w = rsqrtf(var + 1e-5f);
    float* q = out + (size_t)row * CDIM;
    q[lane] = (x0 - mean) * w * g[lane] + b[lane];
    if (lane < 32) q[64 + lane] = (x1 - mean) * w * g[64 + lane] + b[64 + lane];
}

// ---------------- generic tiled f32 GEMM: C[M,N] = A[M,K] @ B[K,N] ----------------
// EPI: 0 = none, 1 = +bias then gelu, 2 = +bias +res
#define BMT 64
#define BNT 64
#define BKT 16
template <int EPI>
__global__ __launch_bounds__(256) void gemm_f32(const float* __restrict__ A, int lda,
                                                const float* __restrict__ B, int ldb,
                                                float* __restrict__ C, int ldc,
                                                int M, int N, int K,
                                                const float* __restrict__ bias,
                                                const float* __restrict__ res) {
    __shared__ float As[BKT][BMT + 4];
    __shared__ float Bs[BKT][BNT + 4];
    int tx = threadIdx.x & 15, ty = threadIdx.x >> 4;
    int m0 = blockIdx.y * BMT, n0 = blockIdx.x * BNT;
    float acc[4][4] = {};
    for (int k0 = 0; k0 < K; k0 += BKT) {
        {
            int k = threadIdx.x & 15;
            int mBase = threadIdx.x >> 4;
#pragma unroll
            for (int i = 0; i < 4; ++i) {
                int m = mBase + i * 16;
                As[k][m] = A[(size_t)(m0 + m) * lda + k0 + k];
            }
        }
        {
            int n = threadIdx.x & 63;
            int kBase = threadIdx.x >> 6;
            int col = n0 + n;
#pragma unroll
            for (int i = 0; i < 4; ++i) {
                int k = kBase + i * 4;
                Bs[k][n] = (col < N) ? B[(size_t)(k0 + k) * ldb + col] : 0.f;
            }
        }
        __syncthreads();
#pragma unroll
        for (int kk = 0; kk < BKT; ++kk) {
            float4 a4 = *reinterpret_cast<const float4*>(&As[kk][ty * 4]);
            float4 b4 = *reinterpret_cast<const float4*>(&Bs[kk][tx * 4]);
            float av[4] = {a4.x, a4.y, a4.z, a4.w};
            float bv[4] = {b4.x, b4.y, b4.z, b4.w};
#pragma unroll
            for (int i = 0; i < 4; ++i)
#pragma unroll
                for (int j = 0; j < 4; ++j) acc[i][j] += av[i] * bv[j];
        }
        __syncthreads();
    }
#pragma unroll
    for (int i = 0; i < 4; ++i) {
        int row = m0 + ty * 4 + i;
#pragma unroll
        for (int j = 0; j < 4; ++j) {
            int col = n0 + tx * 4 + j;
            if (col < N) {
                float v = acc[i][j];
                if (EPI == 1) v = gelu_exact(v + bias[col]);
                else if (EPI == 2) v = v + bias[col] + res[(size_t)row * ldc + col];
                C[(size_t)row * ldc + col] = v;
            }
        }
    }
}

// ---------------- 3x3 SAME conv as implicit GEMM (K = 3*3*192 = 1728) ----------------
__global__ __launch_bounds__(256) void conv3x3_gemm(const float* __restrict__ cat,
                                                    const float* __restrict__ Wf,
                                                    const float* __restrict__ bfv,
                                                    float* __restrict__ out) {
    __shared__ float As[BKT][BMT + 4];
    __shared__ float Bs[BKT][BNT + 4];
    int tx = threadIdx.x & 15, ty = threadIdx.x >> 4;
    int m0 = blockIdx.y * BMT, n0 = blockIdx.x * BNT;
    const int N = 96, K = 1728;
    float acc[4][4] = {};
    for (int k0 = 0; k0 < K; k0 += BKT) {
        {
            int k = k0 + (threadIdx.x & 15);
            int ky = k / 576;
            int r = k - ky * 576;
            int kx = r / 192;
            int ic = r - kx * 192;
            int mBase = threadIdx.x >> 4;
#pragma unroll
            for (int i = 0; i < 4; ++i) {
                int m = m0 + mBase + i * 16;
                int bb = m >> 12;
                int l = m & 4095;
                int yy = l >> 6;
                int xx = l & 63;
                int iy = yy + ky - 1, ix = xx + kx - 1;
                float v = 0.f;
                if ((unsigned)iy < 64u && (unsigned)ix < 64u)
                    v = cat[(((size_t)bb * 4096 + (size_t)iy * 64 + ix)) * 192 + ic];
                As[k - k0][mBase + i * 16] = v;
            }
        }
        {
            int n = threadIdx.x & 63;
            int kBase = threadIdx.x >> 6;
            int col = n0 + n;
#pragma unroll
            for (int i = 0; i < 4; ++i) {
                int k = kBase + i * 4;
                Bs[k][n] = (col < N) ? Wf[(size_t)(k0 + k) * 96 + col] : 0.f;
            }
        }
        __syncthreads();
#pragma unroll
        for (int kk = 0; kk < BKT; ++kk) {
            float4 a4 = *reinterpret_cast<const float4*>(&As[kk][ty * 4]);
            float4 b4 = *reinterpret_cast<const float4*>(&Bs[kk][tx * 4]);
            float av[4] = {a4.x, a4.y, a4.z, a4.w};
            float bv[4] = {b4.x, b4.y, b4.z, b4.w};
#pragma unroll
            for (int i = 0; i < 4; ++i)
#pragma unroll
                for (int j = 0; j < 4; ++j) acc[i][j] += av[i] * bv[j];
        }
        __syncthreads();
    }
#pragma unroll
    for (int i = 0; i < 4; ++i) {
        int row = m0 + ty * 4 + i;
#pragma unroll
        for (int j = 0; j < 4; ++j) {
            int col = n0 + tx * 4 + j;
            if (col < 96) {
                float v = gelu_exact(acc[i][j] + bfv[col]);
                out[(size_t)row * 96 + col] = v;
            }
        }
    }
}

// ---------------- depthwise causal conv (k=4) + sigmoid(delta) ----------------
__global__ __launch_bounds__(256) void convsig_kernel(const float* __restrict__ xp,
                                                      const float* __restrict__ cw,
                                                      const float* __restrict__ cb,
                                                      float* __restrict__ xc,
                                                      float* __restrict__ dsg) {
    int idx = blockIdx.x * blockDim.x + threadIdx.x;
    if (idx >= MROWS * DIN) return;
    int d = idx % DIN;
    int row = idx / DIN;
    int l = row & (L_SEQ - 1);
    float w0 = cw[d * 4 + 0], w1 = cw[d * 4 + 1], w2 = cw[d * 4 + 2], w3 = cw[d * 4 + 3];
    float acc = cb[d];
    acc += w3 * xp[(size_t)row * XPW + d];
    if (l >= 1) acc += w2 * xp[(size_t)(row - 1) * XPW + d];
    if (l >= 2) acc += w1 * xp[(size_t)(row - 2) * XPW + d];
    if (l >= 3) acc += w0 * xp[(size_t)(row - 3) * XPW + d];
    xc[(size_t)row * DIN + d] = acc;
    float dp = xp[(size_t)row * XPW + 192 + d];
    dsg[(size_t)row * DIN + d] = 1.f / (1.f + __expf(-dp));
}

// ---------------- scan pass1: per-chunk product P, fwd-local final Hf, bwd-local start Gb ----
__global__ __launch_bounds__(192) void scan_pass1(const float* __restrict__ dsg,
                                                  const float* __restrict__ xc,
                                                  const float* __restrict__ xp,
                                                  const float* __restrict__ A,
                                                  float* __restrict__ Pc,
                                                  float* __restrict__ Hf,
                                                  float* __restrict__ Gb) {
    int gid = blockIdx.x; // b*512 + c*16 + n
    int n = gid & 15;
    int c = (gid >> 4) & 31;
    int b = gid >> 9;
    int d = threadIdx.x;
    float asum = 0.f;
#pragma unroll
    for (int j = 0; j < 16; ++j) asum += A[n * 16 + j];
    float h = 0.f, gb = 0.f, Q = 1.f;
    int t0 = c * CHLEN;
    for (int tl = 0; tl < CHLEN; ++tl) {
        size_t row = (size_t)b * L_SEQ + t0 + tl;
        float dl = dsg[row * DIN + d];
        float xv = xc[row * DIN + d];
        float bm = xp[row * XPW + 384 + n];
        float a = __expf(dl * asum);
        float bu = dl * xv * bm;
        h = a * h + bu;
        gb += Q * bu;
        Q *= a;
    }
    size_t cidx = (((size_t)b * NCHUNK + c) * NST + n) * DIN + d;
    Pc[cidx] = Q;
    Hf[cidx] = h;
    Gb[cidx] = gb;
}

// ---------------- scan pass2: combine chunk carries sequentially ----------------
__global__ __launch_bounds__(256) void scan_pass2(const float* __restrict__ Pc,
                                                  const float* __restrict__ Hf,
                                                  const float* __restrict__ Gb,
                                                  float* __restrict__ Hinf,
                                                  float* __restrict__ Hinb) {
    int t = blockIdx.x * blockDim.x + threadIdx.x;
    if (t >= 2 * NST * DIN) return;
    int d = t % DIN;
    int n = (t / DIN) % NST;
    int b = t / (DIN * NST);
    float hin = 0.f;
    for (int c = 0; c < NCHUNK; ++c) {
        size_t idx = (((size_t)b * NCHUNK + c) * NST + n) * DIN + d;
        Hinf[idx] = hin;
        hin = Hf[idx] + Pc[idx] * hin;
    }
    float gin = 0.f;
    for (int c = NCHUNK - 1; c >= 0; --c) {
        size_t idx = (((size_t)b * NCHUNK + c) * NST + n) * DIN + d;
        Hinb[idx] = gin;
        gin = Gb[idx] + Pc[idx] * gin;
    }
}

// ---------------- scan pass3: re-scan with carries, fuse y = sum_n Cm*h + Dp*xc ----------------
__global__ __launch_bounds__(256) void scan_pass3(const float* __restrict__ dsg,
                                                  const float* __restrict__ xc,
                                                  const float* __restrict__ xp,
                                                  const float* __restrict__ A,
                                                  const float* __restrict__ Hinf,
                                                  const float* __restrict__ Hinb,
                                                  const float* __restrict__ Dp,
                                                  float* __restrict__ y) {
    __shared__ float ys[CHLEN * 16];
    int bid = blockIdx.x; // (b * 32 + c) * 12 + dg
    int dg = bid % 12;
    int c = (bid / 12) % NCHUNK;
    int b = bid / (12 * NCHUNK);
    int lane = threadIdx.x & 63;
    int wave = threadIdx.x >> 6;
    int n = lane & 15;
    int dsub = lane >> 4;
    int dloc = wave * 4 + dsub;
    int d = dg * 16 + dloc;
    float asum = 0.f;
#pragma unroll
    for (int j = 0; j < 16; ++j) asum += A[n * 16 + j];
    size_t cidx = (((size_t)b * NCHUNK + c) * NST + n) * DIN + d;
    int t0 = c * CHLEN;
    // forward
    float h = Hinf[cidx];
    for (int tl = 0; tl < CHLEN; ++tl) {
        size_t row = (size_t)b * L_SEQ + t0 + tl;
        float dl = dsg[row * DIN + d];
        float xv = xc[row * DIN + d];
        float bm = xp[row * XPW + 384 + n];
        float cm = xp[row * XPW + 400 + n];
        float a = __expf(dl * asum);
        float bu = dl * xv * bm;
        h = a * h + bu;
        float p = cm * h;
        p += __shfl_xor(p, 1);
        p += __shfl_xor(p, 2);
        p += __shfl_xor(p, 4);
        p += __shfl_xor(p, 8);
        if (n == 0) ys[tl * 16 + dloc] = p;
    }
    // backward
    float gv = Hinb[cidx];
    for (int tl = CHLEN - 1; tl >= 0; --tl) {
        size_t row = (size_t)b * L_SEQ + t0 + tl;
        float dl = dsg[row * DIN + d];
        float xv = xc[row * DIN + d];
        float bm = xp[row * XPW + 384 + n];
        float cm = xp[row * XPW + 400 + n];
        float a = __expf(dl * asum);
        float bu = dl * xv * bm;
        gv = a * gv + bu;
        float p = cm * gv;
        p += __shfl_xor(p, 1);
        p += __shfl_xor(p, 2);
        p += __shfl_xor(p, 4);
        p += __shfl_xor(p, 8);
        if (n == 0) ys[tl * 16 + dloc] += p;
    }
    __syncthreads();
#pragma unroll
    for (int i = 0; i < 8; ++i) {
        int sidx = threadIdx.x + i * 256;
        int tl = sidx >> 4;
        int dl2 = sidx & 15;
        int d2 = dg * 16 + dl2;
        size_t row = (size_t)b * L_SEQ + t0 + tl;
        y[row * DIN + d2] = ys[sidx] + Dp[d2] * xc[row * DIN + d2];
    }
}

// ---------------- cosine-sim fusion: cat = [f1, sim*f1 + (1-sim)*f2] ----------------
__global__ __launch_bounds__(256) void fuse_kernel(const float* __restrict__ f1,
                                                   const float* __restrict__ f2,
                                                   float* __restrict__ cat, int rows) {
    int wave = threadIdx.x >> 6;
    int lane = threadIdx.x & 63;
    int row = blockIdx.x * 4 + wave;
    if (row >= rows) return;
    const float* p1 = f1 + (size_t)row * CDIM;
    const float* p2 = f2 + (size_t)row * CDIM;
    float a0 = p1[lane], b0 = p2[lane];
    float a1 = 0.f, b1 = 0.f;
    if (lane < 32) { a1 = p1[64 + lane]; b1 = p2[64 + lane]; }
    float s11 = a0 * a0 + a1 * a1;
    float s22 = b0 * b0 + b1 * b1;
    float s12 = a0 * b0 + a1 * b1;
#pragma unroll
    for (int o = 32; o >= 1; o >>= 1) {
        s11 += __shfl_xor(s11, o);
        s22 += __shfl_xor(s22, o);
        s12 += __shfl_xor(s12, o);
    }
    float nr1 = fmaxf(sqrtf(s11), 1e-12f);
    float nr2 = fmaxf(sqrtf(s22), 1e-12f);
    float sim = s12 / (nr1 * nr2);
    float* q = cat + (size_t)row * 192;
    q[lane] = a0;
    q[96 + lane] = sim * a0 + (1.f - sim) * b0;
    if (lane < 32) {
        q[64 + lane] = a1;
        q[96 + 64 + lane] = sim * a1 + (1.f - sim) * b1;
    }
}

extern "C" void kernel_launch(void* const* d_in, const int* in_sizes, int n_in,
                              void* d_out, int out_size, void* d_ws, size_t ws_size,
                              hipStream_t stream) {
    const float* x = (const float*)d_in[0];
    const float* norm_g = (const float*)d_in[1];
    const float* norm_b = (const float*)d_in[2];
    const float* Wp[2] = {(const float*)d_in[3], (const float*)d_in[11]};
    const float* cw[2] = {(const float*)d_in[4], (const float*)d_in[12]};
    const float* cb[2] = {(const float*)d_in[5], (const float*)d_in[13]};
    const float* Ab[2] = {(const float*)d_in[6], (const float*)d_in[14]};
    const float* Dpb[2] = {(const float*)d_in[7], (const float*)d_in[15]};
    const float* Wo[2] = {(const float*)d_in[8], (const float*)d_in[16]};
    const float* lng[2] = {(const float*)d_in[9], (const float*)d_in[17]};
    const float* lnb[2] = {(const float*)d_in[10], (const float*)d_in[18]};
    const float* Wf = (const float*)d_in[19];
    const float* bfv = (const float*)d_in[20];
    const float* W1 = (const float*)d_in[21];
    const float* b1 = (const float*)d_in[22];
    const float* W2 = (const float*)d_in[23];
    const float* b2 = (const float*)d_in[24];
    float* out = (float*)d_out;

    float* ws = (float*)d_ws;
    size_t off = 0;
    auto alloc = [&](size_t nelem) { float* p = ws + off; off += nelem; return p; };
    float* xn = alloc((size_t)MROWS * 96);
    float* xp = alloc((size_t)MROWS * XPW);
    float* xcb = alloc((size_t)MROWS * DIN);
    float* dsg = alloc((size_t)MROWS * DIN);
    float* yb = alloc((size_t)MROWS * DIN);
    float* tmp96 = alloc((size_t)MROWS * 96);
    float* f1 = alloc((size_t)MROWS * 96);
    float* f2 = alloc((size_t)MROWS * 96);
    float* cat = alloc((size_t)MROWS * DIN);
    float* h1 = alloc((size_t)MROWS * 384);
    const size_t csz = (size_t)2 * NCHUNK * NST * DIN;
    float* Pc = alloc(csz);
    float* Hfc = alloc(csz);
    float* Gbc = alloc(csz);
    float* Hinf = alloc(csz);
    float* Hinb = alloc(csz);
    (void)ws_size;
    (void)in_sizes;
    (void)n_in;
    (void)out_size;

    // 1. input LayerNorm
    ln96_kernel<<<dim3(2048), dim3(256), 0, stream>>>(x, norm_g, norm_b, xn, MROWS);

    float* fouts[2] = {f1, f2};
    for (int p = 0; p < 2; ++p) {
        // xp = xn @ Wp (first 416 cols only)
        gemm_f32<0><<<dim3(7, 128), dim3(256), 0, stream>>>(xn, 96, Wp[p], 576, xp, XPW,
                                                            MROWS, XPW, 96, nullptr, nullptr);
        convsig_kernel<<<dim3(6144), dim3(256), 0, stream>>>(xp, cw[p], cb[p], xcb, dsg);
        scan_pass1<<<dim3(1024), dim3(192), 0, stream>>>(dsg, xcb, xp, Ab[p], Pc, Hfc, Gbc);
        scan_pass2<<<dim3(24), dim3(256), 0, stream>>>(Pc, Hfc, Gbc, Hinf, Hinb);
        scan_pass3<<<dim3(768), dim3(256), 0, stream>>>(dsg, xcb, xp, Ab[p], Hinf, Hinb,
                                                        Dpb[p], yb);
        // f_pre = y @ Wo ; f = LN(f_pre)
        gemm_f32<0><<<dim3(2, 128), dim3(256), 0, stream>>>(yb, DIN, Wo[p], 96, tmp96, 96,
                                                            MROWS, 96, DIN, nullptr, nullptr);
        ln96_kernel<<<dim3(2048), dim3(256), 0, stream>>>(tmp96, lng[p], lnb[p], fouts[p], MROWS);
    }

    fuse_kernel<<<dim3(2048), dim3(256), 0, stream>>>(f1, f2, cat, MROWS);
    // fc = gelu(conv3x3(cat) + bf)  -> tmp96
    conv3x3_gemm<<<dim3(2, 128), dim3(256), 0, stream>>>(cat, Wf, bfv, tmp96);
    // h1 = gelu(fc @ W1 + b1)
    gemm_f32<1><<<dim3(6, 128), dim3(256), 0, stream>>>(tmp96, 96, W1, 384, h1, 384,
                                                        MROWS, 384, 96, b1, nullptr);
    // out = h1 @ W2 + b2 + res
    gemm_f32<2><<<dim3(2, 128), dim3(256), 0, stream>>>(h1, 384, W2, 96, out, 96,
                                                        MROWS, 96, 384, b2, x);
}

// Round 2
// 502.700 us; speedup vs baseline: 1.2986x; 1.2986x over previous
//
#include <hip/hip_runtime.h>
#include <hip/hip_bf16.h>
#include <math.h>

#define L_SEQ 4096
#define CDIM 96
#define DIN 192
#define NST 16
#define XPW 416
#define NCHUNK 32
#define CHLEN 128
#define MROWS 8192

typedef __attribute__((ext_vector_type(8))) short bf16x8;
typedef __attribute__((ext_vector_type(4))) float f32x4;

__device__ __forceinline__ float gelu_exact(float x) {
    return 0.5f * x * (1.0f + erff(x * 0.70710678118654752f));
}

__device__ __forceinline__ float bf2f(__hip_bfloat16 v) { return __bfloat162float(v); }

// ---------------- f32 -> bf16 conversions ----------------
__global__ __launch_bounds__(256) void cvt_f32_bf16(const float* __restrict__ in,
                                                    __hip_bfloat16* __restrict__ out, int n) {
    int i = blockIdx.x * 256 + threadIdx.x;
    if (i < n) out[i] = __float2bfloat16(in[i]);
}

// Wp: [96][576] f32 -> [96][416] bf16 (only first 416 cols used)
__global__ __launch_bounds__(256) void cvt_wp(const float* __restrict__ in,
                                              __hip_bfloat16* __restrict__ out) {
    int i = blockIdx.x * 256 + threadIdx.x;
    if (i >= 96 * XPW) return;
    int r = i / XPW, c = i - r * XPW;
    out[i] = __float2bfloat16(in[r * 576 + c]);
}

// ---------------- LayerNorm over last dim 96, one wave per row ----------------
template <typename OT>
__global__ __launch_bounds__(256) void ln96_kernel(const float* __restrict__ in,
                                                   const float* __restrict__ g,
                                                   const float* __restrict__ b,
                                                   OT* __restrict__ out, int rows) {
    int wave = threadIdx.x >> 6;
    int lane = threadIdx.x & 63;
    int row = blockIdx.x * 4 + wave;
    if (row >= rows) return;
    const float* p = in + (size_t)row * CDIM;
    float x0 = p[lane];
    float x1 = (lane < 32) ? p[64 + lane] : 0.f;
    float s = x0 + x1, sq = x0 * x0 + x1 * x1;
#pragma unroll
    for (int o = 32; o >= 1; o >>= 1) { s += __shfl_xor(s, o); sq += __shfl_xor(sq, o); }
    float mean = s * (1.f / 96.f);
    float var = sq * (1.f / 96.f) - mean * mean;
    float w = rsqrtf(var + 1e-5f);
    OT* q = out + (size_t)row * CDIM;
    q[lane] = (OT)((x0 - mean) * w * g[lane] + b[lane]);
    if (lane < 32) q[64 + lane] = (OT)((x1 - mean) * w * g[64 + lane] + b[64 + lane]);
}

// ---------------- bf16 MFMA GEMM: C[M,N] = A[M,K]bf16 @ B[K,N]bf16 ----------------
// Block tile 64x96, 4 waves (2 in M x 2 in N), wave tile 32x48, BK=32.
// EPI: 0 = none, 1 = +bias then gelu, 2 = +bias + f32 residual
template <int EPI, typename CT>
__global__ __launch_bounds__(256) void gemm_bf16(const __hip_bfloat16* __restrict__ A, int lda,
                                                 const __hip_bfloat16* __restrict__ B, int ldb,
                                                 CT* __restrict__ C, int ldc, int N, int K,
                                                 const float* __restrict__ bias,
                                                 const float* __restrict__ res) {
    __shared__ __hip_bfloat16 As[64][48];   // [row][k], stride 96B (16B-aligned)
    __shared__ __hip_bfloat16 Bs[96][48];   // transposed: [col][k]
    int tid = threadIdx.x;
    int lane = tid & 63, wid = tid >> 6;
    int wm = wid & 1, wn = wid >> 1;
    int m0 = blockIdx.y * 64, n0 = blockIdx.x * 96;
    f32x4 acc[2][3] = {};
    int rowA = tid >> 2, kbA = (tid & 3) * 8;  // A staging: one bf16x8 per thread
    for (int k0 = 0; k0 < K; k0 += 32) {
        // stage A (coalesced 16B loads)
        *(bf16x8*)&As[rowA][kbA] =
            *reinterpret_cast<const bf16x8*>(A + (size_t)(m0 + rowA) * lda + k0 + kbA);
        // stage B transposed (coalesced global, scattered LDS writes)
#pragma unroll
        for (int i = 0; i < 3; ++i) {
            int v = tid + i * 256;           // 768 vec4s = 32k x 96n / 4
            int k = v / 24, n4 = (v % 24) * 4;
#pragma unroll
            for (int t = 0; t < 4; ++t) {
                int col = n0 + n4 + t;
                __hip_bfloat16 bv = (col < N) ? B[(size_t)(k0 + k) * ldb + col]
                                              : __float2bfloat16(0.f);
                Bs[n4 + t][k] = bv;
            }
        }
        __syncthreads();
        bf16x8 afr[2], bfr[3];
#pragma unroll
        for (int i = 0; i < 2; ++i)
            afr[i] = *(bf16x8*)&As[wm * 32 + i * 16 + (lane & 15)][(lane >> 4) * 8];
#pragma unroll
        for (int j = 0; j < 3; ++j)
            bfr[j] = *(bf16x8*)&Bs[wn * 48 + j * 16 + (lane & 15)][(lane >> 4) * 8];
#pragma unroll
        for (int i = 0; i < 2; ++i)
#pragma unroll
            for (int j = 0; j < 3; ++j)
                acc[i][j] = __builtin_amdgcn_mfma_f32_16x16x32_bf16(afr[i], bfr[j], acc[i][j], 0, 0, 0);
        __syncthreads();
    }
#pragma unroll
    for (int i = 0; i < 2; ++i) {
        int crow = m0 + wm * 32 + i * 16 + ((lane >> 4) << 2);
#pragma unroll
        for (int j = 0; j < 3; ++j) {
            int ccol = n0 + wn * 48 + j * 16 + (lane & 15);
            if (ccol < N) {
#pragma unroll
                for (int q = 0; q < 4; ++q) {
                    float v = acc[i][j][q];
                    if (EPI == 1) v = gelu_exact(v + bias[ccol]);
                    else if (EPI == 2) v = v + bias[ccol] + res[(size_t)(crow + q) * ldc + ccol];
                    C[(size_t)(crow + q) * ldc + ccol] = (CT)v;
                }
            }
        }
    }
}

// ---------------- 3x3 SAME conv as implicit MFMA GEMM (K=1728, N=96) ----------------
__global__ __launch_bounds__(256) void conv3x3_mfma(const __hip_bfloat16* __restrict__ cat,
                                                    const __hip_bfloat16* __restrict__ Wf,
                                                    const float* __restrict__ bfv,
                                                    __hip_bfloat16* __restrict__ out) {
    __shared__ __hip_bfloat16 As[64][48];
    __shared__ __hip_bfloat16 Bs[96][48];
    int tid = threadIdx.x;
    int lane = tid & 63, wid = tid >> 6;
    int wm = wid & 1, wn = wid >> 1;
    int m0 = blockIdx.y * 64;
    const int N = 96, K = 1728;
    f32x4 acc[2][3] = {};
    int rowA = tid >> 2, kbA = (tid & 3) * 8;
    int m = m0 + rowA;
    int bb = m >> 12, l = m & 4095, yy = l >> 6, xx = l & 63;
    for (int k0 = 0; k0 < K; k0 += 32) {
        // chunk of 32 k has fixed (ky,kx), contiguous ic
        int ky = k0 / 576;
        int r = k0 - ky * 576;
        int kx = r / 192;
        int ic = (r - kx * 192) + kbA;
        int iy = yy + ky - 1, ix = xx + kx - 1;
        bf16x8 av = {};
        if ((unsigned)iy < 64u && (unsigned)ix < 64u)
            av = *reinterpret_cast<const bf16x8*>(
                cat + ((size_t)bb * 4096 + (size_t)iy * 64 + ix) * 192 + ic);
        *(bf16x8*)&As[rowA][kbA] = av;
#pragma unroll
        for (int i = 0; i < 3; ++i) {
            int v = tid + i * 256;
            int k = v / 24, n4 = (v % 24) * 4;
#pragma unroll
            for (int t = 0; t < 4; ++t)
                Bs[n4 + t][k] = Wf[(size_t)(k0 + k) * 96 + n4 + t];
        }
        __syncthreads();
        bf16x8 afr[2], bfr[3];
#pragma unroll
        for (int i = 0; i < 2; ++i)
            afr[i] = *(bf16x8*)&As[wm * 32 + i * 16 + (lane & 15)][(lane >> 4) * 8];
#pragma unroll
        for (int j = 0; j < 3; ++j)
            bfr[j] = *(bf16x8*)&Bs[wn * 48 + j * 16 + (lane & 15)][(lane >> 4) * 8];
#pragma unroll
        for (int i = 0; i < 2; ++i)
#pragma unroll
            for (int j = 0; j < 3; ++j)
                acc[i][j] = __builtin_amdgcn_mfma_f32_16x16x32_bf16(afr[i], bfr[j], acc[i][j], 0, 0, 0);
        __syncthreads();
    }
#pragma unroll
    for (int i = 0; i < 2; ++i) {
        int crow = m0 + wm * 32 + i * 16 + ((lane >> 4) << 2);
#pragma unroll
        for (int j = 0; j < 3; ++j) {
            int ccol = wn * 48 + j * 16 + (lane & 15);
#pragma unroll
            for (int q = 0; q < 4; ++q) {
                float v = gelu_exact(acc[i][j][q] + bfv[ccol]);
                out[(size_t)(crow + q) * 96 + ccol] = __float2bfloat16(v);
            }
        }
    }
}

// ---------------- depthwise causal conv (k=4) + sigmoid(delta) ----------------
__global__ __launch_bounds__(256) void convsig_kernel(const float* __restrict__ xp,
                                                      const float* __restrict__ cw,
                                                      const float* __restrict__ cb,
                                                      float* __restrict__ xc,
                                                      float* __restrict__ dsg) {
    int idx = blockIdx.x * blockDim.x + threadIdx.x;
    if (idx >= MROWS * DIN) return;
    int d = idx % DIN;
    int row = idx / DIN;
    int l = row & (L_SEQ - 1);
    float w0 = cw[d * 4 + 0], w1 = cw[d * 4 + 1], w2 = cw[d * 4 + 2], w3 = cw[d * 4 + 3];
    float acc = cb[d];
    acc += w3 * xp[(size_t)row * XPW + d];
    if (l >= 1) acc += w2 * xp[(size_t)(row - 1) * XPW + d];
    if (l >= 2) acc += w1 * xp[(size_t)(row - 2) * XPW + d];
    if (l >= 3) acc += w0 * xp[(size_t)(row - 3) * XPW + d];
    xc[(size_t)row * DIN + d] = acc;
    float dp = xp[(size_t)row * XPW + 192 + d];
    dsg[(size_t)row * DIN + d] = 1.f / (1.f + __expf(-dp));
}

// ---------------- scan pass1: per-chunk P, fwd-local final Hf, bwd-local start Gb ----
__global__ __launch_bounds__(192) void scan_pass1(const float* __restrict__ dsg,
                                                  const float* __restrict__ xc,
                                                  const float* __restrict__ xp,
                                                  const float* __restrict__ A,
                                                  float* __restrict__ Pc,
                                                  float* __restrict__ Hf,
                                                  float* __restrict__ Gb) {
    int gid = blockIdx.x; // b*512 + c*16 + n
    int n = gid & 15;
    int c = (gid >> 4) & 31;
    int b = gid >> 9;
    int d = threadIdx.x;
    float asum = 0.f;
#pragma unroll
    for (int j = 0; j < 16; ++j) asum += A[n * 16 + j];
    float h = 0.f, gb = 0.f, Q = 1.f;
    int t0 = c * CHLEN;
    for (int tl = 0; tl < CHLEN; ++tl) {
        size_t row = (size_t)b * L_SEQ + t0 + tl;
        float dl = dsg[row * DIN + d];
        float xv = xc[row * DIN + d];
        float bm = xp[row * XPW + 384 + n];
        float a = __expf(dl * asum);
        float bu = dl * xv * bm;
        h = a * h + bu;
        gb += Q * bu;
        Q *= a;
    }
    size_t cidx = (((size_t)b * NCHUNK + c) * NST + n) * DIN + d;
    Pc[cidx] = Q;
    Hf[cidx] = h;
    Gb[cidx] = gb;
}

// ---------------- scan pass2: combine chunk carries sequentially ----------------
__global__ __launch_bounds__(256) void scan_pass2(const float* __restrict__ Pc,
                                                  const float* __restrict__ Hf,
                                                  const float* __restrict__ Gb,
                                                  float* __restrict__ Hinf,
                                                  float* __restrict__ Hinb) {
    int t = blockIdx.x * blockDim.x + threadIdx.x;
    if (t >= 2 * NST * DIN) return;
    int d = t % DIN;
    int n = (t / DIN) % NST;
    int b = t / (DIN * NST);
    float hin = 0.f;
    for (int c = 0; c < NCHUNK; ++c) {
        size_t idx = (((size_t)b * NCHUNK + c) * NST + n) * DIN + d;
        Hinf[idx] = hin;
        hin = Hf[idx] + Pc[idx] * hin;
    }
    float gin = 0.f;
    for (int c = NCHUNK - 1; c >= 0; --c) {
        size_t idx = (((size_t)b * NCHUNK + c) * NST + n) * DIN + d;
        Hinb[idx] = gin;
        gin = Gb[idx] + Pc[idx] * gin;
    }
}

// ---------------- scan pass3: re-scan with carries, fuse y = sum_n Cm*h + Dp*xc ----------------
__global__ __launch_bounds__(256) void scan_pass3(const float* __restrict__ dsg,
                                                  const float* __restrict__ xc,
                                                  const float* __restrict__ xp,
                                                  const float* __restrict__ A,
                                                  const float* __restrict__ Hinf,
                                                  const float* __restrict__ Hinb,
                                                  const float* __restrict__ Dp,
                                                  __hip_bfloat16* __restrict__ y) {
    __shared__ float ys[CHLEN * 16];
    int bid = blockIdx.x; // (b * 32 + c) * 12 + dg
    int dg = bid % 12;
    int c = (bid / 12) % NCHUNK;
    int b = bid / (12 * NCHUNK);
    int lane = threadIdx.x & 63;
    int wave = threadIdx.x >> 6;
    int n = lane & 15;
    int dsub = lane >> 4;
    int dloc = wave * 4 + dsub;
    int d = dg * 16 + dloc;
    float asum = 0.f;
#pragma unroll
    for (int j = 0; j < 16; ++j) asum += A[n * 16 + j];
    size_t cidx = (((size_t)b * NCHUNK + c) * NST + n) * DIN + d;
    int t0 = c * CHLEN;
    float h = Hinf[cidx];
    for (int tl = 0; tl < CHLEN; ++tl) {
        size_t row = (size_t)b * L_SEQ + t0 + tl;
        float dl = dsg[row * DIN + d];
        float xv = xc[row * DIN + d];
        float bm = xp[row * XPW + 384 + n];
        float cm = xp[row * XPW + 400 + n];
        float a = __expf(dl * asum);
        float bu = dl * xv * bm;
        h = a * h + bu;
        float p = cm * h;
        p += __shfl_xor(p, 1);
        p += __shfl_xor(p, 2);
        p += __shfl_xor(p, 4);
        p += __shfl_xor(p, 8);
        if (n == 0) ys[tl * 16 + dloc] = p;
    }
    float gv = Hinb[cidx];
    for (int tl = CHLEN - 1; tl >= 0; --tl) {
        size_t row = (size_t)b * L_SEQ + t0 + tl;
        float dl = dsg[row * DIN + d];
        float xv = xc[row * DIN + d];
        float bm = xp[row * XPW + 384 + n];
        float cm = xp[row * XPW + 400 + n];
        float a = __expf(dl * asum);
        float bu = dl * xv * bm;
        gv = a * gv + bu;
        float p = cm * gv;
        p += __shfl_xor(p, 1);
        p += __shfl_xor(p, 2);
        p += __shfl_xor(p, 4);
        p += __shfl_xor(p, 8);
        if (n == 0) ys[tl * 16 + dloc] += p;
    }
    __syncthreads();
#pragma unroll
    for (int i = 0; i < 8; ++i) {
        int sidx = threadIdx.x + i * 256;
        int tl = sidx >> 4;
        int dl2 = sidx & 15;
        int d2 = dg * 16 + dl2;
        size_t row = (size_t)b * L_SEQ + t0 + tl;
        y[row * DIN + d2] = __float2bfloat16(ys[sidx] + Dp[d2] * xc[row * DIN + d2]);
    }
}

// ---------------- cosine-sim fusion: cat = [f1, sim*f1 + (1-sim)*f2] (bf16 out) ----------------
__global__ __launch_bounds__(256) void fuse_kernel(const float* __restrict__ f1,
                                                   const float* __restrict__ f2,
                                                   __hip_bfloat16* __restrict__ cat, int rows) {
    int wave = threadIdx.x >> 6;
    int lane = threadIdx.x & 63;
    int row = blockIdx.x * 4 + wave;
    if (row >= rows) return;
    const float* p1 = f1 + (size_t)row * CDIM;
    const float* p2 = f2 + (size_t)row * CDIM;
    float a0 = p1[lane], b0 = p2[lane];
    float a1 = 0.f, b1 = 0.f;
    if (lane < 32) { a1 = p1[64 + lane]; b1 = p2[64 + lane]; }
    float s11 = a0 * a0 + a1 * a1;
    float s22 = b0 * b0 + b1 * b1;
    float s12 = a0 * b0 + a1 * b1;
#pragma unroll
    for (int o = 32; o >= 1; o >>= 1) {
        s11 += __shfl_xor(s11, o);
        s22 += __shfl_xor(s22, o);
        s12 += __shfl_xor(s12, o);
    }
    float nr1 = fmaxf(sqrtf(s11), 1e-12f);
    float nr2 = fmaxf(sqrtf(s22), 1e-12f);
    float sim = s12 / (nr1 * nr2);
    __hip_bfloat16* q = cat + (size_t)row * 192;
    q[lane] = __float2bfloat16(a0);
    q[96 + lane] = __float2bfloat16(sim * a0 + (1.f - sim) * b0);
    if (lane < 32) {
        q[64 + lane] = __float2bfloat16(a1);
        q[96 + 64 + lane] = __float2bfloat16(sim * a1 + (1.f - sim) * b1);
    }
}

extern "C" void kernel_launch(void* const* d_in, const int* in_sizes, int n_in,
                              void* d_out, int out_size, void* d_ws, size_t ws_size,
                              hipStream_t stream) {
    const float* x = (const float*)d_in[0];
    const float* norm_g = (const float*)d_in[1];
    const float* norm_b = (const float*)d_in[2];
    const float* Wp[2] = {(const float*)d_in[3], (const float*)d_in[11]};
    const float* cw[2] = {(const float*)d_in[4], (const float*)d_in[12]};
    const float* cb[2] = {(const float*)d_in[5], (const float*)d_in[13]};
    const float* Ab[2] = {(const float*)d_in[6], (const float*)d_in[14]};
    const float* Dpb[2] = {(const float*)d_in[7], (const float*)d_in[15]};
    const float* Wo[2] = {(const float*)d_in[8], (const float*)d_in[16]};
    const float* lng[2] = {(const float*)d_in[9], (const float*)d_in[17]};
    const float* lnb[2] = {(const float*)d_in[10], (const float*)d_in[18]};
    const float* Wf = (const float*)d_in[19];
    const float* bfv = (const float*)d_in[20];
    const float* W1 = (const float*)d_in[21];
    const float* b1 = (const float*)d_in[22];
    const float* W2 = (const float*)d_in[23];
    const float* b2 = (const float*)d_in[24];
    float* out = (float*)d_out;

    char* base = (char*)d_ws;
    size_t off = 0;
    auto alloc = [&](size_t bytes) { void* p = base + off; off += (bytes + 255) & ~(size_t)255; return p; };
    float* xp = (float*)alloc((size_t)MROWS * XPW * 4);
    float* xcb = (float*)alloc((size_t)MROWS * DIN * 4);
    float* dsg = (float*)alloc((size_t)MROWS * DIN * 4);
    float* tmp96 = (float*)alloc((size_t)MROWS * 96 * 4);
    float* f1 = (float*)alloc((size_t)MROWS * 96 * 4);
    float* f2 = (float*)alloc((size_t)MROWS * 96 * 4);
    const size_t csz = (size_t)2 * NCHUNK * NST * DIN;
    float* Pc = (float*)alloc(csz * 4);
    float* Hfc = (float*)alloc(csz * 4);
    float* Gbc = (float*)alloc(csz * 4);
    float* Hinf = (float*)alloc(csz * 4);
    float* Hinb = (float*)alloc(csz * 4);
    __hip_bfloat16* xn_bf = (__hip_bfloat16*)alloc((size_t)MROWS * 96 * 2);
    __hip_bfloat16* yb_bf = (__hip_bfloat16*)alloc((size_t)MROWS * DIN * 2);
    __hip_bfloat16* cat_bf = (__hip_bfloat16*)alloc((size_t)MROWS * DIN * 2);
    __hip_bfloat16* fc_bf = (__hip_bfloat16*)alloc((size_t)MROWS * 96 * 2);
    __hip_bfloat16* h1_bf = (__hip_bfloat16*)alloc((size_t)MROWS * 384 * 2);
    __hip_bfloat16* wpb[2] = {(__hip_bfloat16*)alloc(96 * XPW * 2),
                              (__hip_bfloat16*)alloc(96 * XPW * 2)};
    __hip_bfloat16* wob[2] = {(__hip_bfloat16*)alloc(DIN * 96 * 2),
                              (__hip_bfloat16*)alloc(DIN * 96 * 2)};
    __hip_bfloat16* wfb = (__hip_bfloat16*)alloc(1728 * 96 * 2);
    __hip_bfloat16* w1b = (__hip_bfloat16*)alloc(96 * 384 * 2);
    __hip_bfloat16* w2b = (__hip_bfloat16*)alloc(384 * 96 * 2);
    (void)ws_size; (void)in_sizes; (void)n_in; (void)out_size;

    // weight conversions
    cvt_wp<<<dim3((96 * XPW + 255) / 256), dim3(256), 0, stream>>>(Wp[0], wpb[0]);
    cvt_wp<<<dim3((96 * XPW + 255) / 256), dim3(256), 0, stream>>>(Wp[1], wpb[1]);
    cvt_f32_bf16<<<dim3((DIN * 96 + 255) / 256), dim3(256), 0, stream>>>(Wo[0], wob[0], DIN * 96);
    cvt_f32_bf16<<<dim3((DIN * 96 + 255) / 256), dim3(256), 0, stream>>>(Wo[1], wob[1], DIN * 96);
    cvt_f32_bf16<<<dim3((1728 * 96 + 255) / 256), dim3(256), 0, stream>>>(Wf, wfb, 1728 * 96);
    cvt_f32_bf16<<<dim3((96 * 384 + 255) / 256), dim3(256), 0, stream>>>(W1, w1b, 96 * 384);
    cvt_f32_bf16<<<dim3((384 * 96 + 255) / 256), dim3(256), 0, stream>>>(W2, w2b, 384 * 96);

    // 1. input LayerNorm -> bf16
    ln96_kernel<__hip_bfloat16><<<dim3(2048), dim3(256), 0, stream>>>(x, norm_g, norm_b, xn_bf, MROWS);

    float* fouts[2] = {f1, f2};
    for (int p = 0; p < 2; ++p) {
        // xp = xn @ Wp[:, :416]
        gemm_bf16<0, float><<<dim3(5, 128), dim3(256), 0, stream>>>(
            xn_bf, 96, wpb[p], XPW, xp, XPW, XPW, 96, nullptr, nullptr);
        convsig_kernel<<<dim3(6144), dim3(256), 0, stream>>>(xp, cw[p], cb[p], xcb, dsg);
        scan_pass1<<<dim3(1024), dim3(192), 0, stream>>>(dsg, xcb, xp, Ab[p], Pc, Hfc, Gbc);
        scan_pass2<<<dim3(24), dim3(256), 0, stream>>>(Pc, Hfc, Gbc, Hinf, Hinb);
        scan_pass3<<<dim3(768), dim3(256), 0, stream>>>(dsg, xcb, xp, Ab[p], Hinf, Hinb,
                                                        Dpb[p], yb_bf);
        // f_pre = y @ Wo ; f = LN(f_pre)
        gemm_bf16<0, float><<<dim3(1, 128), dim3(256), 0, stream>>>(
            yb_bf, DIN, wob[p], 96, tmp96, 96, 96, DIN, nullptr, nullptr);
        ln96_kernel<float><<<dim3(2048), dim3(256), 0, stream>>>(tmp96, lng[p], lnb[p], fouts[p], MROWS);
    }

    fuse_kernel<<<dim3(2048), dim3(256), 0, stream>>>(f1, f2, cat_bf, MROWS);
    // fc = gelu(conv3x3(cat) + bf)
    conv3x3_mfma<<<dim3(1, 128), dim3(256), 0, stream>>>(cat_bf, wfb, bfv, fc_bf);
    // h1 = gelu(fc @ W1 + b1)
    gemm_bf16<1, __hip_bfloat16><<<dim3(4, 128), dim3(256), 0, stream>>>(
        fc_bf, 96, w1b, 384, h1_bf, 384, 384, 96, b1, nullptr);
    // out = h1 @ W2 + b2 + res
    gemm_bf16<2, float><<<dim3(1, 128), dim3(256), 0, stream>>>(
        h1_bf, 384, w2b, 96, out, 96, 96, 384, b2, x);
}

// Round 3
// 391.500 us; speedup vs baseline: 1.6675x; 1.2840x over previous
//
#include <hip/hip_runtime.h>
#include <hip/hip_bf16.h>
#include <math.h>

#define L_SEQ 4096
#define CDIM 96
#define DIN 192
#define NST 16
#define XPW 416
#define NCHUNK 64
#define CHLEN 64
#define MROWS 8192

typedef __attribute__((ext_vector_type(8))) short bf16x8;
typedef __attribute__((ext_vector_type(4))) float f32x4;

__device__ __forceinline__ float gelu_exact(float x) {
    return 0.5f * x * (1.0f + erff(x * 0.70710678118654752f));
}

// ---------------- all weight conversions in one kernel ----------------
__global__ __launch_bounds__(256) void cvt_all(
    const float* __restrict__ Wp0, const float* __restrict__ Wp1,
    const float* __restrict__ Wo0, const float* __restrict__ Wo1,
    const float* __restrict__ Wf, const float* __restrict__ W1, const float* __restrict__ W2,
    __hip_bfloat16* __restrict__ wp0, __hip_bfloat16* __restrict__ wp1,
    __hip_bfloat16* __restrict__ wo0, __hip_bfloat16* __restrict__ wo1,
    __hip_bfloat16* __restrict__ wfb, __hip_bfloat16* __restrict__ w1b,
    __hip_bfloat16* __restrict__ w2b) {
    int i = blockIdx.x * 256 + threadIdx.x;
    const int S_WP = 96 * XPW, S_WO = DIN * 96, S_WF = 1728 * 96, S_W1 = 96 * 384, S_W2 = 384 * 96;
    if (i < S_WP) { int r = i / XPW, c = i - r * XPW; wp0[i] = __float2bfloat16(Wp0[r * 576 + c]); return; }
    i -= S_WP;
    if (i < S_WP) { int r = i / XPW, c = i - r * XPW; wp1[i] = __float2bfloat16(Wp1[r * 576 + c]); return; }
    i -= S_WP;
    if (i < S_WO) { wo0[i] = __float2bfloat16(Wo0[i]); return; }
    i -= S_WO;
    if (i < S_WO) { wo1[i] = __float2bfloat16(Wo1[i]); return; }
    i -= S_WO;
    if (i < S_WF) { wfb[i] = __float2bfloat16(Wf[i]); return; }
    i -= S_WF;
    if (i < S_W1) { w1b[i] = __float2bfloat16(W1[i]); return; }
    i -= S_W1;
    if (i < S_W2) { w2b[i] = __float2bfloat16(W2[i]); return; }
}

// ---------------- LayerNorm over last dim 96, one wave per row ----------------
template <typename OT>
__global__ __launch_bounds__(256) void ln96_kernel(const float* __restrict__ in,
                                                   const float* __restrict__ g,
                                                   const float* __restrict__ b,
                                                   OT* __restrict__ out, int rows) {
    int wave = threadIdx.x >> 6;
    int lane = threadIdx.x & 63;
    int row = blockIdx.x * 4 + wave;
    if (row >= rows) return;
    const float* p = in + (size_t)row * CDIM;
    float x0 = p[lane];
    float x1 = (lane < 32) ? p[64 + lane] : 0.f;
    float s = x0 + x1, sq = x0 * x0 + x1 * x1;
#pragma unroll
    for (int o = 32; o >= 1; o >>= 1) { s += __shfl_xor(s, o); sq += __shfl_xor(sq, o); }
    float mean = s * (1.f / 96.f);
    float var = sq * (1.f / 96.f) - mean * mean;
    float w = rsqrtf(var + 1e-5f);
    OT* q = out + (size_t)row * CDIM;
    q[lane] = (OT)((x0 - mean) * w * g[lane] + b[lane]);
    if (lane < 32) q[64 + lane] = (OT)((x1 - mean) * w * g[64 + lane] + b[64 + lane]);
}

// ---------------- bf16 MFMA GEMM: C[M,N] = A[M,K]bf16 @ B[K,N]bf16 ----------------
// Block tile BM x 96, 4 waves (2 in M x 2 in N), BK=32.
// EPI: 0 = none, 1 = +bias then gelu, 2 = +bias + f32 residual
template <int BM, int EPI, typename CT>
__global__ __launch_bounds__(256) void gemm_bf16(const __hip_bfloat16* __restrict__ A, int lda,
                                                 const __hip_bfloat16* __restrict__ B, int ldb,
                                                 CT* __restrict__ C, int ldc, int N, int K,
                                                 const float* __restrict__ bias,
                                                 const float* __restrict__ res) {
    __shared__ __hip_bfloat16 As[BM][48];   // [row][k], stride 96B (16B-aligned)
    __shared__ __hip_bfloat16 Bs[96][48];   // transposed: [col][k]
    constexpr int MI = BM / 32;             // fragments per wave in M
    int tid = threadIdx.x;
    int lane = tid & 63, wid = tid >> 6;
    int wm = wid & 1, wn = wid >> 1;
    int m0 = blockIdx.y * BM, n0 = blockIdx.x * 96;
    f32x4 acc[MI][3] = {};
    int rowA = tid >> 2, kbA = (tid & 3) * 8;
    for (int k0 = 0; k0 < K; k0 += 32) {
        if (tid < BM * 4)
            *(bf16x8*)&As[rowA][kbA] =
                *reinterpret_cast<const bf16x8*>(A + (size_t)(m0 + rowA) * lda + k0 + kbA);
#pragma unroll
        for (int i = 0; i < 3; ++i) {
            int v = tid + i * 256;           // 768 vec4s = 32k x 96n / 4
            int k = v / 24, n4 = (v % 24) * 4;
#pragma unroll
            for (int t = 0; t < 4; ++t) {
                int col = n0 + n4 + t;
                __hip_bfloat16 bv = (col < N) ? B[(size_t)(k0 + k) * ldb + col]
                                              : __float2bfloat16(0.f);
                Bs[n4 + t][k] = bv;
            }
        }
        __syncthreads();
        bf16x8 afr[MI], bfr[3];
#pragma unroll
        for (int i = 0; i < MI; ++i)
            afr[i] = *(bf16x8*)&As[wm * (BM / 2) + i * 16 + (lane & 15)][(lane >> 4) * 8];
#pragma unroll
        for (int j = 0; j < 3; ++j)
            bfr[j] = *(bf16x8*)&Bs[wn * 48 + j * 16 + (lane & 15)][(lane >> 4) * 8];
#pragma unroll
        for (int i = 0; i < MI; ++i)
#pragma unroll
            for (int j = 0; j < 3; ++j)
                acc[i][j] = __builtin_amdgcn_mfma_f32_16x16x32_bf16(afr[i], bfr[j], acc[i][j], 0, 0, 0);
        __syncthreads();
    }
#pragma unroll
    for (int i = 0; i < MI; ++i) {
        int crow = m0 + wm * (BM / 2) + i * 16 + ((lane >> 4) << 2);
#pragma unroll
        for (int j = 0; j < 3; ++j) {
            int ccol = n0 + wn * 48 + j * 16 + (lane & 15);
            if (ccol < N) {
#pragma unroll
                for (int q = 0; q < 4; ++q) {
                    float v = acc[i][j][q];
                    if (EPI == 1) v = gelu_exact(v + bias[ccol]);
                    else if (EPI == 2) v = v + bias[ccol] + res[(size_t)(crow + q) * ldc + ccol];
                    C[(size_t)(crow + q) * ldc + ccol] = (CT)v;
                }
            }
        }
    }
}

// ---------------- 3x3 SAME conv as implicit MFMA GEMM (K=1728, N=96, BM=32) ----------------
__global__ __launch_bounds__(256) void conv3x3_mfma(const __hip_bfloat16* __restrict__ cat,
                                                    const __hip_bfloat16* __restrict__ Wf,
                                                    const float* __restrict__ bfv,
                                                    __hip_bfloat16* __restrict__ out) {
    __shared__ __hip_bfloat16 As[32][48];
    __shared__ __hip_bfloat16 Bs[96][48];
    int tid = threadIdx.x;
    int lane = tid & 63, wid = tid >> 6;
    int wm = wid & 1, wn = wid >> 1;
    int m0 = blockIdx.y * 32;
    const int K = 1728;
    f32x4 acc[3] = {};
    int rowA = tid >> 2, kbA = (tid & 3) * 8;
    int m = m0 + rowA;
    int bb = m >> 12, l = m & 4095, yy = l >> 6, xx = l & 63;
    for (int k0 = 0; k0 < K; k0 += 32) {
        int ky = k0 / 576;
        int r = k0 - ky * 576;
        int kx = r / 192;
        int ic = (r - kx * 192) + kbA;
        if (tid < 128) {
            int iy = yy + ky - 1, ix = xx + kx - 1;
            bf16x8 av = {};
            if ((unsigned)iy < 64u && (unsigned)ix < 64u)
                av = *reinterpret_cast<const bf16x8*>(
                    cat + ((size_t)bb * 4096 + (size_t)iy * 64 + ix) * 192 + ic);
            *(bf16x8*)&As[rowA][kbA] = av;
        }
#pragma unroll
        for (int i = 0; i < 3; ++i) {
            int v = tid + i * 256;
            int k = v / 24, n4 = (v % 24) * 4;
#pragma unroll
            for (int t = 0; t < 4; ++t)
                Bs[n4 + t][k] = Wf[(size_t)(k0 + k) * 96 + n4 + t];
        }
        __syncthreads();
        bf16x8 afr, bfr[3];
        afr = *(bf16x8*)&As[wm * 16 + (lane & 15)][(lane >> 4) * 8];
#pragma unroll
        for (int j = 0; j < 3; ++j)
            bfr[j] = *(bf16x8*)&Bs[wn * 48 + j * 16 + (lane & 15)][(lane >> 4) * 8];
#pragma unroll
        for (int j = 0; j < 3; ++j)
            acc[j] = __builtin_amdgcn_mfma_f32_16x16x32_bf16(afr, bfr[j], acc[j], 0, 0, 0);
        __syncthreads();
    }
    int crow = m0 + wm * 16 + ((lane >> 4) << 2);
#pragma unroll
    for (int j = 0; j < 3; ++j) {
        int ccol = wn * 48 + j * 16 + (lane & 15);
#pragma unroll
        for (int q = 0; q < 4; ++q) {
            float v = gelu_exact(acc[j][q] + bfv[ccol]);
            out[(size_t)(crow + q) * 96 + ccol] = __float2bfloat16(v);
        }
    }
}

// ---------------- depthwise causal conv (k=4) + sigmoid(delta), float4 ----------------
__global__ __launch_bounds__(256) void convsig_kernel(const float* __restrict__ xp,
                                                      const float* __restrict__ cw,
                                                      const float* __restrict__ cb,
                                                      float* __restrict__ xc,
                                                      float* __restrict__ dsg) {
    int idx = blockIdx.x * 256 + threadIdx.x;
    if (idx >= MROWS * 48) return;
    int d4 = idx % 48;
    int row = idx / 48;
    int d = d4 * 4;
    int l = row & (L_SEQ - 1);
    const float4 zero = {0.f, 0.f, 0.f, 0.f};
    float4 c0 = *(const float4*)(xp + (size_t)row * XPW + d);
    float4 p1 = (l >= 1) ? *(const float4*)(xp + (size_t)(row - 1) * XPW + d) : zero;
    float4 p2 = (l >= 2) ? *(const float4*)(xp + (size_t)(row - 2) * XPW + d) : zero;
    float4 p3 = (l >= 3) ? *(const float4*)(xp + (size_t)(row - 3) * XPW + d) : zero;
    float4 dp = *(const float4*)(xp + (size_t)row * XPW + 192 + d);
    float a0[4] = {c0.x, c0.y, c0.z, c0.w};
    float a1[4] = {p1.x, p1.y, p1.z, p1.w};
    float a2[4] = {p2.x, p2.y, p2.z, p2.w};
    float a3[4] = {p3.x, p3.y, p3.z, p3.w};
    float dd[4] = {dp.x, dp.y, dp.z, dp.w};
    float oc[4], od[4];
#pragma unroll
    for (int i = 0; i < 4; ++i) {
        float4 w = *(const float4*)(cw + (size_t)(d + i) * 4);  // (w0,w1,w2,w3)
        oc[i] = cb[d + i] + w.w * a0[i] + w.z * a1[i] + w.y * a2[i] + w.x * a3[i];
        od[i] = 1.f / (1.f + __expf(-dd[i]));
    }
    *(float4*)(xc + (size_t)row * DIN + d) = *(float4*)oc;
    *(float4*)(dsg + (size_t)row * DIN + d) = *(float4*)od;
}

// ---------------- scan pass1: LDS-staged chunk scan; per-(n,d) thread ----------------
// grid: b * NCHUNK * 12 blocks; block = (b, c, dg); 256 threads = 16 n x 16 d
__global__ __launch_bounds__(256) void scan_pass1(const float* __restrict__ dsg,
                                                  const float* __restrict__ xc,
                                                  const float* __restrict__ xp,
                                                  const float* __restrict__ A,
                                                  float* __restrict__ Pc,
                                                  float* __restrict__ Hf,
                                                  float* __restrict__ Gb) {
    __shared__ float sd[CHLEN][16], sx[CHLEN][16], sb[CHLEN][16], sA[256];
    int bid = blockIdx.x;
    int dg = bid % 12;
    int c = (bid / 12) % NCHUNK;
    int b = bid / (12 * NCHUNK);
    int tid = threadIdx.x;
    sA[tid] = A[tid];
    {
        int r = tid >> 2, q = (tid & 3) * 4;
        size_t grow = (size_t)b * L_SEQ + c * CHLEN + r;
        *(float4*)&sd[r][q] = *(const float4*)(dsg + grow * DIN + dg * 16 + q);
        *(float4*)&sx[r][q] = *(const float4*)(xc + grow * DIN + dg * 16 + q);
        *(float4*)&sb[r][q] = *(const float4*)(xp + grow * XPW + 384 + q);
    }
    __syncthreads();
    int n = tid & 15, drow = tid >> 4;
    float asum = 0.f;
#pragma unroll
    for (int j = 0; j < 16; ++j) asum += sA[n * 16 + j];
    float h = 0.f, gb = 0.f, Q = 1.f;
    for (int t = 0; t < CHLEN; ++t) {
        float dl = sd[t][drow];
        float xv = sx[t][drow];
        float bm = sb[t][n];
        float a = __expf(dl * asum);
        float bu = dl * xv * bm;
        h = a * h + bu;
        gb += Q * bu;
        Q *= a;
    }
    size_t cidx = (((size_t)b * NCHUNK + c) * NST + n) * DIN + dg * 16 + drow;
    Pc[cidx] = Q;
    Hf[cidx] = h;
    Gb[cidx] = gb;
}

// ---------------- scan pass2: combine chunk carries sequentially ----------------
__global__ __launch_bounds__(256) void scan_pass2(const float* __restrict__ Pc,
                                                  const float* __restrict__ Hf,
                                                  const float* __restrict__ Gb,
                                                  float* __restrict__ Hinf,
                                                  float* __restrict__ Hinb) {
    int t = blockIdx.x * blockDim.x + threadIdx.x;
    if (t >= 2 * NST * DIN) return;
    int d = t % DIN;
    int n = (t / DIN) % NST;
    int b = t / (DIN * NST);
    float hin = 0.f;
    for (int c = 0; c < NCHUNK; ++c) {
        size_t idx = (((size_t)b * NCHUNK + c) * NST + n) * DIN + d;
        Hinf[idx] = hin;
        hin = Hf[idx] + Pc[idx] * hin;
    }
    float gin = 0.f;
    for (int c = NCHUNK - 1; c >= 0; --c) {
        size_t idx = (((size_t)b * NCHUNK + c) * NST + n) * DIN + d;
        Hinb[idx] = gin;
        gin = Gb[idx] + Pc[idx] * gin;
    }
}

// ---------------- scan pass3: LDS-staged re-scan with carries, fused y ----------------
// grid: b * NCHUNK * 12; block = (b, c, dg); 4 waves, each wave: 16 n x 4 d
__global__ __launch_bounds__(256) void scan_pass3(const float* __restrict__ dsg,
                                                  const float* __restrict__ xc,
                                                  const float* __restrict__ xp,
                                                  const float* __restrict__ A,
                                                  const float* __restrict__ Hinf,
                                                  const float* __restrict__ Hinb,
                                                  const float* __restrict__ Dp,
                                                  __hip_bfloat16* __restrict__ y) {
    __shared__ float sd[CHLEN][16], sx[CHLEN][16], sb[CHLEN][16], sc[CHLEN][16];
    __shared__ float ys[CHLEN * 16], sA[256];
    int bid = blockIdx.x;
    int dg = bid % 12;
    int c = (bid / 12) % NCHUNK;
    int b = bid / (12 * NCHUNK);
    int tid = threadIdx.x;
    sA[tid] = A[tid];
    {
        int r = tid >> 2, q = (tid & 3) * 4;
        size_t grow = (size_t)b * L_SEQ + c * CHLEN + r;
        *(float4*)&sd[r][q] = *(const float4*)(dsg + grow * DIN + dg * 16 + q);
        *(float4*)&sx[r][q] = *(const float4*)(xc + grow * DIN + dg * 16 + q);
        *(float4*)&sb[r][q] = *(const float4*)(xp + grow * XPW + 384 + q);
        *(float4*)&sc[r][q] = *(const float4*)(xp + grow * XPW + 400 + q);
    }
    __syncthreads();
    int lane = tid & 63, wave = tid >> 6;
    int n = lane & 15;
    int dloc = wave * 4 + (lane >> 4);
    int d = dg * 16 + dloc;
    float asum = 0.f;
#pragma unroll
    for (int j = 0; j < 16; ++j) asum += sA[n * 16 + j];
    size_t cidx = (((size_t)b * NCHUNK + c) * NST + n) * DIN + d;
    float h = Hinf[cidx];
    for (int t = 0; t < CHLEN; ++t) {
        float dl = sd[t][dloc];
        float xv = sx[t][dloc];
        float a = __expf(dl * asum);
        float bu = dl * xv * sb[t][n];
        h = a * h + bu;
        float p = sc[t][n] * h;
        p += __shfl_xor(p, 1);
        p += __shfl_xor(p, 2);
        p += __shfl_xor(p, 4);
        p += __shfl_xor(p, 8);
        if (n == 0) ys[t * 16 + dloc] = p;
    }
    float gv = Hinb[cidx];
    for (int t = CHLEN - 1; t >= 0; --t) {
        float dl = sd[t][dloc];
        float xv = sx[t][dloc];
        float a = __expf(dl * asum);
        float bu = dl * xv * sb[t][n];
        gv = a * gv + bu;
        float p = sc[t][n] * gv;
        p += __shfl_xor(p, 1);
        p += __shfl_xor(p, 2);
        p += __shfl_xor(p, 4);
        p += __shfl_xor(p, 8);
        if (n == 0) ys[t * 16 + dloc] += p;
    }
    __syncthreads();
#pragma unroll
    for (int i = 0; i < 4; ++i) {
        int sidx = tid + i * 256;
        int tl = sidx >> 4;
        int dl2 = sidx & 15;
        int d2 = dg * 16 + dl2;
        size_t row = (size_t)b * L_SEQ + c * CHLEN + tl;
        y[row * DIN + d2] = __float2bfloat16(ys[sidx] + Dp[d2] * sx[tl][dl2]);
    }
}

// ---------------- cosine-sim fusion: cat = [f1, sim*f1 + (1-sim)*f2] (bf16 out) ----------------
__global__ __launch_bounds__(256) void fuse_kernel(const float* __restrict__ f1,
                                                   const float* __restrict__ f2,
                                                   __hip_bfloat16* __restrict__ cat, int rows) {
    int wave = threadIdx.x >> 6;
    int lane = threadIdx.x & 63;
    int row = blockIdx.x * 4 + wave;
    if (row >= rows) return;
    const float* p1 = f1 + (size_t)row * CDIM;
    const float* p2 = f2 + (size_t)row * CDIM;
    float a0 = p1[lane], b0 = p2[lane];
    float a1 = 0.f, b1 = 0.f;
    if (lane < 32) { a1 = p1[64 + lane]; b1 = p2[64 + lane]; }
    float s11 = a0 * a0 + a1 * a1;
    float s22 = b0 * b0 + b1 * b1;
    float s12 = a0 * b0 + a1 * b1;
#pragma unroll
    for (int o = 32; o >= 1; o >>= 1) {
        s11 += __shfl_xor(s11, o);
        s22 += __shfl_xor(s22, o);
        s12 += __shfl_xor(s12, o);
    }
    float nr1 = fmaxf(sqrtf(s11), 1e-12f);
    float nr2 = fmaxf(sqrtf(s22), 1e-12f);
    float sim = s12 / (nr1 * nr2);
    __hip_bfloat16* q = cat + (size_t)row * 192;
    q[lane] = __float2bfloat16(a0);
    q[96 + lane] = __float2bfloat16(sim * a0 + (1.f - sim) * b0);
    if (lane < 32) {
        q[64 + lane] = __float2bfloat16(a1);
        q[96 + 64 + lane] = __float2bfloat16(sim * a1 + (1.f - sim) * b1);
    }
}

extern "C" void kernel_launch(void* const* d_in, const int* in_sizes, int n_in,
                              void* d_out, int out_size, void* d_ws, size_t ws_size,
                              hipStream_t stream) {
    const float* x = (const float*)d_in[0];
    const float* norm_g = (const float*)d_in[1];
    const float* norm_b = (const float*)d_in[2];
    const float* Wp[2] = {(const float*)d_in[3], (const float*)d_in[11]};
    const float* cw[2] = {(const float*)d_in[4], (const float*)d_in[12]};
    const float* cb[2] = {(const float*)d_in[5], (const float*)d_in[13]};
    const float* Ab[2] = {(const float*)d_in[6], (const float*)d_in[14]};
    const float* Dpb[2] = {(const float*)d_in[7], (const float*)d_in[15]};
    const float* Wo[2] = {(const float*)d_in[8], (const float*)d_in[16]};
    const float* lng[2] = {(const float*)d_in[9], (const float*)d_in[17]};
    const float* lnb[2] = {(const float*)d_in[10], (const float*)d_in[18]};
    const float* Wf = (const float*)d_in[19];
    const float* bfv = (const float*)d_in[20];
    const float* W1 = (const float*)d_in[21];
    const float* b1 = (const float*)d_in[22];
    const float* W2 = (const float*)d_in[23];
    const float* b2 = (const float*)d_in[24];
    float* out = (float*)d_out;

    char* base = (char*)d_ws;
    size_t off = 0;
    auto alloc = [&](size_t bytes) { void* p = base + off; off += (bytes + 255) & ~(size_t)255; return p; };
    float* xp = (float*)alloc((size_t)MROWS * XPW * 4);
    float* xcb = (float*)alloc((size_t)MROWS * DIN * 4);
    float* dsg = (float*)alloc((size_t)MROWS * DIN * 4);
    float* tmp96 = (float*)alloc((size_t)MROWS * 96 * 4);
    float* f1 = (float*)alloc((size_t)MROWS * 96 * 4);
    float* f2 = (float*)alloc((size_t)MROWS * 96 * 4);
    const size_t csz = (size_t)2 * NCHUNK * NST * DIN;
    float* Pc = (float*)alloc(csz * 4);
    float* Hfc = (float*)alloc(csz * 4);
    float* Gbc = (float*)alloc(csz * 4);
    float* Hinf = (float*)alloc(csz * 4);
    float* Hinb = (float*)alloc(csz * 4);
    __hip_bfloat16* xn_bf = (__hip_bfloat16*)alloc((size_t)MROWS * 96 * 2);
    __hip_bfloat16* yb_bf = (__hip_bfloat16*)alloc((size_t)MROWS * DIN * 2);
    __hip_bfloat16* cat_bf = (__hip_bfloat16*)alloc((size_t)MROWS * DIN * 2);
    __hip_bfloat16* fc_bf = (__hip_bfloat16*)alloc((size_t)MROWS * 96 * 2);
    __hip_bfloat16* h1_bf = (__hip_bfloat16*)alloc((size_t)MROWS * 384 * 2);
    __hip_bfloat16* wpb[2] = {(__hip_bfloat16*)alloc(96 * XPW * 2),
                              (__hip_bfloat16*)alloc(96 * XPW * 2)};
    __hip_bfloat16* wob[2] = {(__hip_bfloat16*)alloc(DIN * 96 * 2),
                              (__hip_bfloat16*)alloc(DIN * 96 * 2)};
    __hip_bfloat16* wfb = (__hip_bfloat16*)alloc(1728 * 96 * 2);
    __hip_bfloat16* w1b = (__hip_bfloat16*)alloc(96 * 384 * 2);
    __hip_bfloat16* w2b = (__hip_bfloat16*)alloc(384 * 96 * 2);
    (void)ws_size; (void)in_sizes; (void)n_in; (void)out_size;

    // all weight conversions (one launch)
    cvt_all<<<dim3(1392), dim3(256), 0, stream>>>(Wp[0], Wp[1], Wo[0], Wo[1], Wf, W1, W2,
                                                  wpb[0], wpb[1], wob[0], wob[1], wfb, w1b, w2b);

    // 1. input LayerNorm -> bf16
    ln96_kernel<__hip_bfloat16><<<dim3(2048), dim3(256), 0, stream>>>(x, norm_g, norm_b, xn_bf, MROWS);

    float* fouts[2] = {f1, f2};
    for (int p = 0; p < 2; ++p) {
        // xp = xn @ Wp[:, :416]
        gemm_bf16<64, 0, float><<<dim3(5, 128), dim3(256), 0, stream>>>(
            xn_bf, 96, wpb[p], XPW, xp, XPW, XPW, 96, nullptr, nullptr);
        convsig_kernel<<<dim3(1536), dim3(256), 0, stream>>>(xp, cw[p], cb[p], xcb, dsg);
        scan_pass1<<<dim3(2 * NCHUNK * 12), dim3(256), 0, stream>>>(dsg, xcb, xp, Ab[p], Pc, Hfc, Gbc);
        scan_pass2<<<dim3(24), dim3(256), 0, stream>>>(Pc, Hfc, Gbc, Hinf, Hinb);
        scan_pass3<<<dim3(2 * NCHUNK * 12), dim3(256), 0, stream>>>(dsg, xcb, xp, Ab[p], Hinf, Hinb,
                                                                    Dpb[p], yb_bf);
        // f_pre = y @ Wo ; f = LN(f_pre)
        gemm_bf16<32, 0, float><<<dim3(1, 256), dim3(256), 0, stream>>>(
            yb_bf, DIN, wob[p], 96, tmp96, 96, 96, DIN, nullptr, nullptr);
        ln96_kernel<float><<<dim3(2048), dim3(256), 0, stream>>>(tmp96, lng[p], lnb[p], fouts[p], MROWS);
    }

    fuse_kernel<<<dim3(2048), dim3(256), 0, stream>>>(f1, f2, cat_bf, MROWS);
    // fc = gelu(conv3x3(cat) + bf)
    conv3x3_mfma<<<dim3(1, 256), dim3(256), 0, stream>>>(cat_bf, wfb, bfv, fc_bf);
    // h1 = gelu(fc @ W1 + b1)
    gemm_bf16<64, 1, __hip_bfloat16><<<dim3(4, 128), dim3(256), 0, stream>>>(
        fc_bf, 96, w1b, 384, h1_bf, 384, 384, 96, b1, nullptr);
    // out = h1 @ W2 + b2 + res
    gemm_bf16<32, 2, float><<<dim3(1, 256), dim3(256), 0, stream>>>(
        h1_bf, 384, w2b, 96, out, 96, 96, 384, b2, x);
}

// Round 4
// 297.270 us; speedup vs baseline: 2.1961x; 1.3170x over previous
//
#include <hip/hip_runtime.h>
#include <hip/hip_bf16.h>
#include <math.h>

#define L_SEQ 4096
#define CDIM 96
#define DIN 192
#define NST 16
#define XPW 416
#define NCHUNK 64
#define CHLEN 64
#define MROWS 8192

typedef __attribute__((ext_vector_type(8))) short bf16x8;
typedef __attribute__((ext_vector_type(4))) float f32x4;

__device__ __forceinline__ float gelu_exact(float x) {
    return 0.5f * x * (1.0f + erff(x * 0.70710678118654752f));
}

// ---------------- weight convert + transpose: BT[col][k] bf16 ----------------
__global__ __launch_bounds__(256) void cvt_all(
    const float* __restrict__ Wp0, const float* __restrict__ Wp1,
    const float* __restrict__ Wo0, const float* __restrict__ Wo1,
    const float* __restrict__ Wf, const float* __restrict__ W1, const float* __restrict__ W2,
    __hip_bfloat16* __restrict__ wp0T, __hip_bfloat16* __restrict__ wp1T,
    __hip_bfloat16* __restrict__ wo0T, __hip_bfloat16* __restrict__ wo1T,
    __hip_bfloat16* __restrict__ wfT, __hip_bfloat16* __restrict__ w1T,
    __hip_bfloat16* __restrict__ w2T) {
    int i = blockIdx.x * 256 + threadIdx.x;
    const int S_WP = 480 * 96;    // padded cols 416..479 = 0
    const int S_WO = 96 * 192;
    const int S_WF = 96 * 1728;
    const int S_W1 = 384 * 96;
    const int S_W2 = 96 * 384;
    if (i < S_WP) { int c = i / 96, r = i % 96; wp0T[i] = __float2bfloat16(c < 416 ? Wp0[r * 576 + c] : 0.f); return; }
    i -= S_WP;
    if (i < S_WP) { int c = i / 96, r = i % 96; wp1T[i] = __float2bfloat16(c < 416 ? Wp1[r * 576 + c] : 0.f); return; }
    i -= S_WP;
    if (i < S_WO) { int c = i / 192, r = i % 192; wo0T[i] = __float2bfloat16(Wo0[r * 96 + c]); return; }
    i -= S_WO;
    if (i < S_WO) { int c = i / 192, r = i % 192; wo1T[i] = __float2bfloat16(Wo1[r * 96 + c]); return; }
    i -= S_WO;
    if (i < S_WF) { int c = i / 1728, k = i % 1728; wfT[i] = __float2bfloat16(Wf[k * 96 + c]); return; }
    i -= S_WF;
    if (i < S_W1) { int c = i / 96, r = i % 96; w1T[i] = __float2bfloat16(W1[r * 384 + c]); return; }
    i -= S_W1;
    if (i < S_W2) { int c = i / 384, r = i % 384; w2T[i] = __float2bfloat16(W2[r * 96 + c]); return; }
}

// ---------------- LayerNorm over last dim 96, one wave per row ----------------
template <typename OT>
__global__ __launch_bounds__(256) void ln96_kernel(const float* __restrict__ in,
                                                   const float* __restrict__ g,
                                                   const float* __restrict__ b,
                                                   OT* __restrict__ out, int rows) {
    int wave = threadIdx.x >> 6;
    int lane = threadIdx.x & 63;
    int row = blockIdx.x * 4 + wave;
    if (row >= rows) return;
    const float* p = in + (size_t)row * CDIM;
    float x0 = p[lane];
    float x1 = (lane < 32) ? p[64 + lane] : 0.f;
    float s = x0 + x1, sq = x0 * x0 + x1 * x1;
#pragma unroll
    for (int o = 32; o >= 1; o >>= 1) { s += __shfl_xor(s, o); sq += __shfl_xor(sq, o); }
    float mean = s * (1.f / 96.f);
    float var = sq * (1.f / 96.f) - mean * mean;
    float w = rsqrtf(var + 1e-5f);
    OT* q = out + (size_t)row * CDIM;
    q[lane] = (OT)((x0 - mean) * w * g[lane] + b[lane]);
    if (lane < 32) q[64 + lane] = (OT)((x1 - mean) * w * g[64 + lane] + b[64 + lane]);
}

// ---------------- LDS-free direct-fragment MFMA GEMM ----------------
// wave (wm,wn) computes (MI*16) x (NI*16); block = WR x WC waves.
// A[M][lda] row-major bf16; BT[Npad][K] (B transposed) bf16.
// EPI: 0 none, 1 +bias gelu, 2 +bias + f32 residual
template <int MI, int NI, int WR, int WC, int K, int EPI, typename CT>
__global__ __launch_bounds__(WR * WC * 64) void gemm_direct(
    const __hip_bfloat16* __restrict__ A, int lda,
    const __hip_bfloat16* __restrict__ BT,
    CT* __restrict__ C, int ldc, int N,
    const float* __restrict__ bias, const float* __restrict__ res) {
    int tid = threadIdx.x;
    int lane = tid & 63, wid = tid >> 6;
    int wm = wid % WR, wn = wid / WR;
    int m0 = blockIdx.y * (WR * MI * 16) + wm * MI * 16;
    int n0 = blockIdx.x * (WC * NI * 16) + wn * NI * 16;
    int lr = lane & 15, kh = (lane >> 4) * 8;
    f32x4 acc[MI][NI] = {};
    const __hip_bfloat16* Ap = A + (size_t)(m0 + lr) * lda + kh;
    const __hip_bfloat16* Bp = BT + (size_t)(n0 + lr) * K + kh;
#pragma unroll
    for (int k0 = 0; k0 < K; k0 += 32) {
        bf16x8 af[MI], bf[NI];
#pragma unroll
        for (int i = 0; i < MI; ++i)
            af[i] = *reinterpret_cast<const bf16x8*>(Ap + (size_t)i * 16 * lda + k0);
#pragma unroll
        for (int j = 0; j < NI; ++j)
            bf[j] = *reinterpret_cast<const bf16x8*>(Bp + (size_t)j * 16 * K + k0);
#pragma unroll
        for (int i = 0; i < MI; ++i)
#pragma unroll
            for (int j = 0; j < NI; ++j)
                acc[i][j] = __builtin_amdgcn_mfma_f32_16x16x32_bf16(af[i], bf[j], acc[i][j], 0, 0, 0);
    }
    int cr = (lane >> 4) << 2;
#pragma unroll
    for (int i = 0; i < MI; ++i) {
        int row = m0 + i * 16 + cr;
#pragma unroll
        for (int j = 0; j < NI; ++j) {
            int col = n0 + j * 16 + lr;
            if (col < N) {
#pragma unroll
                for (int q = 0; q < 4; ++q) {
                    float v = acc[i][j][q];
                    if (EPI == 1) v = gelu_exact(v + bias[col]);
                    else if (EPI == 2) v = v + bias[col] + res[(size_t)(row + q) * ldc + col];
                    C[(size_t)(row + q) * ldc + col] = (CT)v;
                }
            }
        }
    }
}

// ---------------- 3x3 SAME conv, LDS-free implicit MFMA GEMM ----------------
// block = 32 rows (2 m-waves x 2 n-waves); WfT[96][1728], k = (ky*3+kx)*192+ic
__global__ __launch_bounds__(256) void conv3x3_direct(const __hip_bfloat16* __restrict__ cat,
                                                      const __hip_bfloat16* __restrict__ WfT,
                                                      const float* __restrict__ bfv,
                                                      __hip_bfloat16* __restrict__ out) {
    int tid = threadIdx.x;
    int lane = tid & 63, wid = tid >> 6;
    int wm = wid & 1, wn = wid >> 1;
    int m0 = blockIdx.x * 32 + wm * 16;
    int n0 = wn * 48;
    int lr = lane & 15, kh = (lane >> 4) * 8;
    int m = m0 + lr;
    int bb = m >> 12, l = m & 4095, yy = l >> 6, xx = l & 63;
    f32x4 acc[3] = {};
    const __hip_bfloat16* Bp = WfT + (size_t)(n0 + lr) * 1728 + kh;
#pragma unroll
    for (int ky = 0; ky < 3; ++ky) {
        int iy = yy + ky - 1;
#pragma unroll
        for (int kx = 0; kx < 3; ++kx) {
            int ix = xx + kx - 1;
            bool ok = ((unsigned)iy < 64u) && ((unsigned)ix < 64u);
            const __hip_bfloat16* Ap =
                cat + ((size_t)bb * 4096 + (size_t)(iy * 64 + ix)) * 192 + kh;
            int kbase = (ky * 3 + kx) * 192;
#pragma unroll
            for (int kc = 0; kc < 192; kc += 32) {
                bf16x8 af = {};
                if (ok) af = *reinterpret_cast<const bf16x8*>(Ap + kc);
#pragma unroll
                for (int j = 0; j < 3; ++j) {
                    bf16x8 bf = *reinterpret_cast<const bf16x8*>(Bp + (size_t)j * 16 * 1728 + kbase + kc);
                    acc[j] = __builtin_amdgcn_mfma_f32_16x16x32_bf16(af, bf, acc[j], 0, 0, 0);
                }
            }
        }
    }
    int cr = (lane >> 4) << 2;
    int crow = m0 + cr;
#pragma unroll
    for (int j = 0; j < 3; ++j) {
        int ccol = n0 + j * 16 + lr;
#pragma unroll
        for (int q = 0; q < 4; ++q) {
            float v = gelu_exact(acc[j][q] + bfv[ccol]);
            out[(size_t)(crow + q) * 96 + ccol] = __float2bfloat16(v);
        }
    }
}

// ---------------- depthwise causal conv (k=4) + sigmoid(delta), float4 ----------------
__global__ __launch_bounds__(256) void convsig_kernel(const float* __restrict__ xp,
                                                      const float* __restrict__ cw,
                                                      const float* __restrict__ cb,
                                                      float* __restrict__ xc,
                                                      float* __restrict__ dsg) {
    int idx = blockIdx.x * 256 + threadIdx.x;
    if (idx >= MROWS * 48) return;
    int d4 = idx % 48;
    int row = idx / 48;
    int d = d4 * 4;
    int l = row & (L_SEQ - 1);
    const float4 zero = {0.f, 0.f, 0.f, 0.f};
    float4 c0 = *(const float4*)(xp + (size_t)row * XPW + d);
    float4 p1 = (l >= 1) ? *(const float4*)(xp + (size_t)(row - 1) * XPW + d) : zero;
    float4 p2 = (l >= 2) ? *(const float4*)(xp + (size_t)(row - 2) * XPW + d) : zero;
    float4 p3 = (l >= 3) ? *(const float4*)(xp + (size_t)(row - 3) * XPW + d) : zero;
    float4 dp = *(const float4*)(xp + (size_t)row * XPW + 192 + d);
    float a0[4] = {c0.x, c0.y, c0.z, c0.w};
    float a1[4] = {p1.x, p1.y, p1.z, p1.w};
    float a2[4] = {p2.x, p2.y, p2.z, p2.w};
    float a3[4] = {p3.x, p3.y, p3.z, p3.w};
    float dd[4] = {dp.x, dp.y, dp.z, dp.w};
    float oc[4], od[4];
#pragma unroll
    for (int i = 0; i < 4; ++i) {
        float4 w = *(const float4*)(cw + (size_t)(d + i) * 4);
        oc[i] = cb[d + i] + w.w * a0[i] + w.z * a1[i] + w.y * a2[i] + w.x * a3[i];
        od[i] = 1.f / (1.f + __expf(-dd[i]));
    }
    *(float4*)(xc + (size_t)row * DIN + d) = *(float4*)oc;
    *(float4*)(dsg + (size_t)row * DIN + d) = *(float4*)od;
}

// ---------------- scan pass1: LDS-staged chunk scan; per-(n,d) thread ----------------
__global__ __launch_bounds__(256) void scan_pass1(const float* __restrict__ dsg,
                                                  const float* __restrict__ xc,
                                                  const float* __restrict__ xp,
                                                  const float* __restrict__ A,
                                                  float* __restrict__ Pc,
                                                  float* __restrict__ Hf,
                                                  float* __restrict__ Gb) {
    __shared__ float sd[CHLEN][16], sx[CHLEN][16], sb[CHLEN][16], sA[256];
    int bid = blockIdx.x;
    int dg = bid % 12;
    int c = (bid / 12) % NCHUNK;
    int b = bid / (12 * NCHUNK);
    int tid = threadIdx.x;
    sA[tid] = A[tid];
    {
        int r = tid >> 2, q = (tid & 3) * 4;
        size_t grow = (size_t)b * L_SEQ + c * CHLEN + r;
        *(float4*)&sd[r][q] = *(const float4*)(dsg + grow * DIN + dg * 16 + q);
        *(float4*)&sx[r][q] = *(const float4*)(xc + grow * DIN + dg * 16 + q);
        *(float4*)&sb[r][q] = *(const float4*)(xp + grow * XPW + 384 + q);
    }
    __syncthreads();
    int n = tid & 15, drow = tid >> 4;
    float asum = 0.f;
#pragma unroll
    for (int j = 0; j < 16; ++j) asum += sA[n * 16 + j];
    float h = 0.f, gb = 0.f, Q = 1.f;
    for (int t = 0; t < CHLEN; ++t) {
        float dl = sd[t][drow];
        float xv = sx[t][drow];
        float bm = sb[t][n];
        float a = __expf(dl * asum);
        float bu = dl * xv * bm;
        h = a * h + bu;
        gb += Q * bu;
        Q *= a;
    }
    size_t cidx = (((size_t)b * NCHUNK + c) * NST + n) * DIN + dg * 16 + drow;
    Pc[cidx] = Q;
    Hf[cidx] = h;
    Gb[cidx] = gb;
}

// ---------------- scan pass2: combine chunk carries sequentially ----------------
__global__ __launch_bounds__(256) void scan_pass2(const float* __restrict__ Pc,
                                                  const float* __restrict__ Hf,
                                                  const float* __restrict__ Gb,
                                                  float* __restrict__ Hinf,
                                                  float* __restrict__ Hinb) {
    int t = blockIdx.x * blockDim.x + threadIdx.x;
    if (t >= 2 * NST * DIN) return;
    int d = t % DIN;
    int n = (t / DIN) % NST;
    int b = t / (DIN * NST);
    float hin = 0.f;
    for (int c = 0; c < NCHUNK; ++c) {
        size_t idx = (((size_t)b * NCHUNK + c) * NST + n) * DIN + d;
        Hinf[idx] = hin;
        hin = Hf[idx] + Pc[idx] * hin;
    }
    float gin = 0.f;
    for (int c = NCHUNK - 1; c >= 0; --c) {
        size_t idx = (((size_t)b * NCHUNK + c) * NST + n) * DIN + d;
        Hinb[idx] = gin;
        gin = Gb[idx] + Pc[idx] * gin;
    }
}

// ---------------- scan pass3: LDS-staged re-scan with carries, fused y ----------------
__global__ __launch_bounds__(256) void scan_pass3(const float* __restrict__ dsg,
                                                  const float* __restrict__ xc,
                                                  const float* __restrict__ xp,
                                                  const float* __restrict__ A,
                                                  const float* __restrict__ Hinf,
                                                  const float* __restrict__ Hinb,
                                                  const float* __restrict__ Dp,
                                                  __hip_bfloat16* __restrict__ y) {
    __shared__ float sd[CHLEN][16], sx[CHLEN][16], sb[CHLEN][16], sc[CHLEN][16];
    __shared__ float ys[CHLEN * 16], sA[256];
    int bid = blockIdx.x;
    int dg = bid % 12;
    int c = (bid / 12) % NCHUNK;
    int b = bid / (12 * NCHUNK);
    int tid = threadIdx.x;
    sA[tid] = A[tid];
    {
        int r = tid >> 2, q = (tid & 3) * 4;
        size_t grow = (size_t)b * L_SEQ + c * CHLEN + r;
        *(float4*)&sd[r][q] = *(const float4*)(dsg + grow * DIN + dg * 16 + q);
        *(float4*)&sx[r][q] = *(const float4*)(xc + grow * DIN + dg * 16 + q);
        *(float4*)&sb[r][q] = *(const float4*)(xp + grow * XPW + 384 + q);
        *(float4*)&sc[r][q] = *(const float4*)(xp + grow * XPW + 400 + q);
    }
    __syncthreads();
    int lane = tid & 63, wave = tid >> 6;
    int n = lane & 15;
    int dloc = wave * 4 + (lane >> 4);
    int d = dg * 16 + dloc;
    float asum = 0.f;
#pragma unroll
    for (int j = 0; j < 16; ++j) asum += sA[n * 16 + j];
    size_t cidx = (((size_t)b * NCHUNK + c) * NST + n) * DIN + d;
    float h = Hinf[cidx];
    for (int t = 0; t < CHLEN; ++t) {
        float dl = sd[t][dloc];
        float xv = sx[t][dloc];
        float a = __expf(dl * asum);
        float bu = dl * xv * sb[t][n];
        h = a * h + bu;
        float p = sc[t][n] * h;
        p += __shfl_xor(p, 1);
        p += __shfl_xor(p, 2);
        p += __shfl_xor(p, 4);
        p += __shfl_xor(p, 8);
        if (n == 0) ys[t * 16 + dloc] = p;
    }
    float gv = Hinb[cidx];
    for (int t = CHLEN - 1; t >= 0; --t) {
        float dl = sd[t][dloc];
        float xv = sx[t][dloc];
        float a = __expf(dl * asum);
        float bu = dl * xv * sb[t][n];
        gv = a * gv + bu;
        float p = sc[t][n] * gv;
        p += __shfl_xor(p, 1);
        p += __shfl_xor(p, 2);
        p += __shfl_xor(p, 4);
        p += __shfl_xor(p, 8);
        if (n == 0) ys[t * 16 + dloc] += p;
    }
    __syncthreads();
#pragma unroll
    for (int i = 0; i < 4; ++i) {
        int sidx = tid + i * 256;
        int tl = sidx >> 4;
        int dl2 = sidx & 15;
        int d2 = dg * 16 + dl2;
        size_t row = (size_t)b * L_SEQ + c * CHLEN + tl;
        y[row * DIN + d2] = __float2bfloat16(ys[sidx] + Dp[d2] * sx[tl][dl2]);
    }
}

// ---------------- cosine-sim fusion: cat = [f1, sim*f1 + (1-sim)*f2] (bf16 out) ----------------
__global__ __launch_bounds__(256) void fuse_kernel(const float* __restrict__ f1,
                                                   const float* __restrict__ f2,
                                                   __hip_bfloat16* __restrict__ cat, int rows) {
    int wave = threadIdx.x >> 6;
    int lane = threadIdx.x & 63;
    int row = blockIdx.x * 4 + wave;
    if (row >= rows) return;
    const float* p1 = f1 + (size_t)row * CDIM;
    const float* p2 = f2 + (size_t)row * CDIM;
    float a0 = p1[lane], b0 = p2[lane];
    float a1 = 0.f, b1 = 0.f;
    if (lane < 32) { a1 = p1[64 + lane]; b1 = p2[64 + lane]; }
    float s11 = a0 * a0 + a1 * a1;
    float s22 = b0 * b0 + b1 * b1;
    float s12 = a0 * b0 + a1 * b1;
#pragma unroll
    for (int o = 32; o >= 1; o >>= 1) {
        s11 += __shfl_xor(s11, o);
        s22 += __shfl_xor(s22, o);
        s12 += __shfl_xor(s12, o);
    }
    float nr1 = fmaxf(sqrtf(s11), 1e-12f);
    float nr2 = fmaxf(sqrtf(s22), 1e-12f);
    float sim = s12 / (nr1 * nr2);
    __hip_bfloat16* q = cat + (size_t)row * 192;
    q[lane] = __float2bfloat16(a0);
    q[96 + lane] = __float2bfloat16(sim * a0 + (1.f - sim) * b0);
    if (lane < 32) {
        q[64 + lane] = __float2bfloat16(a1);
        q[96 + 64 + lane] = __float2bfloat16(sim * a1 + (1.f - sim) * b1);
    }
}

extern "C" void kernel_launch(void* const* d_in, const int* in_sizes, int n_in,
                              void* d_out, int out_size, void* d_ws, size_t ws_size,
                              hipStream_t stream) {
    const float* x = (const float*)d_in[0];
    const float* norm_g = (const float*)d_in[1];
    const float* norm_b = (const float*)d_in[2];
    const float* Wp[2] = {(const float*)d_in[3], (const float*)d_in[11]};
    const float* cw[2] = {(const float*)d_in[4], (const float*)d_in[12]};
    const float* cb[2] = {(const float*)d_in[5], (const float*)d_in[13]};
    const float* Ab[2] = {(const float*)d_in[6], (const float*)d_in[14]};
    const float* Dpb[2] = {(const float*)d_in[7], (const float*)d_in[15]};
    const float* Wo[2] = {(const float*)d_in[8], (const float*)d_in[16]};
    const float* lng[2] = {(const float*)d_in[9], (const float*)d_in[17]};
    const float* lnb[2] = {(const float*)d_in[10], (const float*)d_in[18]};
    const float* Wf = (const float*)d_in[19];
    const float* bfv = (const float*)d_in[20];
    const float* W1 = (const float*)d_in[21];
    const float* b1 = (const float*)d_in[22];
    const float* W2 = (const float*)d_in[23];
    const float* b2 = (const float*)d_in[24];
    float* out = (float*)d_out;

    char* base = (char*)d_ws;
    size_t off = 0;
    auto alloc = [&](size_t bytes) { void* p = base + off; off += (bytes + 255) & ~(size_t)255; return p; };
    float* xp = (float*)alloc((size_t)MROWS * XPW * 4);
    float* xcb = (float*)alloc((size_t)MROWS * DIN * 4);
    float* dsg = (float*)alloc((size_t)MROWS * DIN * 4);
    float* tmp96 = (float*)alloc((size_t)MROWS * 96 * 4);
    float* f1 = (float*)alloc((size_t)MROWS * 96 * 4);
    float* f2 = (float*)alloc((size_t)MROWS * 96 * 4);
    const size_t csz = (size_t)2 * NCHUNK * NST * DIN;
    float* Pc = (float*)alloc(csz * 4);
    float* Hfc = (float*)alloc(csz * 4);
    float* Gbc = (float*)alloc(csz * 4);
    float* Hinf = (float*)alloc(csz * 4);
    float* Hinb = (float*)alloc(csz * 4);
    __hip_bfloat16* xn_bf = (__hip_bfloat16*)alloc((size_t)MROWS * 96 * 2);
    __hip_bfloat16* yb_bf = (__hip_bfloat16*)alloc((size_t)MROWS * DIN * 2);
    __hip_bfloat16* cat_bf = (__hip_bfloat16*)alloc((size_t)MROWS * DIN * 2);
    __hip_bfloat16* fc_bf = (__hip_bfloat16*)alloc((size_t)MROWS * 96 * 2);
    __hip_bfloat16* h1_bf = (__hip_bfloat16*)alloc((size_t)MROWS * 384 * 2);
    __hip_bfloat16* wpT[2] = {(__hip_bfloat16*)alloc(480 * 96 * 2),
                              (__hip_bfloat16*)alloc(480 * 96 * 2)};
    __hip_bfloat16* woT[2] = {(__hip_bfloat16*)alloc(96 * 192 * 2),
                              (__hip_bfloat16*)alloc(96 * 192 * 2)};
    __hip_bfloat16* wfT = (__hip_bfloat16*)alloc(96 * 1728 * 2);
    __hip_bfloat16* w1T = (__hip_bfloat16*)alloc(384 * 96 * 2);
    __hip_bfloat16* w2T = (__hip_bfloat16*)alloc(96 * 384 * 2);
    (void)ws_size; (void)in_sizes; (void)n_in; (void)out_size;

    // weight convert + transpose (one launch)
    cvt_all<<<dim3(1440), dim3(256), 0, stream>>>(Wp[0], Wp[1], Wo[0], Wo[1], Wf, W1, W2,
                                                  wpT[0], wpT[1], woT[0], woT[1], wfT, w1T, w2T);

    // input LayerNorm -> bf16
    ln96_kernel<__hip_bfloat16><<<dim3(2048), dim3(256), 0, stream>>>(x, norm_g, norm_b, xn_bf, MROWS);

    float* fouts[2] = {f1, f2};
    for (int p = 0; p < 2; ++p) {
        // xp = xn @ Wp[:, :416]  (M=8192, N=416->480, K=96)
        gemm_direct<2, 3, 2, 2, 96, 0, float><<<dim3(5, 128), dim3(256), 0, stream>>>(
            xn_bf, 96, wpT[p], xp, XPW, XPW, nullptr, nullptr);
        convsig_kernel<<<dim3(1536), dim3(256), 0, stream>>>(xp, cw[p], cb[p], xcb, dsg);
        scan_pass1<<<dim3(2 * NCHUNK * 12), dim3(256), 0, stream>>>(dsg, xcb, xp, Ab[p], Pc, Hfc, Gbc);
        scan_pass2<<<dim3(24), dim3(256), 0, stream>>>(Pc, Hfc, Gbc, Hinf, Hinb);
        scan_pass3<<<dim3(2 * NCHUNK * 12), dim3(256), 0, stream>>>(dsg, xcb, xp, Ab[p], Hinf, Hinb,
                                                                    Dpb[p], yb_bf);
        // f_pre = y @ Wo (M=8192, N=96, K=192)
        gemm_direct<1, 3, 2, 2, 192, 0, float><<<dim3(1, 256), dim3(256), 0, stream>>>(
            yb_bf, DIN, woT[p], tmp96, 96, 96, nullptr, nullptr);
        ln96_kernel<float><<<dim3(2048), dim3(256), 0, stream>>>(tmp96, lng[p], lnb[p], fouts[p], MROWS);
    }

    fuse_kernel<<<dim3(2048), dim3(256), 0, stream>>>(f1, f2, cat_bf, MROWS);
    // fc = gelu(conv3x3(cat) + bf)
    conv3x3_direct<<<dim3(256), dim3(256), 0, stream>>>(cat_bf, wfT, bfv, fc_bf);
    // h1 = gelu(fc @ W1 + b1)  (N=384, K=96)
    gemm_direct<2, 3, 2, 2, 96, 1, __hip_bfloat16><<<dim3(4, 128), dim3(256), 0, stream>>>(
        fc_bf, 96, w1T, h1_bf, 384, 384, b1, nullptr);
    // out = h1 @ W2 + b2 + res  (N=96, K=384)
    gemm_direct<1, 3, 2, 2, 384, 2, float><<<dim3(1, 256), dim3(256), 0, stream>>>(
        h1_bf, 384, w2T, out, 96, 96, b2, x);
}

// Round 5
// 234.815 us; speedup vs baseline: 2.7802x; 1.2660x over previous
//
#include <hip/hip_runtime.h>
#include <hip/hip_bf16.h>
#include <math.h>

#define L_SEQ 4096
#define CDIM 96
#define DIN 192
#define NST 16
#define XPW 416
#define NCHUNK 64
#define CHLEN 64
#define MROWS 8192

typedef __attribute__((ext_vector_type(8))) short bf16x8;
typedef __attribute__((ext_vector_type(4))) float f32x4;
typedef __attribute__((ext_vector_type(4))) short s16x4;

__device__ __forceinline__ float gelu_exact(float x) {
    return 0.5f * x * (1.0f + erff(x * 0.70710678118654752f));
}

__device__ __forceinline__ float fast_exp2(float x) {
#if __has_builtin(__builtin_amdgcn_exp2f)
    return __builtin_amdgcn_exp2f(x);
#else
    return exp2f(x);
#endif
}

// sum across the 16 lanes of each DPP row (n = lane&15) using row_ror adds (VALU, no DS pipe)
__device__ __forceinline__ float rowsum16(float s) {
    s += __int_as_float(__builtin_amdgcn_update_dpp(0, __float_as_int(s), 0x128, 0xF, 0xF, false));
    s += __int_as_float(__builtin_amdgcn_update_dpp(0, __float_as_int(s), 0x124, 0xF, 0xF, false));
    s += __int_as_float(__builtin_amdgcn_update_dpp(0, __float_as_int(s), 0x122, 0xF, 0xF, false));
    s += __int_as_float(__builtin_amdgcn_update_dpp(0, __float_as_int(s), 0x121, 0xF, 0xF, false));
    return s;
}

__device__ __forceinline__ unsigned short f2bf_bits(float f) {
    __hip_bfloat16 h = __float2bfloat16(f);
    return *reinterpret_cast<unsigned short*>(&h);
}

// ---------------- weight convert + transpose: BT[col][k] bf16 ----------------
__global__ __launch_bounds__(256) void cvt_all(
    const float* __restrict__ Wp0, const float* __restrict__ Wp1,
    const float* __restrict__ Wo0, const float* __restrict__ Wo1,
    const float* __restrict__ Wf, const float* __restrict__ W1, const float* __restrict__ W2,
    __hip_bfloat16* __restrict__ wp0T, __hip_bfloat16* __restrict__ wp1T,
    __hip_bfloat16* __restrict__ wo0T, __hip_bfloat16* __restrict__ wo1T,
    __hip_bfloat16* __restrict__ wfT, __hip_bfloat16* __restrict__ w1T,
    __hip_bfloat16* __restrict__ w2T) {
    int i = blockIdx.x * 256 + threadIdx.x;
    const int S_WP = 480 * 96;
    const int S_WO = 96 * 192;
    const int S_WF = 96 * 1728;
    const int S_W1 = 384 * 96;
    const int S_W2 = 96 * 384;
    if (i < S_WP) { int c = i / 96, r = i % 96; wp0T[i] = __float2bfloat16(c < 416 ? Wp0[r * 576 + c] : 0.f); return; }
    i -= S_WP;
    if (i < S_WP) { int c = i / 96, r = i % 96; wp1T[i] = __float2bfloat16(c < 416 ? Wp1[r * 576 + c] : 0.f); return; }
    i -= S_WP;
    if (i < S_WO) { int c = i / 192, r = i % 192; wo0T[i] = __float2bfloat16(Wo0[r * 96 + c]); return; }
    i -= S_WO;
    if (i < S_WO) { int c = i / 192, r = i % 192; wo1T[i] = __float2bfloat16(Wo1[r * 96 + c]); return; }
    i -= S_WO;
    if (i < S_WF) { int c = i / 1728, k = i % 1728; wfT[i] = __float2bfloat16(Wf[k * 96 + c]); return; }
    i -= S_WF;
    if (i < S_W1) { int c = i / 96, r = i % 96; w1T[i] = __float2bfloat16(W1[r * 384 + c]); return; }
    i -= S_W1;
    if (i < S_W2) { int c = i / 384, r = i % 384; w2T[i] = __float2bfloat16(W2[r * 96 + c]); return; }
}

// ---------------- LayerNorm over last dim 96, one wave per row ----------------
template <typename OT>
__global__ __launch_bounds__(256) void ln96_kernel(const float* __restrict__ in,
                                                   const float* __restrict__ g,
                                                   const float* __restrict__ b,
                                                   OT* __restrict__ out, int rows) {
    int wave = threadIdx.x >> 6;
    int lane = threadIdx.x & 63;
    int row = blockIdx.x * 4 + wave;
    if (row >= rows) return;
    const float* p = in + (size_t)row * CDIM;
    float x0 = p[lane];
    float x1 = (lane < 32) ? p[64 + lane] : 0.f;
    float s = x0 + x1, sq = x0 * x0 + x1 * x1;
#pragma unroll
    for (int o = 32; o >= 1; o >>= 1) { s += __shfl_xor(s, o); sq += __shfl_xor(sq, o); }
    float mean = s * (1.f / 96.f);
    float var = sq * (1.f / 96.f) - mean * mean;
    float w = rsqrtf(var + 1e-5f);
    OT* q = out + (size_t)row * CDIM;
    q[lane] = (OT)((x0 - mean) * w * g[lane] + b[lane]);
    if (lane < 32) q[64 + lane] = (OT)((x1 - mean) * w * g[64 + lane] + b[64 + lane]);
}

// ---------------- LDS-free direct-fragment MFMA GEMM ----------------
template <int MI, int NI, int WR, int WC, int K, int EPI, typename CT>
__global__ __launch_bounds__(WR * WC * 64) void gemm_direct(
    const __hip_bfloat16* __restrict__ A, int lda,
    const __hip_bfloat16* __restrict__ BT,
    CT* __restrict__ C, int ldc, int N,
    const float* __restrict__ bias, const float* __restrict__ res) {
    int tid = threadIdx.x;
    int lane = tid & 63, wid = tid >> 6;
    int wm = wid % WR, wn = wid / WR;
    int m0 = blockIdx.y * (WR * MI * 16) + wm * MI * 16;
    int n0 = blockIdx.x * (WC * NI * 16) + wn * NI * 16;
    int lr = lane & 15, kh = (lane >> 4) * 8;
    f32x4 acc[MI][NI] = {};
    const __hip_bfloat16* Ap = A + (size_t)(m0 + lr) * lda + kh;
    const __hip_bfloat16* Bp = BT + (size_t)(n0 + lr) * K + kh;
#pragma unroll
    for (int k0 = 0; k0 < K; k0 += 32) {
        bf16x8 af[MI], bf[NI];
#pragma unroll
        for (int i = 0; i < MI; ++i)
            af[i] = *reinterpret_cast<const bf16x8*>(Ap + (size_t)i * 16 * lda + k0);
#pragma unroll
        for (int j = 0; j < NI; ++j)
            bf[j] = *reinterpret_cast<const bf16x8*>(Bp + (size_t)j * 16 * K + k0);
#pragma unroll
        for (int i = 0; i < MI; ++i)
#pragma unroll
            for (int j = 0; j < NI; ++j)
                acc[i][j] = __builtin_amdgcn_mfma_f32_16x16x32_bf16(af[i], bf[j], acc[i][j], 0, 0, 0);
    }
    int cr = (lane >> 4) << 2;
#pragma unroll
    for (int i = 0; i < MI; ++i) {
        int row = m0 + i * 16 + cr;
#pragma unroll
        for (int j = 0; j < NI; ++j) {
            int col = n0 + j * 16 + lr;
            if (col < N) {
#pragma unroll
                for (int q = 0; q < 4; ++q) {
                    float v = acc[i][j][q];
                    if (EPI == 1) v = gelu_exact(v + bias[col]);
                    else if (EPI == 2) v = v + bias[col] + res[(size_t)(row + q) * ldc + col];
                    C[(size_t)(row + q) * ldc + col] = (CT)v;
                }
            }
        }
    }
}

// ---------------- 3x3 SAME conv, LDS-free implicit MFMA GEMM ----------------
__global__ __launch_bounds__(256) void conv3x3_direct(const __hip_bfloat16* __restrict__ cat,
                                                      const __hip_bfloat16* __restrict__ WfT,
                                                      const float* __restrict__ bfv,
                                                      __hip_bfloat16* __restrict__ out) {
    int tid = threadIdx.x;
    int lane = tid & 63, wid = tid >> 6;
    int wm = wid & 1, wn = wid >> 1;
    int m0 = blockIdx.x * 32 + wm * 16;
    int n0 = wn * 48;
    int lr = lane & 15, kh = (lane >> 4) * 8;
    int m = m0 + lr;
    int bb = m >> 12, l = m & 4095, yy = l >> 6, xx = l & 63;
    f32x4 acc[3] = {};
    const __hip_bfloat16* Bp = WfT + (size_t)(n0 + lr) * 1728 + kh;
#pragma unroll
    for (int ky = 0; ky < 3; ++ky) {
        int iy = yy + ky - 1;
#pragma unroll
        for (int kx = 0; kx < 3; ++kx) {
            int ix = xx + kx - 1;
            bool ok = ((unsigned)iy < 64u) && ((unsigned)ix < 64u);
            const __hip_bfloat16* Ap =
                cat + ((size_t)bb * 4096 + (size_t)(iy * 64 + ix)) * 192 + kh;
            int kbase = (ky * 3 + kx) * 192;
#pragma unroll
            for (int kc = 0; kc < 192; kc += 32) {
                bf16x8 af = {};
                if (ok) af = *reinterpret_cast<const bf16x8*>(Ap + kc);
#pragma unroll
                for (int j = 0; j < 3; ++j) {
                    bf16x8 bf = *reinterpret_cast<const bf16x8*>(Bp + (size_t)j * 16 * 1728 + kbase + kc);
                    acc[j] = __builtin_amdgcn_mfma_f32_16x16x32_bf16(af, bf, acc[j], 0, 0, 0);
                }
            }
        }
    }
    int cr = (lane >> 4) << 2;
    int crow = m0 + cr;
#pragma unroll
    for (int j = 0; j < 3; ++j) {
        int ccol = n0 + j * 16 + lr;
#pragma unroll
        for (int q = 0; q < 4; ++q) {
            float v = gelu_exact(acc[j][q] + bfv[ccol]);
            out[(size_t)(crow + q) * 96 + ccol] = __float2bfloat16(v);
        }
    }
}

// ---------------- depthwise causal conv (k=4) + sigmoid(delta), float4 ----------------
__global__ __launch_bounds__(256) void convsig_kernel(const float* __restrict__ xp,
                                                      const float* __restrict__ cw,
                                                      const float* __restrict__ cb,
                                                      float* __restrict__ xc,
                                                      float* __restrict__ dsg) {
    int idx = blockIdx.x * 256 + threadIdx.x;
    if (idx >= MROWS * 48) return;
    int d4 = idx % 48;
    int row = idx / 48;
    int d = d4 * 4;
    int l = row & (L_SEQ - 1);
    const float4 zero = {0.f, 0.f, 0.f, 0.f};
    float4 c0 = *(const float4*)(xp + (size_t)row * XPW + d);
    float4 p1 = (l >= 1) ? *(const float4*)(xp + (size_t)(row - 1) * XPW + d) : zero;
    float4 p2 = (l >= 2) ? *(const float4*)(xp + (size_t)(row - 2) * XPW + d) : zero;
    float4 p3 = (l >= 3) ? *(const float4*)(xp + (size_t)(row - 3) * XPW + d) : zero;
    float4 dp = *(const float4*)(xp + (size_t)row * XPW + 192 + d);
    float a0[4] = {c0.x, c0.y, c0.z, c0.w};
    float a1[4] = {p1.x, p1.y, p1.z, p1.w};
    float a2[4] = {p2.x, p2.y, p2.z, p2.w};
    float a3[4] = {p3.x, p3.y, p3.z, p3.w};
    float dd[4] = {dp.x, dp.y, dp.z, dp.w};
    float oc[4], od[4];
#pragma unroll
    for (int i = 0; i < 4; ++i) {
        float4 w = *(const float4*)(cw + (size_t)(d + i) * 4);
        oc[i] = cb[d + i] + w.w * a0[i] + w.z * a1[i] + w.y * a2[i] + w.x * a3[i];
        od[i] = 1.f / (1.f + __expf(-dd[i]));
    }
    *(float4*)(xc + (size_t)row * DIN + d) = *(float4*)oc;
    *(float4*)(dsg + (size_t)row * DIN + d) = *(float4*)od;
}

// ---------------- scan pass1: LDS-staged chunk scan (packed float2 reads) ----------------
// block = (b, c, dg); 256 threads = 16 n x 16 d. Outputs chunk-last layout [b][n][d][c].
__global__ __launch_bounds__(256) void scan_pass1(const float* __restrict__ dsg,
                                                  const float* __restrict__ xc,
                                                  const float* __restrict__ xp,
                                                  const float* __restrict__ A,
                                                  float* __restrict__ Pc,
                                                  float* __restrict__ Hf,
                                                  float* __restrict__ Gb) {
    __shared__ float2 sdx[CHLEN][16];
    __shared__ float sb[CHLEN][16];
    __shared__ float sA[256];
    int bid = blockIdx.x;
    int dg = bid % 12;
    int c = (bid / 12) % NCHUNK;
    int b = bid / (12 * NCHUNK);
    int tid = threadIdx.x;
    sA[tid] = A[tid];
    {
        int r = tid >> 2, q = (tid & 3) * 4;
        size_t grow = (size_t)b * L_SEQ + c * CHLEN + r;
        float4 dv = *(const float4*)(dsg + grow * DIN + dg * 16 + q);
        float4 xv = *(const float4*)(xc + grow * DIN + dg * 16 + q);
        float4 w1 = {dv.x, xv.x, dv.y, xv.y};
        float4 w2 = {dv.z, xv.z, dv.w, xv.w};
        *(float4*)&sdx[r][q] = w1;
        *(float4*)&sdx[r][q + 2] = w2;
        *(float4*)&sb[r][q] = *(const float4*)(xp + grow * XPW + 384 + q);
    }
    __syncthreads();
    int n = tid & 15, drow = tid >> 4;
    float asum = 0.f;
#pragma unroll
    for (int j = 0; j < 16; ++j) asum += sA[n * 16 + j];
    float asum2 = asum * 1.44269504f;
    float h = 0.f, gb = 0.f, Q = 1.f;
    for (int t = 0; t < CHLEN; ++t) {
        float2 dx = sdx[t][drow];
        float bm = sb[t][n];
        float a = fast_exp2(dx.x * asum2);
        float bu = dx.x * dx.y * bm;
        h = a * h + bu;
        gb += Q * bu;
        Q *= a;
    }
    size_t cidx = (((size_t)b * NST + n) * DIN + dg * 16 + drow) * NCHUNK + c;
    Pc[cidx] = Q;
    Hf[cidx] = h;
    Gb[cidx] = gb;
}

// ---------------- scan pass2: combine chunk carries (contiguous float4 loads) ----------------
__global__ __launch_bounds__(256) void scan_pass2(const float* __restrict__ Pc,
                                                  const float* __restrict__ Hf,
                                                  const float* __restrict__ Gb,
                                                  float* __restrict__ Hinf,
                                                  float* __restrict__ Hinb) {
    int t = blockIdx.x * 256 + threadIdx.x;
    if (t >= 2 * NST * DIN) return;
    size_t base = (size_t)t * NCHUNK;
    {
        float4 P4[16], H4[16];
        const float4* Pp = (const float4*)(Pc + base);
        const float4* Hp = (const float4*)(Hf + base);
#pragma unroll
        for (int i = 0; i < 16; ++i) { P4[i] = Pp[i]; H4[i] = Hp[i]; }
        float hin = 0.f;
        float4* Op = (float4*)(Hinf + base);
#pragma unroll
        for (int i = 0; i < 16; ++i) {
            float4 o;
            o.x = hin; hin = H4[i].x + P4[i].x * hin;
            o.y = hin; hin = H4[i].y + P4[i].y * hin;
            o.z = hin; hin = H4[i].z + P4[i].z * hin;
            o.w = hin; hin = H4[i].w + P4[i].w * hin;
            Op[i] = o;
        }
    }
    {
        float4 P4[16], G4[16];
        const float4* Pp = (const float4*)(Pc + base);
        const float4* Gp = (const float4*)(Gb + base);
#pragma unroll
        for (int i = 0; i < 16; ++i) { P4[i] = Pp[i]; G4[i] = Gp[i]; }
        float gin = 0.f;
        float4* Op = (float4*)(Hinb + base);
#pragma unroll
        for (int i = 15; i >= 0; --i) {
            float4 o;
            o.w = gin; gin = G4[i].w + P4[i].w * gin;
            o.z = gin; gin = G4[i].z + P4[i].z * gin;
            o.y = gin; gin = G4[i].y + P4[i].y * gin;
            o.x = gin; gin = G4[i].x + P4[i].x * gin;
            Op[i] = o;
        }
    }
}

// ---------------- scan pass3: fused fwd+bwd re-scan, DPP row reduction, fused y ----------------
// block = (b, c, dg); 4 waves, each wave: 16 n x 4 d (n = lane&15 aligns with DPP rows)
__global__ __launch_bounds__(256) void scan_pass3(const float* __restrict__ dsg,
                                                  const float* __restrict__ xc,
                                                  const float* __restrict__ xp,
                                                  const float* __restrict__ A,
                                                  const float* __restrict__ Hinf,
                                                  const float* __restrict__ Hinb,
                                                  const float* __restrict__ Dp,
                                                  __hip_bfloat16* __restrict__ y) {
    __shared__ float2 sdx[CHLEN][16];   // (dsg, xc) per (t, dloc)
    __shared__ float2 sbc[CHLEN][16];   // (Bm, Cm) per (t, n)
    __shared__ float ysf[CHLEN][16], ysb[CHLEN][16];
    __shared__ float sA[256];
    int bid = blockIdx.x;
    int dg = bid % 12;
    int c = (bid / 12) % NCHUNK;
    int b = bid / (12 * NCHUNK);
    int tid = threadIdx.x;
    sA[tid] = A[tid];
    {
        int r = tid >> 2, q = (tid & 3) * 4;
        size_t grow = (size_t)b * L_SEQ + c * CHLEN + r;
        float4 dv = *(const float4*)(dsg + grow * DIN + dg * 16 + q);
        float4 xv = *(const float4*)(xc + grow * DIN + dg * 16 + q);
        float4 w1 = {dv.x, xv.x, dv.y, xv.y};
        float4 w2 = {dv.z, xv.z, dv.w, xv.w};
        *(float4*)&sdx[r][q] = w1;
        *(float4*)&sdx[r][q + 2] = w2;
        float4 bv = *(const float4*)(xp + grow * XPW + 384 + q);
        float4 cv = *(const float4*)(xp + grow * XPW + 400 + q);
        float4 u1 = {bv.x, cv.x, bv.y, cv.y};
        float4 u2 = {bv.z, cv.z, bv.w, cv.w};
        *(float4*)&sbc[r][q] = u1;
        *(float4*)&sbc[r][q + 2] = u2;
    }
    __syncthreads();
    int lane = tid & 63, wave = tid >> 6;
    int n = lane & 15;
    int dloc = wave * 4 + (lane >> 4);
    int d = dg * 16 + dloc;
    float asum = 0.f;
#pragma unroll
    for (int j = 0; j < 16; ++j) asum += sA[n * 16 + j];
    float asum2 = asum * 1.44269504f;
    size_t cidx = (((size_t)b * NST + n) * DIN + d) * NCHUNK + c;
    float h = Hinf[cidx];
    float gv = Hinb[cidx];
    for (int t = 0; t < CHLEN; ++t) {
        int tb = CHLEN - 1 - t;
        float2 dxf = sdx[t][dloc];
        float2 bcf = sbc[t][n];
        float2 dxb = sdx[tb][dloc];
        float2 bcb = sbc[tb][n];
        float af = fast_exp2(dxf.x * asum2);
        float buf_ = dxf.x * dxf.y * bcf.x;
        h = af * h + buf_;
        float pf = rowsum16(bcf.y * h);
        float ab = fast_exp2(dxb.x * asum2);
        float bub_ = dxb.x * dxb.y * bcb.x;
        gv = ab * gv + bub_;
        float pb = rowsum16(bcb.y * gv);
        if (n == 0) {
            ysf[t][dloc] = pf;
            ysb[tb][dloc] = pb;
        }
    }
    __syncthreads();
    {
        int tl = tid >> 2, q = (tid & 3) * 4;
        int d2 = dg * 16 + q;
        float4 Dv = *(const float4*)(Dp + d2);
        float vs[4];
#pragma unroll
        for (int i = 0; i < 4; ++i)
            vs[i] = ysf[tl][q + i] + ysb[tl][q + i] + ((const float*)&Dv)[i] * sdx[tl][q + i].y;
        s16x4 pk = {(short)f2bf_bits(vs[0]), (short)f2bf_bits(vs[1]),
                    (short)f2bf_bits(vs[2]), (short)f2bf_bits(vs[3])};
        size_t row = (size_t)b * L_SEQ + c * CHLEN + tl;
        *(s16x4*)((unsigned short*)y + row * DIN + d2) = pk;
    }
}

// ---------------- cosine-sim fusion: cat = [f1, sim*f1 + (1-sim)*f2] (bf16 out) ----------------
__global__ __launch_bounds__(256) void fuse_kernel(const float* __restrict__ f1,
                                                   const float* __restrict__ f2,
                                                   __hip_bfloat16* __restrict__ cat, int rows) {
    int wave = threadIdx.x >> 6;
    int lane = threadIdx.x & 63;
    int row = blockIdx.x * 4 + wave;
    if (row >= rows) return;
    const float* p1 = f1 + (size_t)row * CDIM;
    const float* p2 = f2 + (size_t)row * CDIM;
    float a0 = p1[lane], b0 = p2[lane];
    float a1 = 0.f, b1 = 0.f;
    if (lane < 32) { a1 = p1[64 + lane]; b1 = p2[64 + lane]; }
    float s11 = a0 * a0 + a1 * a1;
    float s22 = b0 * b0 + b1 * b1;
    float s12 = a0 * b0 + a1 * b1;
#pragma unroll
    for (int o = 32; o >= 1; o >>= 1) {
        s11 += __shfl_xor(s11, o);
        s22 += __shfl_xor(s22, o);
        s12 += __shfl_xor(s12, o);
    }
    float nr1 = fmaxf(sqrtf(s11), 1e-12f);
    float nr2 = fmaxf(sqrtf(s22), 1e-12f);
    float sim = s12 / (nr1 * nr2);
    __hip_bfloat16* q = cat + (size_t)row * 192;
    q[lane] = __float2bfloat16(a0);
    q[96 + lane] = __float2bfloat16(sim * a0 + (1.f - sim) * b0);
    if (lane < 32) {
        q[64 + lane] = __float2bfloat16(a1);
        q[96 + 64 + lane] = __float2bfloat16(sim * a1 + (1.f - sim) * b1);
    }
}

extern "C" void kernel_launch(void* const* d_in, const int* in_sizes, int n_in,
                              void* d_out, int out_size, void* d_ws, size_t ws_size,
                              hipStream_t stream) {
    const float* x = (const float*)d_in[0];
    const float* norm_g = (const float*)d_in[1];
    const float* norm_b = (const float*)d_in[2];
    const float* Wp[2] = {(const float*)d_in[3], (const float*)d_in[11]};
    const float* cw[2] = {(const float*)d_in[4], (const float*)d_in[12]};
    const float* cb[2] = {(const float*)d_in[5], (const float*)d_in[13]};
    const float* Ab[2] = {(const float*)d_in[6], (const float*)d_in[14]};
    const float* Dpb[2] = {(const float*)d_in[7], (const float*)d_in[15]};
    const float* Wo[2] = {(const float*)d_in[8], (const float*)d_in[16]};
    const float* lng[2] = {(const float*)d_in[9], (const float*)d_in[17]};
    const float* lnb[2] = {(const float*)d_in[10], (const float*)d_in[18]};
    const float* Wf = (const float*)d_in[19];
    const float* bfv = (const float*)d_in[20];
    const float* W1 = (const float*)d_in[21];
    const float* b1 = (const float*)d_in[22];
    const float* W2 = (const float*)d_in[23];
    const float* b2 = (const float*)d_in[24];
    float* out = (float*)d_out;

    char* base = (char*)d_ws;
    size_t off = 0;
    auto alloc = [&](size_t bytes) { void* p = base + off; off += (bytes + 255) & ~(size_t)255; return p; };
    float* xp = (float*)alloc((size_t)MROWS * XPW * 4);
    float* xcb = (float*)alloc((size_t)MROWS * DIN * 4);
    float* dsg = (float*)alloc((size_t)MROWS * DIN * 4);
    float* tmp96 = (float*)alloc((size_t)MROWS * 96 * 4);
    float* f1 = (float*)alloc((size_t)MROWS * 96 * 4);
    float* f2 = (float*)alloc((size_t)MROWS * 96 * 4);
    const size_t csz = (size_t)2 * NCHUNK * NST * DIN;
    float* Pc = (float*)alloc(csz * 4);
    float* Hfc = (float*)alloc(csz * 4);
    float* Gbc = (float*)alloc(csz * 4);
    float* Hinf = (float*)alloc(csz * 4);
    float* Hinb = (float*)alloc(csz * 4);
    __hip_bfloat16* xn_bf = (__hip_bfloat16*)alloc((size_t)MROWS * 96 * 2);
    __hip_bfloat16* yb_bf = (__hip_bfloat16*)alloc((size_t)MROWS * DIN * 2);
    __hip_bfloat16* cat_bf = (__hip_bfloat16*)alloc((size_t)MROWS * DIN * 2);
    __hip_bfloat16* fc_bf = (__hip_bfloat16*)alloc((size_t)MROWS * 96 * 2);
    __hip_bfloat16* h1_bf = (__hip_bfloat16*)alloc((size_t)MROWS * 384 * 2);
    __hip_bfloat16* wpT[2] = {(__hip_bfloat16*)alloc(480 * 96 * 2),
                              (__hip_bfloat16*)alloc(480 * 96 * 2)};
    __hip_bfloat16* woT[2] = {(__hip_bfloat16*)alloc(96 * 192 * 2),
                              (__hip_bfloat16*)alloc(96 * 192 * 2)};
    __hip_bfloat16* wfT = (__hip_bfloat16*)alloc(96 * 1728 * 2);
    __hip_bfloat16* w1T = (__hip_bfloat16*)alloc(384 * 96 * 2);
    __hip_bfloat16* w2T = (__hip_bfloat16*)alloc(96 * 384 * 2);
    (void)ws_size; (void)in_sizes; (void)n_in; (void)out_size;

    cvt_all<<<dim3(1440), dim3(256), 0, stream>>>(Wp[0], Wp[1], Wo[0], Wo[1], Wf, W1, W2,
                                                  wpT[0], wpT[1], woT[0], woT[1], wfT, w1T, w2T);

    ln96_kernel<__hip_bfloat16><<<dim3(2048), dim3(256), 0, stream>>>(x, norm_g, norm_b, xn_bf, MROWS);

    float* fouts[2] = {f1, f2};
    for (int p = 0; p < 2; ++p) {
        gemm_direct<2, 3, 2, 2, 96, 0, float><<<dim3(5, 128), dim3(256), 0, stream>>>(
            xn_bf, 96, wpT[p], xp, XPW, XPW, nullptr, nullptr);
        convsig_kernel<<<dim3(1536), dim3(256), 0, stream>>>(xp, cw[p], cb[p], xcb, dsg);
        scan_pass1<<<dim3(2 * NCHUNK * 12), dim3(256), 0, stream>>>(dsg, xcb, xp, Ab[p], Pc, Hfc, Gbc);
        scan_pass2<<<dim3(24), dim3(256), 0, stream>>>(Pc, Hfc, Gbc, Hinf, Hinb);
        scan_pass3<<<dim3(2 * NCHUNK * 12), dim3(256), 0, stream>>>(dsg, xcb, xp, Ab[p], Hinf, Hinb,
                                                                    Dpb[p], yb_bf);
        gemm_direct<1, 3, 2, 2, 192, 0, float><<<dim3(1, 256), dim3(256), 0, stream>>>(
            yb_bf, DIN, woT[p], tmp96, 96, 96, nullptr, nullptr);
        ln96_kernel<float><<<dim3(2048), dim3(256), 0, stream>>>(tmp96, lng[p], lnb[p], fouts[p], MROWS);
    }

    fuse_kernel<<<dim3(2048), dim3(256), 0, stream>>>(f1, f2, cat_bf, MROWS);
    conv3x3_direct<<<dim3(256), dim3(256), 0, stream>>>(cat_bf, wfT, bfv, fc_bf);
    gemm_direct<2, 3, 2, 2, 96, 1, __hip_bfloat16><<<dim3(4, 128), dim3(256), 0, stream>>>(
        fc_bf, 96, w1T, h1_bf, 384, 384, b1, nullptr);
    gemm_direct<1, 3, 2, 2, 384, 2, float><<<dim3(1, 256), dim3(256), 0, stream>>>(
        h1_bf, 384, w2T, out, 96, 96, b2, x);
}

// Round 6
// 183.434 us; speedup vs baseline: 3.5589x; 1.2801x over previous
//
#include <hip/hip_runtime.h>
#include <hip/hip_bf16.h>
#include <math.h>

#define L_SEQ 4096
#define CDIM 96
#define DIN 192
#define NST 16
#define NCHUNK 64
#define CHLEN 64
#define MROWS 8192
#define XPW2 960   // combined xp width: 2 branches x 480 (416 used + pad)

typedef __attribute__((ext_vector_type(8))) short bf16x8;
typedef __attribute__((ext_vector_type(4))) float f32x4;
typedef __attribute__((ext_vector_type(4))) short s16x4;

__device__ __forceinline__ float gelu_exact(float x) {
    return 0.5f * x * (1.0f + erff(x * 0.70710678118654752f));
}

__device__ __forceinline__ float fast_exp2(float x) {
#if __has_builtin(__builtin_amdgcn_exp2f)
    return __builtin_amdgcn_exp2f(x);
#else
    return exp2f(x);
#endif
}

// sum across the 16 lanes of each DPP row (n = lane&15) using row_ror adds (VALU, no DS pipe)
__device__ __forceinline__ float rowsum16(float s) {
    s += __int_as_float(__builtin_amdgcn_update_dpp(0, __float_as_int(s), 0x128, 0xF, 0xF, false));
    s += __int_as_float(__builtin_amdgcn_update_dpp(0, __float_as_int(s), 0x124, 0xF, 0xF, false));
    s += __int_as_float(__builtin_amdgcn_update_dpp(0, __float_as_int(s), 0x122, 0xF, 0xF, false));
    s += __int_as_float(__builtin_amdgcn_update_dpp(0, __float_as_int(s), 0x121, 0xF, 0xF, false));
    return s;
}

__device__ __forceinline__ unsigned short f2bf_bits(float f) {
    __hip_bfloat16 h = __float2bfloat16(f);
    return *reinterpret_cast<unsigned short*>(&h);
}

// ---------------- weight convert + transpose: BT[col][k] bf16 ----------------
__global__ __launch_bounds__(256) void cvt_all(
    const float* __restrict__ Wp0, const float* __restrict__ Wp1,
    const float* __restrict__ Wo0, const float* __restrict__ Wo1,
    const float* __restrict__ Wf, const float* __restrict__ W1, const float* __restrict__ W2,
    __hip_bfloat16* __restrict__ wpT, __hip_bfloat16* __restrict__ wo0T,
    __hip_bfloat16* __restrict__ wo1T, __hip_bfloat16* __restrict__ wfT,
    __hip_bfloat16* __restrict__ w1T, __hip_bfloat16* __restrict__ w2T) {
    int i = blockIdx.x * 256 + threadIdx.x;
    const int S_WPALL = XPW2 * 96;
    const int S_WO = 96 * 192;
    const int S_WF = 96 * 1728;
    const int S_W1 = 384 * 96;
    const int S_W2 = 96 * 384;
    if (i < S_WPALL) {
        int j = i / 96, r = i % 96;
        int br = j / 480, cc = j % 480;
        const float* W = br ? Wp1 : Wp0;
        wpT[i] = __float2bfloat16(cc < 416 ? W[r * 576 + cc] : 0.f);
        return;
    }
    i -= S_WPALL;
    if (i < S_WO) { int c = i / 192, r = i % 192; wo0T[i] = __float2bfloat16(Wo0[r * 96 + c]); return; }
    i -= S_WO;
    if (i < S_WO) { int c = i / 192, r = i % 192; wo1T[i] = __float2bfloat16(Wo1[r * 96 + c]); return; }
    i -= S_WO;
    if (i < S_WF) { int c = i / 1728, k = i % 1728; wfT[i] = __float2bfloat16(Wf[k * 96 + c]); return; }
    i -= S_WF;
    if (i < S_W1) { int c = i / 96, r = i % 96; w1T[i] = __float2bfloat16(W1[r * 384 + c]); return; }
    i -= S_W1;
    if (i < S_W2) { int c = i / 384, r = i % 384; w2T[i] = __float2bfloat16(W2[r * 96 + c]); return; }
}

// ---------------- LayerNorm over last dim 96, one wave per row ----------------
template <typename OT>
__global__ __launch_bounds__(256) void ln96_kernel(const float* __restrict__ in,
                                                   const float* __restrict__ g,
                                                   const float* __restrict__ b,
                                                   OT* __restrict__ out, int rows) {
    int wave = threadIdx.x >> 6;
    int lane = threadIdx.x & 63;
    int row = blockIdx.x * 4 + wave;
    if (row >= rows) return;
    const float* p = in + (size_t)row * CDIM;
    float x0 = p[lane];
    float x1 = (lane < 32) ? p[64 + lane] : 0.f;
    float s = x0 + x1, sq = x0 * x0 + x1 * x1;
#pragma unroll
    for (int o = 32; o >= 1; o >>= 1) { s += __shfl_xor(s, o); sq += __shfl_xor(sq, o); }
    float mean = s * (1.f / 96.f);
    float var = sq * (1.f / 96.f) - mean * mean;
    float w = rsqrtf(var + 1e-5f);
    OT* q = out + (size_t)row * CDIM;
    q[lane] = (OT)((x0 - mean) * w * g[lane] + b[lane]);
    if (lane < 32) q[64 + lane] = (OT)((x1 - mean) * w * g[64 + lane] + b[64 + lane]);
}

// ---------------- LDS-free direct-fragment MFMA GEMM ----------------
template <int MI, int NI, int WR, int WC, int K, int EPI, typename CT>
__global__ __launch_bounds__(WR * WC * 64) void gemm_direct(
    const __hip_bfloat16* __restrict__ A, int lda,
    const __hip_bfloat16* __restrict__ BT,
    CT* __restrict__ C, int ldc, int N,
    const float* __restrict__ bias, const float* __restrict__ res) {
    int tid = threadIdx.x;
    int lane = tid & 63, wid = tid >> 6;
    int wm = wid % WR, wn = wid / WR;
    int m0 = blockIdx.y * (WR * MI * 16) + wm * MI * 16;
    int n0 = blockIdx.x * (WC * NI * 16) + wn * NI * 16;
    int lr = lane & 15, kh = (lane >> 4) * 8;
    f32x4 acc[MI][NI] = {};
    const __hip_bfloat16* Ap = A + (size_t)(m0 + lr) * lda + kh;
    const __hip_bfloat16* Bp = BT + (size_t)(n0 + lr) * K + kh;
#pragma unroll
    for (int k0 = 0; k0 < K; k0 += 32) {
        bf16x8 af[MI], bf[NI];
#pragma unroll
        for (int i = 0; i < MI; ++i)
            af[i] = *reinterpret_cast<const bf16x8*>(Ap + (size_t)i * 16 * lda + k0);
#pragma unroll
        for (int j = 0; j < NI; ++j)
            bf[j] = *reinterpret_cast<const bf16x8*>(Bp + (size_t)j * 16 * K + k0);
#pragma unroll
        for (int i = 0; i < MI; ++i)
#pragma unroll
            for (int j = 0; j < NI; ++j)
                acc[i][j] = __builtin_amdgcn_mfma_f32_16x16x32_bf16(af[i], bf[j], acc[i][j], 0, 0, 0);
    }
    int cr = (lane >> 4) << 2;
#pragma unroll
    for (int i = 0; i < MI; ++i) {
        int row = m0 + i * 16 + cr;
#pragma unroll
        for (int j = 0; j < NI; ++j) {
            int col = n0 + j * 16 + lr;
            if (col < N) {
#pragma unroll
                for (int q = 0; q < 4; ++q) {
                    float v = acc[i][j][q];
                    if (EPI == 1) v = gelu_exact(v + bias[col]);
                    else if (EPI == 2) v = v + bias[col] + res[(size_t)(row + q) * ldc + col];
                    C[(size_t)(row + q) * ldc + col] = (CT)v;
                }
            }
        }
    }
}

// ---------------- Wo GEMM (K=192, N=96) with fused LayerNorm epilogue ----------------
// grid.y = 512 row-blocks of 32 over M=16384 (= 2 branches x 8192); branch = blockIdx.y>>8
__global__ __launch_bounds__(256) void gemm_wo_ln(
    const __hip_bfloat16* __restrict__ A,      // [16384][192]
    const __hip_bfloat16* __restrict__ BT0, const __hip_bfloat16* __restrict__ BT1,
    const float* __restrict__ g0, const float* __restrict__ b0,
    const float* __restrict__ g1, const float* __restrict__ b1,
    float* __restrict__ F) {                   // [16384][96]
    int tid = threadIdx.x;
    int lane = tid & 63, wid = tid >> 6;
    int wm = wid & 1, wn = wid >> 1;
    int m0 = blockIdx.y * 32 + wm * 16;
    int n0 = wn * 48;
    int p = blockIdx.y >> 8;
    const __hip_bfloat16* BT = p ? BT1 : BT0;
    const float* g = p ? g1 : g0;
    const float* bb = p ? b1 : b0;
    int lr = lane & 15, kh = (lane >> 4) * 8;
    f32x4 acc[3] = {};
    const __hip_bfloat16* Ap = A + (size_t)(m0 + lr) * 192 + kh;
    const __hip_bfloat16* Bp = BT + (size_t)(n0 + lr) * 192 + kh;
#pragma unroll
    for (int k0 = 0; k0 < 192; k0 += 32) {
        bf16x8 af = *reinterpret_cast<const bf16x8*>(Ap + k0);
#pragma unroll
        for (int j = 0; j < 3; ++j) {
            bf16x8 bf_ = *reinterpret_cast<const bf16x8*>(Bp + (size_t)j * 16 * 192 + k0);
            acc[j] = __builtin_amdgcn_mfma_f32_16x16x32_bf16(af, bf_, acc[j], 0, 0, 0);
        }
    }
    __shared__ float ct[32][100];
    int cr = (lane >> 4) << 2;
#pragma unroll
    for (int j = 0; j < 3; ++j)
#pragma unroll
        for (int q = 0; q < 4; ++q)
            ct[wm * 16 + cr + q][n0 + j * 16 + lr] = acc[j][q];
    __syncthreads();
#pragma unroll
    for (int rr = 0; rr < 8; ++rr) {
        int row = wid * 8 + rr;
        float x0 = ct[row][lane];
        float x1 = (lane < 32) ? ct[row][64 + lane] : 0.f;
        float s = x0 + x1, sq = x0 * x0 + x1 * x1;
#pragma unroll
        for (int o = 32; o >= 1; o >>= 1) { s += __shfl_xor(s, o); sq += __shfl_xor(sq, o); }
        float mean = s * (1.f / 96.f);
        float var = sq * (1.f / 96.f) - mean * mean;
        float w = rsqrtf(var + 1e-5f);
        size_t grow = (size_t)blockIdx.y * 32 + row;
        float* dst = F + grow * 96;
        dst[lane] = (x0 - mean) * w * g[lane] + bb[lane];
        if (lane < 32) dst[64 + lane] = (x1 - mean) * w * g[64 + lane] + bb[64 + lane];
    }
}

// ---------------- 3x3 SAME conv, LDS-free implicit MFMA GEMM ----------------
__global__ __launch_bounds__(256) void conv3x3_direct(const __hip_bfloat16* __restrict__ cat,
                                                      const __hip_bfloat16* __restrict__ WfT,
                                                      const float* __restrict__ bfv,
                                                      __hip_bfloat16* __restrict__ out) {
    int tid = threadIdx.x;
    int lane = tid & 63, wid = tid >> 6;
    int wm = wid & 1, wn = wid >> 1;
    int m0 = blockIdx.x * 32 + wm * 16;
    int n0 = wn * 48;
    int lr = lane & 15, kh = (lane >> 4) * 8;
    int m = m0 + lr;
    int bb = m >> 12, l = m & 4095, yy = l >> 6, xx = l & 63;
    f32x4 acc[3] = {};
    const __hip_bfloat16* Bp = WfT + (size_t)(n0 + lr) * 1728 + kh;
#pragma unroll
    for (int ky = 0; ky < 3; ++ky) {
        int iy = yy + ky - 1;
#pragma unroll
        for (int kx = 0; kx < 3; ++kx) {
            int ix = xx + kx - 1;
            bool ok = ((unsigned)iy < 64u) && ((unsigned)ix < 64u);
            const __hip_bfloat16* Ap =
                cat + ((size_t)bb * 4096 + (size_t)(iy * 64 + ix)) * 192 + kh;
            int kbase = (ky * 3 + kx) * 192;
#pragma unroll
            for (int kc = 0; kc < 192; kc += 32) {
                bf16x8 af = {};
                if (ok) af = *reinterpret_cast<const bf16x8*>(Ap + kc);
#pragma unroll
                for (int j = 0; j < 3; ++j) {
                    bf16x8 bf = *reinterpret_cast<const bf16x8*>(Bp + (size_t)j * 16 * 1728 + kbase + kc);
                    acc[j] = __builtin_amdgcn_mfma_f32_16x16x32_bf16(af, bf, acc[j], 0, 0, 0);
                }
            }
        }
    }
    int cr = (lane >> 4) << 2;
    int crow = m0 + cr;
#pragma unroll
    for (int j = 0; j < 3; ++j) {
        int ccol = n0 + j * 16 + lr;
#pragma unroll
        for (int q = 0; q < 4; ++q) {
            float v = gelu_exact(acc[j][q] + bfv[ccol]);
            out[(size_t)(crow + q) * 96 + ccol] = __float2bfloat16(v);
        }
    }
}

// ---------------- scan pass1 (fused depthwise conv + sigmoid): per-chunk scan ----------------
// grid: p*2*64*12; block=(p,b,c,dg); 256 thr = 16 n x 16 d. Carries out in chunk-last layout.
__global__ __launch_bounds__(256) void scan_pass1f(
    const float* __restrict__ xpw,
    const float* __restrict__ cw0, const float* __restrict__ cw1,
    const float* __restrict__ cb0, const float* __restrict__ cb1,
    const float* __restrict__ A0, const float* __restrict__ A1,
    float* __restrict__ Pc, float* __restrict__ Hf, float* __restrict__ Gb) {
    __shared__ float rawx[67][16];
    __shared__ float2 sdx[CHLEN][16];
    __shared__ float sb[CHLEN][16];
    __shared__ float sA[256];
    int bid = blockIdx.x;
    int dg = bid % 12;
    int c = (bid / 12) % NCHUNK;
    int b = (bid / (12 * NCHUNK)) & 1;
    int p = bid / (12 * NCHUNK * 2);
    const float* cw = p ? cw1 : cw0;
    const float* cbp = p ? cb1 : cb0;
    const float* Am = p ? A1 : A0;
    int tid = threadIdx.x;
    sA[tid] = Am[tid];
    int xb = p * 480;
    int t0 = c * CHLEN;
    int r = tid >> 2, q = (tid & 3) * 4;
    size_t grow = (size_t)b * L_SEQ + t0 + r;
    const float* rowp = xpw + grow * XPW2 + xb;
    *(float4*)&rawx[r + 3][q] = *(const float4*)(rowp + dg * 16 + q);
    float4 dv = *(const float4*)(rowp + 192 + dg * 16 + q);
    *(float4*)&sb[r][q] = *(const float4*)(rowp + 384 + q);
    if (tid < 12) {
        int rr = tid >> 2, qq = (tid & 3) * 4;
        int src = t0 - 3 + rr;
        float4 v = {0.f, 0.f, 0.f, 0.f};
        if (src >= 0)
            v = *(const float4*)(xpw + ((size_t)b * L_SEQ + src) * XPW2 + xb + dg * 16 + qq);
        *(float4*)&rawx[rr][qq] = v;
    }
    __syncthreads();
    float dd[4] = {dv.x, dv.y, dv.z, dv.w};
#pragma unroll
    for (int i = 0; i < 4; ++i) {
        int d = dg * 16 + q + i;
        float4 w = *(const float4*)(cw + (size_t)d * 4);
        float xc = cbp[d] + w.w * rawx[r + 3][q + i] + w.z * rawx[r + 2][q + i] +
                   w.y * rawx[r + 1][q + i] + w.x * rawx[r][q + i];
        float ds = 1.f / (1.f + __expf(-dd[i]));
        sdx[r][q + i] = make_float2(ds, xc);
    }
    __syncthreads();
    int n = tid & 15, drow = tid >> 4;
    float asum = 0.f;
#pragma unroll
    for (int j = 0; j < 16; ++j) asum += sA[n * 16 + j];
    float asum2 = asum * 1.44269504f;
    float h = 0.f, gb = 0.f, Q = 1.f;
    for (int t = 0; t < CHLEN; ++t) {
        float2 dx = sdx[t][drow];
        float bm = sb[t][n];
        float a = fast_exp2(dx.x * asum2);
        float bu = dx.x * dx.y * bm;
        h = a * h + bu;
        gb += Q * bu;
        Q *= a;
    }
    size_t cidx = ((((size_t)p * 2 + b) * NST + n) * DIN + dg * 16 + drow) * NCHUNK + c;
    Pc[cidx] = Q;
    Hf[cidx] = h;
    Gb[cidx] = gb;
}

// ---------------- scan pass2: combine chunk carries (contiguous float4 loads) ----------------
__global__ __launch_bounds__(256) void scan_pass2(const float* __restrict__ Pc,
                                                  const float* __restrict__ Hf,
                                                  const float* __restrict__ Gb,
                                                  float* __restrict__ Hinf,
                                                  float* __restrict__ Hinb) {
    int t = blockIdx.x * 256 + threadIdx.x;
    if (t >= 2 * 2 * NST * DIN) return;
    size_t base = (size_t)t * NCHUNK;
    {
        float4 P4[16], H4[16];
        const float4* Pp = (const float4*)(Pc + base);
        const float4* Hp = (const float4*)(Hf + base);
#pragma unroll
        for (int i = 0; i < 16; ++i) { P4[i] = Pp[i]; H4[i] = Hp[i]; }
        float hin = 0.f;
        float4* Op = (float4*)(Hinf + base);
#pragma unroll
        for (int i = 0; i < 16; ++i) {
            float4 o;
            o.x = hin; hin = H4[i].x + P4[i].x * hin;
            o.y = hin; hin = H4[i].y + P4[i].y * hin;
            o.z = hin; hin = H4[i].z + P4[i].z * hin;
            o.w = hin; hin = H4[i].w + P4[i].w * hin;
            Op[i] = o;
        }
    }
    {
        float4 P4[16], G4[16];
        const float4* Pp = (const float4*)(Pc + base);
        const float4* Gp = (const float4*)(Gb + base);
#pragma unroll
        for (int i = 0; i < 16; ++i) { P4[i] = Pp[i]; G4[i] = Gp[i]; }
        float gin = 0.f;
        float4* Op = (float4*)(Hinb + base);
#pragma unroll
        for (int i = 15; i >= 0; --i) {
            float4 o;
            o.w = gin; gin = G4[i].w + P4[i].w * gin;
            o.z = gin; gin = G4[i].z + P4[i].z * gin;
            o.y = gin; gin = G4[i].y + P4[i].y * gin;
            o.x = gin; gin = G4[i].x + P4[i].x * gin;
            Op[i] = o;
        }
    }
}

// ---------------- scan pass3 (fused conv): fwd+bwd re-scan, DPP reduction, fused y ----------------
__global__ __launch_bounds__(256) void scan_pass3f(
    const float* __restrict__ xpw,
    const float* __restrict__ cw0, const float* __restrict__ cw1,
    const float* __restrict__ cb0, const float* __restrict__ cb1,
    const float* __restrict__ A0, const float* __restrict__ A1,
    const float* __restrict__ Hinf, const float* __restrict__ Hinb,
    const float* __restrict__ Dp0, const float* __restrict__ Dp1,
    __hip_bfloat16* __restrict__ y) {
    __shared__ float rawx[67][16];
    __shared__ float2 sdx[CHLEN][16];   // (dsg, xc)
    __shared__ float2 sbc[CHLEN][16];   // (Bm, Cm)
    __shared__ float ysf[CHLEN][16], ysb[CHLEN][16];
    __shared__ float sA[256];
    int bid = blockIdx.x;
    int dg = bid % 12;
    int c = (bid / 12) % NCHUNK;
    int b = (bid / (12 * NCHUNK)) & 1;
    int p = bid / (12 * NCHUNK * 2);
    const float* cw = p ? cw1 : cw0;
    const float* cbp = p ? cb1 : cb0;
    const float* Am = p ? A1 : A0;
    const float* Dp = p ? Dp1 : Dp0;
    int tid = threadIdx.x;
    sA[tid] = Am[tid];
    int xb = p * 480;
    int t0 = c * CHLEN;
    int r = tid >> 2, q = (tid & 3) * 4;
    size_t grow = (size_t)b * L_SEQ + t0 + r;
    const float* rowp = xpw + grow * XPW2 + xb;
    *(float4*)&rawx[r + 3][q] = *(const float4*)(rowp + dg * 16 + q);
    float4 dv = *(const float4*)(rowp + 192 + dg * 16 + q);
    {
        float4 bv = *(const float4*)(rowp + 384 + q);
        float4 cv = *(const float4*)(rowp + 400 + q);
        float4 u1 = {bv.x, cv.x, bv.y, cv.y};
        float4 u2 = {bv.z, cv.z, bv.w, cv.w};
        *(float4*)&sbc[r][q] = u1;
        *(float4*)&sbc[r][q + 2] = u2;
    }
    if (tid < 12) {
        int rr = tid >> 2, qq = (tid & 3) * 4;
        int src = t0 - 3 + rr;
        float4 v = {0.f, 0.f, 0.f, 0.f};
        if (src >= 0)
            v = *(const float4*)(xpw + ((size_t)b * L_SEQ + src) * XPW2 + xb + dg * 16 + qq);
        *(float4*)&rawx[rr][qq] = v;
    }
    __syncthreads();
    float dd[4] = {dv.x, dv.y, dv.z, dv.w};
#pragma unroll
    for (int i = 0; i < 4; ++i) {
        int d = dg * 16 + q + i;
        float4 w = *(const float4*)(cw + (size_t)d * 4);
        float xc = cbp[d] + w.w * rawx[r + 3][q + i] + w.z * rawx[r + 2][q + i] +
                   w.y * rawx[r + 1][q + i] + w.x * rawx[r][q + i];
        float ds = 1.f / (1.f + __expf(-dd[i]));
        sdx[r][q + i] = make_float2(ds, xc);
    }
    __syncthreads();
    int lane = tid & 63, wave = tid >> 6;
    int n = lane & 15;
    int dloc = wave * 4 + (lane >> 4);
    int d = dg * 16 + dloc;
    float asum = 0.f;
#pragma unroll
    for (int j = 0; j < 16; ++j) asum += sA[n * 16 + j];
    float asum2 = asum * 1.44269504f;
    size_t cidx = ((((size_t)p * 2 + b) * NST + n) * DIN + d) * NCHUNK + c;
    float h = Hinf[cidx];
    float gv = Hinb[cidx];
    for (int t = 0; t < CHLEN; ++t) {
        int tb = CHLEN - 1 - t;
        float2 dxf = sdx[t][dloc];
        float2 bcf = sbc[t][n];
        float2 dxb = sdx[tb][dloc];
        float2 bcb = sbc[tb][n];
        float af = fast_exp2(dxf.x * asum2);
        float buf_ = dxf.x * dxf.y * bcf.x;
        h = af * h + buf_;
        float pf = rowsum16(bcf.y * h);
        float ab = fast_exp2(dxb.x * asum2);
        float bub_ = dxb.x * dxb.y * bcb.x;
        gv = ab * gv + bub_;
        float pb = rowsum16(bcb.y * gv);
        if (n == 0) {
            ysf[t][dloc] = pf;
            ysb[tb][dloc] = pb;
        }
    }
    __syncthreads();
    {
        int tl = tid >> 2, qq = (tid & 3) * 4;
        int d2 = dg * 16 + qq;
        float4 Dv = *(const float4*)(Dp + d2);
        float vs[4];
#pragma unroll
        for (int i = 0; i < 4; ++i)
            vs[i] = ysf[tl][qq + i] + ysb[tl][qq + i] + ((const float*)&Dv)[i] * sdx[tl][qq + i].y;
        s16x4 pk = {(short)f2bf_bits(vs[0]), (short)f2bf_bits(vs[1]),
                    (short)f2bf_bits(vs[2]), (short)f2bf_bits(vs[3])};
        size_t row = (size_t)b * L_SEQ + t0 + tl;
        *(s16x4*)((unsigned short*)y + ((size_t)p * MROWS + row) * DIN + d2) = pk;
    }
}

// ---------------- cosine-sim fusion: cat = [f1, sim*f1 + (1-sim)*f2] (bf16 out) ----------------
__global__ __launch_bounds__(256) void fuse_kernel(const float* __restrict__ f1,
                                                   const float* __restrict__ f2,
                                                   __hip_bfloat16* __restrict__ cat, int rows) {
    int wave = threadIdx.x >> 6;
    int lane = threadIdx.x & 63;
    int row = blockIdx.x * 4 + wave;
    if (row >= rows) return;
    const float* p1 = f1 + (size_t)row * CDIM;
    const float* p2 = f2 + (size_t)row * CDIM;
    float a0 = p1[lane], b0 = p2[lane];
    float a1 = 0.f, b1 = 0.f;
    if (lane < 32) { a1 = p1[64 + lane]; b1 = p2[64 + lane]; }
    float s11 = a0 * a0 + a1 * a1;
    float s22 = b0 * b0 + b1 * b1;
    float s12 = a0 * b0 + a1 * b1;
#pragma unroll
    for (int o = 32; o >= 1; o >>= 1) {
        s11 += __shfl_xor(s11, o);
        s22 += __shfl_xor(s22, o);
        s12 += __shfl_xor(s12, o);
    }
    float nr1 = fmaxf(sqrtf(s11), 1e-12f);
    float nr2 = fmaxf(sqrtf(s22), 1e-12f);
    float sim = s12 / (nr1 * nr2);
    __hip_bfloat16* q = cat + (size_t)row * 192;
    q[lane] = __float2bfloat16(a0);
    q[96 + lane] = __float2bfloat16(sim * a0 + (1.f - sim) * b0);
    if (lane < 32) {
        q[64 + lane] = __float2bfloat16(a1);
        q[96 + 64 + lane] = __float2bfloat16(sim * a1 + (1.f - sim) * b1);
    }
}

extern "C" void kernel_launch(void* const* d_in, const int* in_sizes, int n_in,
                              void* d_out, int out_size, void* d_ws, size_t ws_size,
                              hipStream_t stream) {
    const float* x = (const float*)d_in[0];
    const float* norm_g = (const float*)d_in[1];
    const float* norm_b = (const float*)d_in[2];
    const float* Wp[2] = {(const float*)d_in[3], (const float*)d_in[11]};
    const float* cw[2] = {(const float*)d_in[4], (const float*)d_in[12]};
    const float* cb[2] = {(const float*)d_in[5], (const float*)d_in[13]};
    const float* Ab[2] = {(const float*)d_in[6], (const float*)d_in[14]};
    const float* Dpb[2] = {(const float*)d_in[7], (const float*)d_in[15]};
    const float* Wo[2] = {(const float*)d_in[8], (const float*)d_in[16]};
    const float* lng[2] = {(const float*)d_in[9], (const float*)d_in[17]};
    const float* lnb[2] = {(const float*)d_in[10], (const float*)d_in[18]};
    const float* Wf = (const float*)d_in[19];
    const float* bfv = (const float*)d_in[20];
    const float* W1 = (const float*)d_in[21];
    const float* b1 = (const float*)d_in[22];
    const float* W2 = (const float*)d_in[23];
    const float* b2 = (const float*)d_in[24];
    float* out = (float*)d_out;

    char* base = (char*)d_ws;
    size_t off = 0;
    auto alloc = [&](size_t bytes) { void* p = base + off; off += (bytes + 255) & ~(size_t)255; return p; };
    float* xpw = (float*)alloc((size_t)MROWS * XPW2 * 4);
    float* f12 = (float*)alloc((size_t)2 * MROWS * 96 * 4);
    const size_t csz = (size_t)2 * 2 * NST * DIN * NCHUNK;
    float* Pc = (float*)alloc(csz * 4);
    float* Hfc = (float*)alloc(csz * 4);
    float* Gbc = (float*)alloc(csz * 4);
    float* Hinf = (float*)alloc(csz * 4);
    float* Hinb = (float*)alloc(csz * 4);
    __hip_bfloat16* xn_bf = (__hip_bfloat16*)alloc((size_t)MROWS * 96 * 2);
    __hip_bfloat16* yb_bf = (__hip_bfloat16*)alloc((size_t)2 * MROWS * DIN * 2);
    __hip_bfloat16* cat_bf = (__hip_bfloat16*)alloc((size_t)MROWS * DIN * 2);
    __hip_bfloat16* fc_bf = (__hip_bfloat16*)alloc((size_t)MROWS * 96 * 2);
    __hip_bfloat16* h1_bf = (__hip_bfloat16*)alloc((size_t)MROWS * 384 * 2);
    __hip_bfloat16* wpT = (__hip_bfloat16*)alloc((size_t)XPW2 * 96 * 2);
    __hip_bfloat16* woT[2] = {(__hip_bfloat16*)alloc(96 * 192 * 2),
                              (__hip_bfloat16*)alloc(96 * 192 * 2)};
    __hip_bfloat16* wfT = (__hip_bfloat16*)alloc(96 * 1728 * 2);
    __hip_bfloat16* w1T = (__hip_bfloat16*)alloc(384 * 96 * 2);
    __hip_bfloat16* w2T = (__hip_bfloat16*)alloc(96 * 384 * 2);
    (void)ws_size; (void)in_sizes; (void)n_in; (void)out_size;

    // 1. weight convert + transpose
    cvt_all<<<dim3(1440), dim3(256), 0, stream>>>(Wp[0], Wp[1], Wo[0], Wo[1], Wf, W1, W2,
                                                  wpT, woT[0], woT[1], wfT, w1T, w2T);
    // 2. input LayerNorm -> bf16
    ln96_kernel<__hip_bfloat16><<<dim3(2048), dim3(256), 0, stream>>>(x, norm_g, norm_b, xn_bf, MROWS);
    // 3. xp(both branches) = xn @ [Wp1|Wp2]  (M=8192, N=960, K=96)
    gemm_direct<2, 3, 2, 2, 96, 0, float><<<dim3(10, 128), dim3(256), 0, stream>>>(
        xn_bf, 96, wpT, xpw, XPW2, XPW2, nullptr, nullptr);
    // 4-6. bidirectional selective scan, both branches fused (conv+sigmoid recomputed in-block)
    scan_pass1f<<<dim3(2 * 2 * NCHUNK * 12), dim3(256), 0, stream>>>(
        xpw, cw[0], cw[1], cb[0], cb[1], Ab[0], Ab[1], Pc, Hfc, Gbc);
    scan_pass2<<<dim3(48), dim3(256), 0, stream>>>(Pc, Hfc, Gbc, Hinf, Hinb);
    scan_pass3f<<<dim3(2 * 2 * NCHUNK * 12), dim3(256), 0, stream>>>(
        xpw, cw[0], cw[1], cb[0], cb[1], Ab[0], Ab[1], Hinf, Hinb, Dpb[0], Dpb[1], yb_bf);
    // 7. f = LN(y @ Wo) for both branches (M=16384)
    gemm_wo_ln<<<dim3(1, 512), dim3(256), 0, stream>>>(
        yb_bf, woT[0], woT[1], lng[0], lnb[0], lng[1], lnb[1], f12);
    // 8. cosine-sim fuse -> cat
    fuse_kernel<<<dim3(2048), dim3(256), 0, stream>>>(f12, f12 + (size_t)MROWS * 96, cat_bf, MROWS);
    // 9. fc = gelu(conv3x3(cat) + bf)
    conv3x3_direct<<<dim3(256), dim3(256), 0, stream>>>(cat_bf, wfT, bfv, fc_bf);
    // 10. h1 = gelu(fc @ W1 + b1)
    gemm_direct<2, 3, 2, 2, 96, 1, __hip_bfloat16><<<dim3(4, 128), dim3(256), 0, stream>>>(
        fc_bf, 96, w1T, h1_bf, 384, 384, b1, nullptr);
    // 11. out = h1 @ W2 + b2 + res
    gemm_direct<1, 3, 2, 2, 384, 2, float><<<dim3(1, 256), dim3(256), 0, stream>>>(
        h1_bf, 384, w2T, out, 96, 96, b2, x);
}

// Round 7
// 176.839 us; speedup vs baseline: 3.6916x; 1.0373x over previous
//
#include <hip/hip_runtime.h>
#include <hip/hip_bf16.h>
#include <math.h>

#define L_SEQ 4096
#define CDIM 96
#define DIN 192
#define NST 16
#define NCHUNK 64
#define CHLEN 64
#define MROWS 8192
#define XPW2 960   // combined xp width: 2 branches x 480 (416 used + pad)
#define SCAN_GRID 3072

typedef __attribute__((ext_vector_type(8))) short bf16x8;
typedef __attribute__((ext_vector_type(4))) float f32x4;
typedef __attribute__((ext_vector_type(4))) short s16x4;
typedef __attribute__((ext_vector_type(4))) unsigned short u16x4;

__device__ __forceinline__ float gelu_exact(float x) {
    return 0.5f * x * (1.0f + erff(x * 0.70710678118654752f));
}

__device__ __forceinline__ float fast_exp2(float x) {
#if __has_builtin(__builtin_amdgcn_exp2f)
    return __builtin_amdgcn_exp2f(x);
#else
    return exp2f(x);
#endif
}

__device__ __forceinline__ float b2f(unsigned short u) {
    return __uint_as_float((unsigned int)u << 16);
}

// 16-lane DPP row reduction; bound_ctrl=true lets LLVM fold to v_add_f32_dpp
__device__ __forceinline__ float rowsum16(float s) {
    s += __int_as_float(__builtin_amdgcn_update_dpp(0, __float_as_int(s), 0x128, 0xF, 0xF, true));
    s += __int_as_float(__builtin_amdgcn_update_dpp(0, __float_as_int(s), 0x124, 0xF, 0xF, true));
    s += __int_as_float(__builtin_amdgcn_update_dpp(0, __float_as_int(s), 0x122, 0xF, 0xF, true));
    s += __int_as_float(__builtin_amdgcn_update_dpp(0, __float_as_int(s), 0x121, 0xF, 0xF, true));
    return s;
}

__device__ __forceinline__ unsigned short f2bf_bits(float f) {
    __hip_bfloat16 h = __float2bfloat16(f);
    return *reinterpret_cast<unsigned short*>(&h);
}

// ---------------- weight convert + transpose: BT[col][k] bf16 ----------------
__global__ __launch_bounds__(256) void cvt_all(
    const float* __restrict__ Wp0, const float* __restrict__ Wp1,
    const float* __restrict__ Wo0, const float* __restrict__ Wo1,
    const float* __restrict__ Wf, const float* __restrict__ W1, const float* __restrict__ W2,
    __hip_bfloat16* __restrict__ wpT, __hip_bfloat16* __restrict__ wo0T,
    __hip_bfloat16* __restrict__ wo1T, __hip_bfloat16* __restrict__ wfT,
    __hip_bfloat16* __restrict__ w1T, __hip_bfloat16* __restrict__ w2T) {
    int i = blockIdx.x * 256 + threadIdx.x;
    const int S_WPALL = XPW2 * 96;
    const int S_WO = 96 * 192;
    const int S_WF = 96 * 1728;
    const int S_W1 = 384 * 96;
    const int S_W2 = 96 * 384;
    if (i < S_WPALL) {
        int j = i / 96, r = i % 96;
        int br = j / 480, cc = j % 480;
        const float* W = br ? Wp1 : Wp0;
        wpT[i] = __float2bfloat16(cc < 416 ? W[r * 576 + cc] : 0.f);
        return;
    }
    i -= S_WPALL;
    if (i < S_WO) { int c = i / 192, r = i % 192; wo0T[i] = __float2bfloat16(Wo0[r * 96 + c]); return; }
    i -= S_WO;
    if (i < S_WO) { int c = i / 192, r = i % 192; wo1T[i] = __float2bfloat16(Wo1[r * 96 + c]); return; }
    i -= S_WO;
    if (i < S_WF) { int c = i / 1728, k = i % 1728; wfT[i] = __float2bfloat16(Wf[k * 96 + c]); return; }
    i -= S_WF;
    if (i < S_W1) { int c = i / 96, r = i % 96; w1T[i] = __float2bfloat16(W1[r * 384 + c]); return; }
    i -= S_W1;
    if (i < S_W2) { int c = i / 384, r = i % 384; w2T[i] = __float2bfloat16(W2[r * 96 + c]); return; }
}

// ---------------- LayerNorm over last dim 96, one wave per row ----------------
template <typename OT>
__global__ __launch_bounds__(256) void ln96_kernel(const float* __restrict__ in,
                                                   const float* __restrict__ g,
                                                   const float* __restrict__ b,
                                                   OT* __restrict__ out, int rows) {
    int wave = threadIdx.x >> 6;
    int lane = threadIdx.x & 63;
    int row = blockIdx.x * 4 + wave;
    if (row >= rows) return;
    const float* p = in + (size_t)row * CDIM;
    float x0 = p[lane];
    float x1 = (lane < 32) ? p[64 + lane] : 0.f;
    float s = x0 + x1, sq = x0 * x0 + x1 * x1;
#pragma unroll
    for (int o = 32; o >= 1; o >>= 1) { s += __shfl_xor(s, o); sq += __shfl_xor(sq, o); }
    float mean = s * (1.f / 96.f);
    float var = sq * (1.f / 96.f) - mean * mean;
    float w = rsqrtf(var + 1e-5f);
    OT* q = out + (size_t)row * CDIM;
    q[lane] = (OT)((x0 - mean) * w * g[lane] + b[lane]);
    if (lane < 32) q[64 + lane] = (OT)((x1 - mean) * w * g[64 + lane] + b[64 + lane]);
}

// ---------------- LDS-free direct-fragment MFMA GEMM ----------------
template <int MI, int NI, int WR, int WC, int K, int EPI, typename CT>
__global__ __launch_bounds__(WR * WC * 64) void gemm_direct(
    const __hip_bfloat16* __restrict__ A, int lda,
    const __hip_bfloat16* __restrict__ BT,
    CT* __restrict__ C, int ldc, int N,
    const float* __restrict__ bias, const float* __restrict__ res) {
    int tid = threadIdx.x;
    int lane = tid & 63, wid = tid >> 6;
    int wm = wid % WR, wn = wid / WR;
    int m0 = blockIdx.y * (WR * MI * 16) + wm * MI * 16;
    int n0 = blockIdx.x * (WC * NI * 16) + wn * NI * 16;
    int lr = lane & 15, kh = (lane >> 4) * 8;
    f32x4 acc[MI][NI] = {};
    const __hip_bfloat16* Ap = A + (size_t)(m0 + lr) * lda + kh;
    const __hip_bfloat16* Bp = BT + (size_t)(n0 + lr) * K + kh;
#pragma unroll
    for (int k0 = 0; k0 < K; k0 += 32) {
        bf16x8 af[MI], bf[NI];
#pragma unroll
        for (int i = 0; i < MI; ++i)
            af[i] = *reinterpret_cast<const bf16x8*>(Ap + (size_t)i * 16 * lda + k0);
#pragma unroll
        for (int j = 0; j < NI; ++j)
            bf[j] = *reinterpret_cast<const bf16x8*>(Bp + (size_t)j * 16 * K + k0);
#pragma unroll
        for (int i = 0; i < MI; ++i)
#pragma unroll
            for (int j = 0; j < NI; ++j)
                acc[i][j] = __builtin_amdgcn_mfma_f32_16x16x32_bf16(af[i], bf[j], acc[i][j], 0, 0, 0);
    }
    int cr = (lane >> 4) << 2;
#pragma unroll
    for (int i = 0; i < MI; ++i) {
        int row = m0 + i * 16 + cr;
#pragma unroll
        for (int j = 0; j < NI; ++j) {
            int col = n0 + j * 16 + lr;
            if (col < N) {
#pragma unroll
                for (int q = 0; q < 4; ++q) {
                    float v = acc[i][j][q];
                    if (EPI == 1) v = gelu_exact(v + bias[col]);
                    else if (EPI == 2) v = v + bias[col] + res[(size_t)(row + q) * ldc + col];
                    C[(size_t)(row + q) * ldc + col] = (CT)v;
                }
            }
        }
    }
}

// ---------------- Wo GEMM both branches + LN + cosine fuse -> cat (bf16) ----------------
// 256 blocks of 32 rows. Per block: f1 = LN(y0@Wo0), f2 = LN(y1@Wo1), sim, cat write.
__global__ __launch_bounds__(256) void gemm_wo_ln_fuse(
    const __hip_bfloat16* __restrict__ A,      // yb [2*8192][192]
    const __hip_bfloat16* __restrict__ BT0, const __hip_bfloat16* __restrict__ BT1,
    const float* __restrict__ g0, const float* __restrict__ b0,
    const float* __restrict__ g1, const float* __restrict__ b1,
    __hip_bfloat16* __restrict__ cat) {        // [8192][192]
    int tid = threadIdx.x;
    int lane = tid & 63, wid = tid >> 6;
    int wm = wid & 1, wn = wid >> 1;
    int m0 = blockIdx.x * 32 + wm * 16;
    int n0 = wn * 48;
    int lr = lane & 15, kh = (lane >> 4) * 8;
    f32x4 acc0[3] = {}, acc1[3] = {};
    const __hip_bfloat16* A0 = A + (size_t)(m0 + lr) * 192 + kh;
    const __hip_bfloat16* A1 = A + (size_t)(MROWS + m0 + lr) * 192 + kh;
    const __hip_bfloat16* Bp0 = BT0 + (size_t)(n0 + lr) * 192 + kh;
    const __hip_bfloat16* Bp1 = BT1 + (size_t)(n0 + lr) * 192 + kh;
#pragma unroll
    for (int k0 = 0; k0 < 192; k0 += 32) {
        bf16x8 af0 = *reinterpret_cast<const bf16x8*>(A0 + k0);
        bf16x8 af1 = *reinterpret_cast<const bf16x8*>(A1 + k0);
#pragma unroll
        for (int j = 0; j < 3; ++j) {
            bf16x8 b0v = *reinterpret_cast<const bf16x8*>(Bp0 + (size_t)j * 16 * 192 + k0);
            bf16x8 b1v = *reinterpret_cast<const bf16x8*>(Bp1 + (size_t)j * 16 * 192 + k0);
            acc0[j] = __builtin_amdgcn_mfma_f32_16x16x32_bf16(af0, b0v, acc0[j], 0, 0, 0);
            acc1[j] = __builtin_amdgcn_mfma_f32_16x16x32_bf16(af1, b1v, acc1[j], 0, 0, 0);
        }
    }
    __shared__ float ct0[32][100], ct1[32][100];
    int cr = (lane >> 4) << 2;
#pragma unroll
    for (int j = 0; j < 3; ++j)
#pragma unroll
        for (int q = 0; q < 4; ++q) {
            ct0[wm * 16 + cr + q][n0 + j * 16 + lr] = acc0[j][q];
            ct1[wm * 16 + cr + q][n0 + j * 16 + lr] = acc1[j][q];
        }
    __syncthreads();
#pragma unroll
    for (int rr = 0; rr < 8; ++rr) {
        int row = wid * 8 + rr;
        float a0 = ct0[row][lane];
        float a1 = (lane < 32) ? ct0[row][64 + lane] : 0.f;
        float c0 = ct1[row][lane];
        float c1 = (lane < 32) ? ct1[row][64 + lane] : 0.f;
        float s0 = a0 + a1, q0 = a0 * a0 + a1 * a1;
        float s1 = c0 + c1, q1 = c0 * c0 + c1 * c1;
#pragma unroll
        for (int o = 32; o >= 1; o >>= 1) {
            s0 += __shfl_xor(s0, o); q0 += __shfl_xor(q0, o);
            s1 += __shfl_xor(s1, o); q1 += __shfl_xor(q1, o);
        }
        float mu0 = s0 * (1.f / 96.f), w0 = rsqrtf(q0 * (1.f / 96.f) - mu0 * mu0 + 1e-5f);
        float mu1 = s1 * (1.f / 96.f), w1 = rsqrtf(q1 * (1.f / 96.f) - mu1 * mu1 + 1e-5f);
        float f1a = (a0 - mu0) * w0 * g0[lane] + b0[lane];
        float f2a = (c0 - mu1) * w1 * g1[lane] + b1[lane];
        float f1b = 0.f, f2b = 0.f;
        if (lane < 32) {
            f1b = (a1 - mu0) * w0 * g0[64 + lane] + b0[64 + lane];
            f2b = (c1 - mu1) * w1 * g1[64 + lane] + b1[64 + lane];
        }
        float s11 = f1a * f1a + f1b * f1b;
        float s22 = f2a * f2a + f2b * f2b;
        float s12 = f1a * f2a + f1b * f2b;
#pragma unroll
        for (int o = 32; o >= 1; o >>= 1) {
            s11 += __shfl_xor(s11, o);
            s22 += __shfl_xor(s22, o);
            s12 += __shfl_xor(s12, o);
        }
        float nr1 = fmaxf(sqrtf(s11), 1e-12f);
        float nr2 = fmaxf(sqrtf(s22), 1e-12f);
        float sim = s12 / (nr1 * nr2);
        size_t grow = (size_t)blockIdx.x * 32 + row;
        __hip_bfloat16* q = cat + grow * 192;
        q[lane] = __float2bfloat16(f1a);
        q[96 + lane] = __float2bfloat16(sim * f1a + (1.f - sim) * f2a);
        if (lane < 32) {
            q[64 + lane] = __float2bfloat16(f1b);
            q[96 + 64 + lane] = __float2bfloat16(sim * f1b + (1.f - sim) * f2b);
        }
    }
}

// ---------------- 3x3 SAME conv, LDS-free implicit MFMA GEMM ----------------
__global__ __launch_bounds__(256) void conv3x3_direct(const __hip_bfloat16* __restrict__ cat,
                                                      const __hip_bfloat16* __restrict__ WfT,
                                                      const float* __restrict__ bfv,
                                                      __hip_bfloat16* __restrict__ out) {
    int tid = threadIdx.x;
    int lane = tid & 63, wid = tid >> 6;
    int wm = wid & 1, wn = wid >> 1;
    int m0 = blockIdx.x * 32 + wm * 16;
    int n0 = wn * 48;
    int lr = lane & 15, kh = (lane >> 4) * 8;
    int m = m0 + lr;
    int bb = m >> 12, l = m & 4095, yy = l >> 6, xx = l & 63;
    f32x4 acc[3] = {};
    const __hip_bfloat16* Bp = WfT + (size_t)(n0 + lr) * 1728 + kh;
#pragma unroll
    for (int ky = 0; ky < 3; ++ky) {
        int iy = yy + ky - 1;
#pragma unroll
        for (int kx = 0; kx < 3; ++kx) {
            int ix = xx + kx - 1;
            bool ok = ((unsigned)iy < 64u) && ((unsigned)ix < 64u);
            const __hip_bfloat16* Ap =
                cat + ((size_t)bb * 4096 + (size_t)(iy * 64 + ix)) * 192 + kh;
            int kbase = (ky * 3 + kx) * 192;
#pragma unroll
            for (int kc = 0; kc < 192; kc += 32) {
                bf16x8 af = {};
                if (ok) af = *reinterpret_cast<const bf16x8*>(Ap + kc);
#pragma unroll
                for (int j = 0; j < 3; ++j) {
                    bf16x8 bf = *reinterpret_cast<const bf16x8*>(Bp + (size_t)j * 16 * 1728 + kbase + kc);
                    acc[j] = __builtin_amdgcn_mfma_f32_16x16x32_bf16(af, bf, acc[j], 0, 0, 0);
                }
            }
        }
    }
    int cr = (lane >> 4) << 2;
    int crow = m0 + cr;
#pragma unroll
    for (int j = 0; j < 3; ++j) {
        int ccol = n0 + j * 16 + lr;
#pragma unroll
        for (int q = 0; q < 4; ++q) {
            float v = gelu_exact(acc[j][q] + bfv[ccol]);
            out[(size_t)(crow + q) * 96 + ccol] = __float2bfloat16(v);
        }
    }
}

// ---------------- scan pass1 (fused depthwise conv + sigmoid), bf16 xp ----------------
__global__ __launch_bounds__(256) void scan_pass1f(
    const __hip_bfloat16* __restrict__ xpw,
    const float* __restrict__ cw0, const float* __restrict__ cw1,
    const float* __restrict__ cb0, const float* __restrict__ cb1,
    const float* __restrict__ A0, const float* __restrict__ A1,
    float* __restrict__ Pc, float* __restrict__ Hf, float* __restrict__ Gb) {
    __shared__ unsigned short rawxu[67][16];
    __shared__ float2 sdx[CHLEN][16];
    __shared__ float sb[CHLEN][16];
    __shared__ float sA[256];
    int bid = (blockIdx.x & 7) * (SCAN_GRID / 8) + (blockIdx.x >> 3);  // XCD swizzle
    int dg = bid % 12;
    int c = (bid / 12) % NCHUNK;
    int b = (bid / (12 * NCHUNK)) & 1;
    int p = bid / (12 * NCHUNK * 2);
    const float* cw = p ? cw1 : cw0;
    const float* cbp = p ? cb1 : cb0;
    const float* Am = p ? A1 : A0;
    int tid = threadIdx.x;
    sA[tid] = Am[tid];
    const unsigned short* xu = (const unsigned short*)xpw;
    int xb = p * 480;
    int t0 = c * CHLEN;
    int r = tid >> 2, q = (tid & 3) * 4;
    size_t grow = (size_t)b * L_SEQ + t0 + r;
    const unsigned short* rowp = xu + grow * XPW2 + xb;
    *(u16x4*)&rawxu[r + 3][q] = *(const u16x4*)(rowp + dg * 16 + q);
    u16x4 dvu = *(const u16x4*)(rowp + 192 + dg * 16 + q);
    u16x4 bvu = *(const u16x4*)(rowp + 384 + q);
    float4 bf4 = {b2f(bvu.x), b2f(bvu.y), b2f(bvu.z), b2f(bvu.w)};
    *(float4*)&sb[r][q] = bf4;
    if (tid < 12) {
        int rr = tid >> 2, qq = (tid & 3) * 4;
        int src = t0 - 3 + rr;
        u16x4 v = {0, 0, 0, 0};
        if (src >= 0)
            v = *(const u16x4*)(xu + ((size_t)b * L_SEQ + src) * XPW2 + xb + dg * 16 + qq);
        *(u16x4*)&rawxu[rr][qq] = v;
    }
    __syncthreads();
    float dd[4] = {b2f(dvu.x), b2f(dvu.y), b2f(dvu.z), b2f(dvu.w)};
#pragma unroll
    for (int i = 0; i < 4; ++i) {
        int d = dg * 16 + q + i;
        float4 w = *(const float4*)(cw + (size_t)d * 4);
        float xc = cbp[d] + w.w * b2f(rawxu[r + 3][q + i]) + w.z * b2f(rawxu[r + 2][q + i]) +
                   w.y * b2f(rawxu[r + 1][q + i]) + w.x * b2f(rawxu[r][q + i]);
        float ds = 1.f / (1.f + __expf(-dd[i]));
        sdx[r][q + i] = make_float2(ds, xc);
    }
    __syncthreads();
    int n = tid & 15, drow = tid >> 4;
    float asum = 0.f;
#pragma unroll
    for (int j = 0; j < 16; ++j) asum += sA[n * 16 + j];
    float asum2 = asum * 1.44269504f;
    float h = 0.f, gb = 0.f, Q = 1.f;
    for (int t = 0; t < CHLEN; ++t) {
        float2 dx = sdx[t][drow];
        float bm = sb[t][n];
        float a = fast_exp2(dx.x * asum2);
        float bu = dx.x * dx.y * bm;
        h = a * h + bu;
        gb += Q * bu;
        Q *= a;
    }
    size_t cidx = ((((size_t)p * 2 + b) * NST + n) * DIN + dg * 16 + drow) * NCHUNK + c;
    Pc[cidx] = Q;
    Hf[cidx] = h;
    Gb[cidx] = gb;
}

// ---------------- scan pass2: combine chunk carries (contiguous float4 loads) ----------------
__global__ __launch_bounds__(256) void scan_pass2(const float* __restrict__ Pc,
                                                  const float* __restrict__ Hf,
                                                  const float* __restrict__ Gb,
                                                  float* __restrict__ Hinf,
                                                  float* __restrict__ Hinb) {
    int t = blockIdx.x * 256 + threadIdx.x;
    if (t >= 2 * 2 * NST * DIN) return;
    size_t base = (size_t)t * NCHUNK;
    {
        float4 P4[16], H4[16];
        const float4* Pp = (const float4*)(Pc + base);
        const float4* Hp = (const float4*)(Hf + base);
#pragma unroll
        for (int i = 0; i < 16; ++i) { P4[i] = Pp[i]; H4[i] = Hp[i]; }
        float hin = 0.f;
        float4* Op = (float4*)(Hinf + base);
#pragma unroll
        for (int i = 0; i < 16; ++i) {
            float4 o;
            o.x = hin; hin = H4[i].x + P4[i].x * hin;
            o.y = hin; hin = H4[i].y + P4[i].y * hin;
            o.z = hin; hin = H4[i].z + P4[i].z * hin;
            o.w = hin; hin = H4[i].w + P4[i].w * hin;
            Op[i] = o;
        }
    }
    {
        float4 P4[16], G4[16];
        const float4* Pp = (const float4*)(Pc + base);
        const float4* Gp = (const float4*)(Gb + base);
#pragma unroll
        for (int i = 0; i < 16; ++i) { P4[i] = Pp[i]; G4[i] = Gp[i]; }
        float gin = 0.f;
        float4* Op = (float4*)(Hinb + base);
#pragma unroll
        for (int i = 15; i >= 0; --i) {
            float4 o;
            o.w = gin; gin = G4[i].w + P4[i].w * gin;
            o.z = gin; gin = G4[i].z + P4[i].z * gin;
            o.y = gin; gin = G4[i].y + P4[i].y * gin;
            o.x = gin; gin = G4[i].x + P4[i].x * gin;
            Op[i] = o;
        }
    }
}

// ---------------- scan pass3 (fused conv): fwd+bwd re-scan, DPP reduce, merged ys ----------------
__global__ __launch_bounds__(256) void scan_pass3f(
    const __hip_bfloat16* __restrict__ xpw,
    const float* __restrict__ cw0, const float* __restrict__ cw1,
    const float* __restrict__ cb0, const float* __restrict__ cb1,
    const float* __restrict__ A0, const float* __restrict__ A1,
    const float* __restrict__ Hinf, const float* __restrict__ Hinb,
    const float* __restrict__ Dp0, const float* __restrict__ Dp1,
    __hip_bfloat16* __restrict__ y) {
    __shared__ unsigned short rawxu[67][16];
    __shared__ float2 sdx[CHLEN][16];   // (dsg, xc)
    __shared__ float2 sbc[CHLEN][16];   // (Bm, Cm)
    __shared__ float ys[CHLEN][16];     // merged fwd+bwd (ordering trick)
    __shared__ float sA[256];
    int bid = (blockIdx.x & 7) * (SCAN_GRID / 8) + (blockIdx.x >> 3);  // XCD swizzle
    int dg = bid % 12;
    int c = (bid / 12) % NCHUNK;
    int b = (bid / (12 * NCHUNK)) & 1;
    int p = bid / (12 * NCHUNK * 2);
    const float* cw = p ? cw1 : cw0;
    const float* cbp = p ? cb1 : cb0;
    const float* Am = p ? A1 : A0;
    const float* Dp = p ? Dp1 : Dp0;
    int tid = threadIdx.x;
    sA[tid] = Am[tid];
    const unsigned short* xu = (const unsigned short*)xpw;
    int xb = p * 480;
    int t0 = c * CHLEN;
    int r = tid >> 2, q = (tid & 3) * 4;
    size_t grow = (size_t)b * L_SEQ + t0 + r;
    const unsigned short* rowp = xu + grow * XPW2 + xb;
    *(u16x4*)&rawxu[r + 3][q] = *(const u16x4*)(rowp + dg * 16 + q);
    u16x4 dvu = *(const u16x4*)(rowp + 192 + dg * 16 + q);
    {
        u16x4 bvu = *(const u16x4*)(rowp + 384 + q);
        u16x4 cvu = *(const u16x4*)(rowp + 400 + q);
        sbc[r][q + 0] = make_float2(b2f(bvu.x), b2f(cvu.x));
        sbc[r][q + 1] = make_float2(b2f(bvu.y), b2f(cvu.y));
        sbc[r][q + 2] = make_float2(b2f(bvu.z), b2f(cvu.z));
        sbc[r][q + 3] = make_float2(b2f(bvu.w), b2f(cvu.w));
    }
    if (tid < 12) {
        int rr = tid >> 2, qq = (tid & 3) * 4;
        int src = t0 - 3 + rr;
        u16x4 v = {0, 0, 0, 0};
        if (src >= 0)
            v = *(const u16x4*)(xu + ((size_t)b * L_SEQ + src) * XPW2 + xb + dg * 16 + qq);
        *(u16x4*)&rawxu[rr][qq] = v;
    }
    __syncthreads();
    float dd[4] = {b2f(dvu.x), b2f(dvu.y), b2f(dvu.z), b2f(dvu.w)};
#pragma unroll
    for (int i = 0; i < 4; ++i) {
        int d = dg * 16 + q + i;
        float4 w = *(const float4*)(cw + (size_t)d * 4);
        float xc = cbp[d] + w.w * b2f(rawxu[r + 3][q + i]) + w.z * b2f(rawxu[r + 2][q + i]) +
                   w.y * b2f(rawxu[r + 1][q + i]) + w.x * b2f(rawxu[r][q + i]);
        float ds = 1.f / (1.f + __expf(-dd[i]));
        sdx[r][q + i] = make_float2(ds, xc);
    }
    __syncthreads();
    int lane = tid & 63, wave = tid >> 6;
    int n = lane & 15;
    int dloc = wave * 4 + (lane >> 4);
    int d = dg * 16 + dloc;
    float asum = 0.f;
#pragma unroll
    for (int j = 0; j < 16; ++j) asum += sA[n * 16 + j];
    float asum2 = asum * 1.44269504f;
    size_t cidx = ((((size_t)p * 2 + b) * NST + n) * DIN + d) * NCHUNK + c;
    float h = Hinf[cidx];
    float gv = Hinb[cidx];
    for (int t = 0; t < CHLEN; ++t) {
        int tb = CHLEN - 1 - t;
        float2 dxf = sdx[t][dloc];
        float2 bcf = sbc[t][n];
        float2 dxb = sdx[tb][dloc];
        float2 bcb = sbc[tb][n];
        float af = fast_exp2(dxf.x * asum2);
        float buf_ = dxf.x * dxf.y * bcf.x;
        h = af * h + buf_;
        float pf = rowsum16(bcf.y * h);
        float ab = fast_exp2(dxb.x * asum2);
        float bub_ = dxb.x * dxb.y * bcb.x;
        gv = ab * gv + bub_;
        float pb = rowsum16(bcb.y * gv);
        if (n == 0) {
            if (t < CHLEN / 2) { ys[t][dloc] = pf; ys[tb][dloc] = pb; }
            else { ys[t][dloc] += pf; ys[tb][dloc] += pb; }
        }
    }
    __syncthreads();
    {
        int tl = tid >> 2, qq = (tid & 3) * 4;
        int d2 = dg * 16 + qq;
        float4 Dv = *(const float4*)(Dp + d2);
        float vs[4];
#pragma unroll
        for (int i = 0; i < 4; ++i)
            vs[i] = ys[tl][qq + i] + ((const float*)&Dv)[i] * sdx[tl][qq + i].y;
        s16x4 pk = {(short)f2bf_bits(vs[0]), (short)f2bf_bits(vs[1]),
                    (short)f2bf_bits(vs[2]), (short)f2bf_bits(vs[3])};
        size_t row = (size_t)b * L_SEQ + t0 + tl;
        *(s16x4*)((unsigned short*)y + ((size_t)p * MROWS + row) * DIN + d2) = pk;
    }
}

extern "C" void kernel_launch(void* const* d_in, const int* in_sizes, int n_in,
                              void* d_out, int out_size, void* d_ws, size_t ws_size,
                              hipStream_t stream) {
    const float* x = (const float*)d_in[0];
    const float* norm_g = (const float*)d_in[1];
    const float* norm_b = (const float*)d_in[2];
    const float* Wp[2] = {(const float*)d_in[3], (const float*)d_in[11]};
    const float* cw[2] = {(const float*)d_in[4], (const float*)d_in[12]};
    const float* cb[2] = {(const float*)d_in[5], (const float*)d_in[13]};
    const float* Ab[2] = {(const float*)d_in[6], (const float*)d_in[14]};
    const float* Dpb[2] = {(const float*)d_in[7], (const float*)d_in[15]};
    const float* Wo[2] = {(const float*)d_in[8], (const float*)d_in[16]};
    const float* lng[2] = {(const float*)d_in[9], (const float*)d_in[17]};
    const float* lnb[2] = {(const float*)d_in[10], (const float*)d_in[18]};
    const float* Wf = (const float*)d_in[19];
    const float* bfv = (const float*)d_in[20];
    const float* W1 = (const float*)d_in[21];
    const float* b1 = (const float*)d_in[22];
    const float* W2 = (const float*)d_in[23];
    const float* b2 = (const float*)d_in[24];
    float* out = (float*)d_out;

    char* base = (char*)d_ws;
    size_t off = 0;
    auto alloc = [&](size_t bytes) { void* p = base + off; off += (bytes + 255) & ~(size_t)255; return p; };
    __hip_bfloat16* xpw = (__hip_bfloat16*)alloc((size_t)MROWS * XPW2 * 2);
    const size_t csz = (size_t)2 * 2 * NST * DIN * NCHUNK;
    float* Pc = (float*)alloc(csz * 4);
    float* Hfc = (float*)alloc(csz * 4);
    float* Gbc = (float*)alloc(csz * 4);
    float* Hinf = (float*)alloc(csz * 4);
    float* Hinb = (float*)alloc(csz * 4);
    __hip_bfloat16* xn_bf = (__hip_bfloat16*)alloc((size_t)MROWS * 96 * 2);
    __hip_bfloat16* yb_bf = (__hip_bfloat16*)alloc((size_t)2 * MROWS * DIN * 2);
    __hip_bfloat16* cat_bf = (__hip_bfloat16*)alloc((size_t)MROWS * DIN * 2);
    __hip_bfloat16* fc_bf = (__hip_bfloat16*)alloc((size_t)MROWS * 96 * 2);
    __hip_bfloat16* h1_bf = (__hip_bfloat16*)alloc((size_t)MROWS * 384 * 2);
    __hip_bfloat16* wpT = (__hip_bfloat16*)alloc((size_t)XPW2 * 96 * 2);
    __hip_bfloat16* woT[2] = {(__hip_bfloat16*)alloc(96 * 192 * 2),
                              (__hip_bfloat16*)alloc(96 * 192 * 2)};
    __hip_bfloat16* wfT = (__hip_bfloat16*)alloc(96 * 1728 * 2);
    __hip_bfloat16* w1T = (__hip_bfloat16*)alloc(384 * 96 * 2);
    __hip_bfloat16* w2T = (__hip_bfloat16*)alloc(96 * 384 * 2);
    (void)ws_size; (void)in_sizes; (void)n_in; (void)out_size;

    // 1. weight convert + transpose
    cvt_all<<<dim3(1440), dim3(256), 0, stream>>>(Wp[0], Wp[1], Wo[0], Wo[1], Wf, W1, W2,
                                                  wpT, woT[0], woT[1], wfT, w1T, w2T);
    // 2. input LayerNorm -> bf16
    ln96_kernel<__hip_bfloat16><<<dim3(2048), dim3(256), 0, stream>>>(x, norm_g, norm_b, xn_bf, MROWS);
    // 3. xp(both branches, bf16) = xn @ [Wp1|Wp2]  (M=8192, N=960, K=96)
    gemm_direct<2, 3, 2, 2, 96, 0, __hip_bfloat16><<<dim3(10, 128), dim3(256), 0, stream>>>(
        xn_bf, 96, wpT, xpw, XPW2, XPW2, nullptr, nullptr);
    // 4-6. bidirectional selective scan, both branches (conv+sigmoid fused in-block)
    scan_pass1f<<<dim3(SCAN_GRID), dim3(256), 0, stream>>>(
        xpw, cw[0], cw[1], cb[0], cb[1], Ab[0], Ab[1], Pc, Hfc, Gbc);
    scan_pass2<<<dim3(48), dim3(256), 0, stream>>>(Pc, Hfc, Gbc, Hinf, Hinb);
    scan_pass3f<<<dim3(SCAN_GRID), dim3(256), 0, stream>>>(
        xpw, cw[0], cw[1], cb[0], cb[1], Ab[0], Ab[1], Hinf, Hinb, Dpb[0], Dpb[1], yb_bf);
    // 7. f1/f2 = LN(y@Wo), cosine fuse -> cat (one launch)
    gemm_wo_ln_fuse<<<dim3(256), dim3(256), 0, stream>>>(
        yb_bf, woT[0], woT[1], lng[0], lnb[0], lng[1], lnb[1], cat_bf);
    // 8. fc = gelu(conv3x3(cat) + bf)
    conv3x3_direct<<<dim3(256), dim3(256), 0, stream>>>(cat_bf, wfT, bfv, fc_bf);
    // 9. h1 = gelu(fc @ W1 + b1)
    gemm_direct<2, 3, 2, 2, 96, 1, __hip_bfloat16><<<dim3(4, 128), dim3(256), 0, stream>>>(
        fc_bf, 96, w1T, h1_bf, 384, 384, b1, nullptr);
    // 10. out = h1 @ W2 + b2 + res
    gemm_direct<1, 3, 2, 2, 384, 2, float><<<dim3(1, 256), dim3(256), 0, stream>>>(
        h1_bf, 384, w2T, out, 96, 96, b2, x);
}

// Round 8
// 161.862 us; speedup vs baseline: 4.0332x; 1.0925x over previous
//
#include <hip/hip_runtime.h>
#include <hip/hip_bf16.h>
#include <math.h>

#define L_SEQ 4096
#define CDIM 96
#define DIN 192
#define NST 16
#define NCHUNK 64
#define CHLEN 64
#define MROWS 8192
#define XPW2 960   // combined xp width: 2 branches x 480 (416 used + pad)
#define SCAN_GRID 3072

typedef __attribute__((ext_vector_type(8))) short bf16x8;
typedef __attribute__((ext_vector_type(4))) float f32x4;
typedef __attribute__((ext_vector_type(4))) short s16x4;
typedef __attribute__((ext_vector_type(4))) unsigned short u16x4;

__device__ __forceinline__ float gelu_exact(float x) {
    return 0.5f * x * (1.0f + erff(x * 0.70710678118654752f));
}

__device__ __forceinline__ float fast_exp2(float x) {
#if __has_builtin(__builtin_amdgcn_exp2f)
    return __builtin_amdgcn_exp2f(x);
#else
    return exp2f(x);
#endif
}

__device__ __forceinline__ float b2f(unsigned short u) {
    return __uint_as_float((unsigned int)u << 16);
}

// 16-lane DPP row reduction (row_ror folds into v_add_f32_dpp)
__device__ __forceinline__ float rowsum16(float s) {
    s += __int_as_float(__builtin_amdgcn_update_dpp(0, __float_as_int(s), 0x128, 0xF, 0xF, true));
    s += __int_as_float(__builtin_amdgcn_update_dpp(0, __float_as_int(s), 0x124, 0xF, 0xF, true));
    s += __int_as_float(__builtin_amdgcn_update_dpp(0, __float_as_int(s), 0x122, 0xF, 0xF, true));
    s += __int_as_float(__builtin_amdgcn_update_dpp(0, __float_as_int(s), 0x121, 0xF, 0xF, true));
    return s;
}

__device__ __forceinline__ unsigned short f2bf_bits(float f) {
    __hip_bfloat16 h = __float2bfloat16(f);
    return *reinterpret_cast<unsigned short*>(&h);
}

// ---------------- prep: weight convert/transpose + input LayerNorm (one launch) ----------------
#define CVT_BLOCKS 1440
__global__ __launch_bounds__(256) void prep_kernel(
    const float* __restrict__ Wp0, const float* __restrict__ Wp1,
    const float* __restrict__ Wo0, const float* __restrict__ Wo1,
    const float* __restrict__ Wf, const float* __restrict__ W1, const float* __restrict__ W2,
    __hip_bfloat16* __restrict__ wpT, __hip_bfloat16* __restrict__ wo0T,
    __hip_bfloat16* __restrict__ wo1T, __hip_bfloat16* __restrict__ wfT,
    __hip_bfloat16* __restrict__ w1T, __hip_bfloat16* __restrict__ w2T,
    const float* __restrict__ x, const float* __restrict__ g, const float* __restrict__ b,
    __hip_bfloat16* __restrict__ xn) {
    if (blockIdx.x >= CVT_BLOCKS) {
        int wave = threadIdx.x >> 6;
        int lane = threadIdx.x & 63;
        int row = (blockIdx.x - CVT_BLOCKS) * 4 + wave;
        if (row >= MROWS) return;
        const float* p = x + (size_t)row * CDIM;
        float x0 = p[lane];
        float x1 = (lane < 32) ? p[64 + lane] : 0.f;
        float s = x0 + x1, sq = x0 * x0 + x1 * x1;
#pragma unroll
        for (int o = 32; o >= 1; o >>= 1) { s += __shfl_xor(s, o); sq += __shfl_xor(sq, o); }
        float mean = s * (1.f / 96.f);
        float var = sq * (1.f / 96.f) - mean * mean;
        float w = rsqrtf(var + 1e-5f);
        __hip_bfloat16* q = xn + (size_t)row * CDIM;
        q[lane] = __float2bfloat16((x0 - mean) * w * g[lane] + b[lane]);
        if (lane < 32) q[64 + lane] = __float2bfloat16((x1 - mean) * w * g[64 + lane] + b[64 + lane]);
        return;
    }
    int i = blockIdx.x * 256 + threadIdx.x;
    const int S_WPALL = XPW2 * 96;
    const int S_WO = 96 * 192;
    const int S_WF = 96 * 1728;
    const int S_W1 = 384 * 96;
    const int S_W2 = 96 * 384;
    if (i < S_WPALL) {
        int j = i / 96, r = i % 96;
        int br = j / 480, cc = j % 480;
        const float* W = br ? Wp1 : Wp0;
        wpT[i] = __float2bfloat16(cc < 416 ? W[r * 576 + cc] : 0.f);
        return;
    }
    i -= S_WPALL;
    if (i < S_WO) { int c = i / 192, r = i % 192; wo0T[i] = __float2bfloat16(Wo0[r * 96 + c]); return; }
    i -= S_WO;
    if (i < S_WO) { int c = i / 192, r = i % 192; wo1T[i] = __float2bfloat16(Wo1[r * 96 + c]); return; }
    i -= S_WO;
    if (i < S_WF) { int c = i / 1728, k = i % 1728; wfT[i] = __float2bfloat16(Wf[k * 96 + c]); return; }
    i -= S_WF;
    if (i < S_W1) { int c = i / 96, r = i % 96; w1T[i] = __float2bfloat16(W1[r * 384 + c]); return; }
    i -= S_W1;
    if (i < S_W2) { int c = i / 384, r = i % 384; w2T[i] = __float2bfloat16(W2[r * 96 + c]); return; }
}

// ---------------- LDS-free direct-fragment MFMA GEMM (optional 2-way K-split) ----------------
template <int MI, int NI, int WR, int WC, int K, int KS, int EPI, typename CT>
__global__ __launch_bounds__(WR * WC * KS * 64) void gemm_direct(
    const __hip_bfloat16* __restrict__ A, int lda,
    const __hip_bfloat16* __restrict__ BT,
    CT* __restrict__ C, int ldc, int N,
    const float* __restrict__ bias, const float* __restrict__ res) {
    __shared__ float part[KS > 1 ? (WR * MI * 16) * (WC * NI * 16) : 1];
    int tid = threadIdx.x;
    int lane = tid & 63, wid = tid >> 6;
    int wk = wid / (WR * WC);
    int wrem = wid % (WR * WC);
    int wm = wrem % WR, wn = wrem / WR;
    int m0 = blockIdx.y * (WR * MI * 16) + wm * MI * 16;
    int n0 = blockIdx.x * (WC * NI * 16) + wn * NI * 16;
    int lr = lane & 15, kh = (lane >> 4) * 8;
    constexpr int KC = K / KS;
    f32x4 acc[MI][NI] = {};
    const __hip_bfloat16* Ap = A + (size_t)(m0 + lr) * lda + kh + wk * KC;
    const __hip_bfloat16* Bp = BT + (size_t)(n0 + lr) * K + kh + wk * KC;
#pragma unroll
    for (int k0 = 0; k0 < KC; k0 += 32) {
        bf16x8 af[MI], bf[NI];
#pragma unroll
        for (int i = 0; i < MI; ++i)
            af[i] = *reinterpret_cast<const bf16x8*>(Ap + (size_t)i * 16 * lda + k0);
#pragma unroll
        for (int j = 0; j < NI; ++j)
            bf[j] = *reinterpret_cast<const bf16x8*>(Bp + (size_t)j * 16 * K + k0);
#pragma unroll
        for (int i = 0; i < MI; ++i)
#pragma unroll
            for (int j = 0; j < NI; ++j)
                acc[i][j] = __builtin_amdgcn_mfma_f32_16x16x32_bf16(af[i], bf[j], acc[i][j], 0, 0, 0);
    }
    int cr = (lane >> 4) << 2;
    if (KS > 1) {
        constexpr int BN = WC * NI * 16;
        if (wk == 1) {
#pragma unroll
            for (int i = 0; i < MI; ++i)
#pragma unroll
                for (int j = 0; j < NI; ++j)
#pragma unroll
                    for (int q = 0; q < 4; ++q)
                        part[(wm * MI * 16 + i * 16 + cr + q) * BN + wn * NI * 16 + j * 16 + lr] =
                            acc[i][j][q];
        }
        __syncthreads();
        if (wk != 0) return;
#pragma unroll
        for (int i = 0; i < MI; ++i)
#pragma unroll
            for (int j = 0; j < NI; ++j)
#pragma unroll
                for (int q = 0; q < 4; ++q)
                    acc[i][j][q] +=
                        part[(wm * MI * 16 + i * 16 + cr + q) * BN + wn * NI * 16 + j * 16 + lr];
    }
#pragma unroll
    for (int i = 0; i < MI; ++i) {
        int row = m0 + i * 16 + cr;
#pragma unroll
        for (int j = 0; j < NI; ++j) {
            int col = n0 + j * 16 + lr;
            if (col < N) {
#pragma unroll
                for (int q = 0; q < 4; ++q) {
                    float v = acc[i][j][q];
                    if (EPI == 1) v = gelu_exact(v + bias[col]);
                    else if (EPI == 2) v = v + bias[col] + res[(size_t)(row + q) * ldc + col];
                    C[(size_t)(row + q) * ldc + col] = (CT)v;
                }
            }
        }
    }
}

// ---------------- Wo GEMM both branches + LN + cosine fuse -> cat (bf16) ----------------
__global__ __launch_bounds__(256) void gemm_wo_ln_fuse(
    const __hip_bfloat16* __restrict__ A,      // yb [2*8192][192]
    const __hip_bfloat16* __restrict__ BT0, const __hip_bfloat16* __restrict__ BT1,
    const float* __restrict__ g0, const float* __restrict__ b0,
    const float* __restrict__ g1, const float* __restrict__ b1,
    __hip_bfloat16* __restrict__ cat) {        // [8192][192]
    int tid = threadIdx.x;
    int lane = tid & 63, wid = tid >> 6;
    int wm = wid & 1, wn = wid >> 1;
    int m0 = blockIdx.x * 32 + wm * 16;
    int n0 = wn * 48;
    int lr = lane & 15, kh = (lane >> 4) * 8;
    f32x4 acc0[3] = {}, acc1[3] = {};
    const __hip_bfloat16* A0 = A + (size_t)(m0 + lr) * 192 + kh;
    const __hip_bfloat16* A1 = A + (size_t)(MROWS + m0 + lr) * 192 + kh;
    const __hip_bfloat16* Bp0 = BT0 + (size_t)(n0 + lr) * 192 + kh;
    const __hip_bfloat16* Bp1 = BT1 + (size_t)(n0 + lr) * 192 + kh;
#pragma unroll
    for (int k0 = 0; k0 < 192; k0 += 32) {
        bf16x8 af0 = *reinterpret_cast<const bf16x8*>(A0 + k0);
        bf16x8 af1 = *reinterpret_cast<const bf16x8*>(A1 + k0);
#pragma unroll
        for (int j = 0; j < 3; ++j) {
            bf16x8 b0v = *reinterpret_cast<const bf16x8*>(Bp0 + (size_t)j * 16 * 192 + k0);
            bf16x8 b1v = *reinterpret_cast<const bf16x8*>(Bp1 + (size_t)j * 16 * 192 + k0);
            acc0[j] = __builtin_amdgcn_mfma_f32_16x16x32_bf16(af0, b0v, acc0[j], 0, 0, 0);
            acc1[j] = __builtin_amdgcn_mfma_f32_16x16x32_bf16(af1, b1v, acc1[j], 0, 0, 0);
        }
    }
    __shared__ float ct0[32][100], ct1[32][100];
    int cr = (lane >> 4) << 2;
#pragma unroll
    for (int j = 0; j < 3; ++j)
#pragma unroll
        for (int q = 0; q < 4; ++q) {
            ct0[wm * 16 + cr + q][n0 + j * 16 + lr] = acc0[j][q];
            ct1[wm * 16 + cr + q][n0 + j * 16 + lr] = acc1[j][q];
        }
    __syncthreads();
#pragma unroll
    for (int rr = 0; rr < 8; ++rr) {
        int row = wid * 8 + rr;
        float a0 = ct0[row][lane];
        float a1 = (lane < 32) ? ct0[row][64 + lane] : 0.f;
        float c0 = ct1[row][lane];
        float c1 = (lane < 32) ? ct1[row][64 + lane] : 0.f;
        float s0 = a0 + a1, q0 = a0 * a0 + a1 * a1;
        float s1 = c0 + c1, q1 = c0 * c0 + c1 * c1;
#pragma unroll
        for (int o = 32; o >= 1; o >>= 1) {
            s0 += __shfl_xor(s0, o); q0 += __shfl_xor(q0, o);
            s1 += __shfl_xor(s1, o); q1 += __shfl_xor(q1, o);
        }
        float mu0 = s0 * (1.f / 96.f), w0 = rsqrtf(q0 * (1.f / 96.f) - mu0 * mu0 + 1e-5f);
        float mu1 = s1 * (1.f / 96.f), w1 = rsqrtf(q1 * (1.f / 96.f) - mu1 * mu1 + 1e-5f);
        float f1a = (a0 - mu0) * w0 * g0[lane] + b0[lane];
        float f2a = (c0 - mu1) * w1 * g1[lane] + b1[lane];
        float f1b = 0.f, f2b = 0.f;
        if (lane < 32) {
            f1b = (a1 - mu0) * w0 * g0[64 + lane] + b0[64 + lane];
            f2b = (c1 - mu1) * w1 * g1[64 + lane] + b1[64 + lane];
        }
        float s11 = f1a * f1a + f1b * f1b;
        float s22 = f2a * f2a + f2b * f2b;
        float s12 = f1a * f2a + f1b * f2b;
#pragma unroll
        for (int o = 32; o >= 1; o >>= 1) {
            s11 += __shfl_xor(s11, o);
            s22 += __shfl_xor(s22, o);
            s12 += __shfl_xor(s12, o);
        }
        float nr1 = fmaxf(sqrtf(s11), 1e-12f);
        float nr2 = fmaxf(sqrtf(s22), 1e-12f);
        float sim = s12 / (nr1 * nr2);
        size_t grow = (size_t)blockIdx.x * 32 + row;
        __hip_bfloat16* q = cat + grow * 192;
        q[lane] = __float2bfloat16(f1a);
        q[96 + lane] = __float2bfloat16(sim * f1a + (1.f - sim) * f2a);
        if (lane < 32) {
            q[64 + lane] = __float2bfloat16(f1b);
            q[96 + 64 + lane] = __float2bfloat16(sim * f1b + (1.f - sim) * f2b);
        }
    }
}

// ---------------- 3x3 SAME conv, K-split implicit MFMA GEMM (8 waves) ----------------
__global__ __launch_bounds__(512) void conv3x3_direct(const __hip_bfloat16* __restrict__ cat,
                                                      const __hip_bfloat16* __restrict__ WfT,
                                                      const float* __restrict__ bfv,
                                                      __hip_bfloat16* __restrict__ out) {
    __shared__ float part[32][96];
    int tid = threadIdx.x;
    int lane = tid & 63, wid = tid >> 6;
    int wm = wid & 1, wn = (wid >> 1) & 1, wk = wid >> 2;
    int m0 = blockIdx.x * 32 + wm * 16;
    int n0 = wn * 48;
    int lr = lane & 15, kh = (lane >> 4) * 8;
    int m = m0 + lr;
    int bb = m >> 12, l = m & 4095, yy = l >> 6, xx = l & 63;
    f32x4 acc[3] = {};
    const __hip_bfloat16* Bp = WfT + (size_t)(n0 + lr) * 1728 + kh;
#pragma unroll
    for (int tap = 0; tap < 9; ++tap) {
        if ((tap & 1) != wk) continue;   // wave-uniform K split (5 even / 4 odd taps)
        int ky = tap / 3, kx = tap % 3;
        int iy = yy + ky - 1, ix = xx + kx - 1;
        bool ok = ((unsigned)iy < 64u) && ((unsigned)ix < 64u);
        const __hip_bfloat16* Ap = cat + ((size_t)bb * 4096 + (size_t)(iy * 64 + ix)) * 192 + kh;
        int kbase = tap * 192;
#pragma unroll
        for (int kc = 0; kc < 192; kc += 32) {
            bf16x8 af = {};
            if (ok) af = *reinterpret_cast<const bf16x8*>(Ap + kc);
#pragma unroll
            for (int j = 0; j < 3; ++j) {
                bf16x8 bf = *reinterpret_cast<const bf16x8*>(Bp + (size_t)j * 16 * 1728 + kbase + kc);
                acc[j] = __builtin_amdgcn_mfma_f32_16x16x32_bf16(af, bf, acc[j], 0, 0, 0);
            }
        }
    }
    int cr = (lane >> 4) << 2;
    if (wk == 1) {
#pragma unroll
        for (int j = 0; j < 3; ++j)
#pragma unroll
            for (int q = 0; q < 4; ++q)
                part[wm * 16 + cr + q][n0 + j * 16 + lr] = acc[j][q];
    }
    __syncthreads();
    if (wk != 0) return;
    int crow = m0 + cr;
#pragma unroll
    for (int j = 0; j < 3; ++j) {
        int ccol = n0 + j * 16 + lr;
#pragma unroll
        for (int q = 0; q < 4; ++q) {
            float v = acc[j][q] + part[wm * 16 + cr + q][ccol];
            v = gelu_exact(v + bfv[ccol]);
            out[(size_t)(crow + q) * 96 + ccol] = __float2bfloat16(v);
        }
    }
}

// ---------------- scan pass1 (fused conv+sigmoid), sdx=(ds, ds*xc) ----------------
__global__ __launch_bounds__(256) void scan_pass1f(
    const __hip_bfloat16* __restrict__ xpw,
    const float* __restrict__ cw0, const float* __restrict__ cw1,
    const float* __restrict__ cb0, const float* __restrict__ cb1,
    const float* __restrict__ A0, const float* __restrict__ A1,
    float* __restrict__ Pc, float* __restrict__ Hf, float* __restrict__ Gb) {
    __shared__ unsigned short rawxu[67][16];
    __shared__ float2 sdx[CHLEN][16];
    __shared__ float sb[CHLEN][16];
    __shared__ float asumv[16];
    int bid = (blockIdx.x & 7) * (SCAN_GRID / 8) + (blockIdx.x >> 3);  // XCD swizzle
    int dg = bid % 12;
    int c = (bid / 12) % NCHUNK;
    int b = (bid / (12 * NCHUNK)) & 1;
    int p = bid / (12 * NCHUNK * 2);
    const float* cw = p ? cw1 : cw0;
    const float* cbp = p ? cb1 : cb0;
    const float* Am = p ? A1 : A0;
    int tid = threadIdx.x;
    if (tid < 16) {
        const float4* Ap4 = (const float4*)(Am + tid * 16);
        float4 a0 = Ap4[0], a1 = Ap4[1], a2 = Ap4[2], a3 = Ap4[3];
        float s = (a0.x + a0.y + a0.z + a0.w) + (a1.x + a1.y + a1.z + a1.w) +
                  (a2.x + a2.y + a2.z + a2.w) + (a3.x + a3.y + a3.z + a3.w);
        asumv[tid] = s * 1.44269504f;
    }
    const unsigned short* xu = (const unsigned short*)xpw;
    int xb = p * 480;
    int t0 = c * CHLEN;
    int r = tid >> 2, q = (tid & 3) * 4;
    size_t grow = (size_t)b * L_SEQ + t0 + r;
    const unsigned short* rowp = xu + grow * XPW2 + xb;
    *(u16x4*)&rawxu[r + 3][q] = *(const u16x4*)(rowp + dg * 16 + q);
    u16x4 dvu = *(const u16x4*)(rowp + 192 + dg * 16 + q);
    u16x4 bvu = *(const u16x4*)(rowp + 384 + q);
    float4 bf4 = {b2f(bvu.x), b2f(bvu.y), b2f(bvu.z), b2f(bvu.w)};
    *(float4*)&sb[r][q] = bf4;
    if (tid < 12) {
        int rr = tid >> 2, qq = (tid & 3) * 4;
        int src = t0 - 3 + rr;
        u16x4 v = {0, 0, 0, 0};
        if (src >= 0)
            v = *(const u16x4*)(xu + ((size_t)b * L_SEQ + src) * XPW2 + xb + dg * 16 + qq);
        *(u16x4*)&rawxu[rr][qq] = v;
    }
    __syncthreads();
    float dd[4] = {b2f(dvu.x), b2f(dvu.y), b2f(dvu.z), b2f(dvu.w)};
#pragma unroll
    for (int i = 0; i < 4; ++i) {
        int d = dg * 16 + q + i;
        float4 w = *(const float4*)(cw + (size_t)d * 4);
        float xc = cbp[d] + w.w * b2f(rawxu[r + 3][q + i]) + w.z * b2f(rawxu[r + 2][q + i]) +
                   w.y * b2f(rawxu[r + 1][q + i]) + w.x * b2f(rawxu[r][q + i]);
        float ds = 1.f / (1.f + __expf(-dd[i]));
        sdx[r][q + i] = make_float2(ds, ds * xc);
    }
    __syncthreads();
    int n = tid & 15, drow = tid >> 4;
    float asum2 = asumv[n];
    float h = 0.f, gb = 0.f, Q = 1.f;
#pragma unroll 4
    for (int t = 0; t < CHLEN; ++t) {
        float2 dx = sdx[t][drow];
        float bm = sb[t][n];
        float a = fast_exp2(dx.x * asum2);
        float bu = dx.y * bm;
        h = a * h + bu;
        gb += Q * bu;
        Q *= a;
    }
    size_t cidx = ((((size_t)p * 2 + b) * NST + n) * DIN + dg * 16 + drow) * NCHUNK + c;
    Pc[cidx] = Q;
    Hf[cidx] = h;
    Gb[cidx] = gb;
}

// ---------------- scan pass2: combine chunk carries (contiguous float4 loads) ----------------
__global__ __launch_bounds__(256) void scan_pass2(const float* __restrict__ Pc,
                                                  const float* __restrict__ Hf,
                                                  const float* __restrict__ Gb,
                                                  float* __restrict__ Hinf,
                                                  float* __restrict__ Hinb) {
    int t = blockIdx.x * 256 + threadIdx.x;
    if (t >= 2 * 2 * NST * DIN) return;
    size_t base = (size_t)t * NCHUNK;
    {
        float4 P4[16], H4[16];
        const float4* Pp = (const float4*)(Pc + base);
        const float4* Hp = (const float4*)(Hf + base);
#pragma unroll
        for (int i = 0; i < 16; ++i) { P4[i] = Pp[i]; H4[i] = Hp[i]; }
        float hin = 0.f;
        float4* Op = (float4*)(Hinf + base);
#pragma unroll
        for (int i = 0; i < 16; ++i) {
            float4 o;
            o.x = hin; hin = H4[i].x + P4[i].x * hin;
            o.y = hin; hin = H4[i].y + P4[i].y * hin;
            o.z = hin; hin = H4[i].z + P4[i].z * hin;
            o.w = hin; hin = H4[i].w + P4[i].w * hin;
            Op[i] = o;
        }
    }
    {
        float4 P4[16], G4[16];
        const float4* Pp = (const float4*)(Pc + base);
        const float4* Gp = (const float4*)(Gb + base);
#pragma unroll
        for (int i = 0; i < 16; ++i) { P4[i] = Pp[i]; G4[i] = Gp[i]; }
        float gin = 0.f;
        float4* Op = (float4*)(Hinb + base);
#pragma unroll
        for (int i = 15; i >= 0; --i) {
            float4 o;
            o.w = gin; gin = G4[i].w + P4[i].w * gin;
            o.z = gin; gin = G4[i].z + P4[i].z * gin;
            o.y = gin; gin = G4[i].y + P4[i].y * gin;
            o.x = gin; gin = G4[i].x + P4[i].x * gin;
            Op[i] = o;
        }
    }
}

// ---------------- scan pass3 (fused conv): fwd+bwd re-scan, unrolled, write-only ys ----------------
__global__ __launch_bounds__(256) void scan_pass3f(
    const __hip_bfloat16* __restrict__ xpw,
    const float* __restrict__ cw0, const float* __restrict__ cw1,
    const float* __restrict__ cb0, const float* __restrict__ cb1,
    const float* __restrict__ A0, const float* __restrict__ A1,
    const float* __restrict__ Hinf, const float* __restrict__ Hinb,
    const float* __restrict__ Dp0, const float* __restrict__ Dp1,
    __hip_bfloat16* __restrict__ y) {
    __shared__ unsigned short rawxu[67][16];
    __shared__ float2 sdx[CHLEN][16];        // (ds, xc)
    __shared__ float2 sbc[CHLEN][16];        // (Bm, Cm)
    __shared__ unsigned short sxcu[CHLEN][16];  // xc as bf16 (epilogue Dp*xc)
    __shared__ float ysf[CHLEN][16], ysb[CHLEN][16];
    __shared__ float asumv[16];
    int bid = (blockIdx.x & 7) * (SCAN_GRID / 8) + (blockIdx.x >> 3);  // XCD swizzle
    int dg = bid % 12;
    int c = (bid / 12) % NCHUNK;
    int b = (bid / (12 * NCHUNK)) & 1;
    int p = bid / (12 * NCHUNK * 2);
    const float* cw = p ? cw1 : cw0;
    const float* cbp = p ? cb1 : cb0;
    const float* Am = p ? A1 : A0;
    const float* Dp = p ? Dp1 : Dp0;
    int tid = threadIdx.x;
    if (tid < 16) {
        const float4* Ap4 = (const float4*)(Am + tid * 16);
        float4 a0 = Ap4[0], a1 = Ap4[1], a2 = Ap4[2], a3 = Ap4[3];
        float s = (a0.x + a0.y + a0.z + a0.w) + (a1.x + a1.y + a1.z + a1.w) +
                  (a2.x + a2.y + a2.z + a2.w) + (a3.x + a3.y + a3.z + a3.w);
        asumv[tid] = s * 1.44269504f;
    }
    const unsigned short* xu = (const unsigned short*)xpw;
    int xb = p * 480;
    int t0 = c * CHLEN;
    int r = tid >> 2, q = (tid & 3) * 4;
    size_t grow = (size_t)b * L_SEQ + t0 + r;
    const unsigned short* rowp = xu + grow * XPW2 + xb;
    *(u16x4*)&rawxu[r + 3][q] = *(const u16x4*)(rowp + dg * 16 + q);
    u16x4 dvu = *(const u16x4*)(rowp + 192 + dg * 16 + q);
    {
        u16x4 bvu = *(const u16x4*)(rowp + 384 + q);
        u16x4 cvu = *(const u16x4*)(rowp + 400 + q);
        sbc[r][q + 0] = make_float2(b2f(bvu.x), b2f(cvu.x));
        sbc[r][q + 1] = make_float2(b2f(bvu.y), b2f(cvu.y));
        sbc[r][q + 2] = make_float2(b2f(bvu.z), b2f(cvu.z));
        sbc[r][q + 3] = make_float2(b2f(bvu.w), b2f(cvu.w));
    }
    if (tid < 12) {
        int rr = tid >> 2, qq = (tid & 3) * 4;
        int src = t0 - 3 + rr;
        u16x4 v = {0, 0, 0, 0};
        if (src >= 0)
            v = *(const u16x4*)(xu + ((size_t)b * L_SEQ + src) * XPW2 + xb + dg * 16 + qq);
        *(u16x4*)&rawxu[rr][qq] = v;
    }
    __syncthreads();
    float dd[4] = {b2f(dvu.x), b2f(dvu.y), b2f(dvu.z), b2f(dvu.w)};
#pragma unroll
    for (int i = 0; i < 4; ++i) {
        int d = dg * 16 + q + i;
        float4 w = *(const float4*)(cw + (size_t)d * 4);
        float xc = cbp[d] + w.w * b2f(rawxu[r + 3][q + i]) + w.z * b2f(rawxu[r + 2][q + i]) +
                   w.y * b2f(rawxu[r + 1][q + i]) + w.x * b2f(rawxu[r][q + i]);
        float ds = 1.f / (1.f + __expf(-dd[i]));
        sdx[r][q + i] = make_float2(ds, xc);
        sxcu[r][q + i] = f2bf_bits(xc);
    }
    __syncthreads();
    int lane = tid & 63, wave = tid >> 6;
    int n = lane & 15;
    int dloc = wave * 4 + (lane >> 4);
    int d = dg * 16 + dloc;
    float asum2 = asumv[n];
    size_t cidx = ((((size_t)p * 2 + b) * NST + n) * DIN + d) * NCHUNK + c;
    float h = Hinf[cidx];
    float gv = Hinb[cidx];
#pragma unroll 4
    for (int t = 0; t < CHLEN; ++t) {
        int tb = CHLEN - 1 - t;
        float2 dxf = sdx[t][dloc];
        float2 bcf = sbc[t][n];
        float2 dxb = sdx[tb][dloc];
        float2 bcb = sbc[tb][n];
        float af = fast_exp2(dxf.x * asum2);
        float buf_ = dxf.x * dxf.y * bcf.x;
        h = af * h + buf_;
        float pf = rowsum16(bcf.y * h);
        float ab = fast_exp2(dxb.x * asum2);
        float bub_ = dxb.x * dxb.y * bcb.x;
        gv = ab * gv + bub_;
        float pb = rowsum16(bcb.y * gv);
        if (n == 0) {
            ysf[t][dloc] = pf;
            ysb[tb][dloc] = pb;
        }
    }
    __syncthreads();
    {
        int tl = tid >> 2, qq = (tid & 3) * 4;
        int d2 = dg * 16 + qq;
        float4 Dv = *(const float4*)(Dp + d2);
        float vs[4];
#pragma unroll
        for (int i = 0; i < 4; ++i)
            vs[i] = ysf[tl][qq + i] + ysb[tl][qq + i] +
                    ((const float*)&Dv)[i] * b2f(sxcu[tl][qq + i]);
        s16x4 pk = {(short)f2bf_bits(vs[0]), (short)f2bf_bits(vs[1]),
                    (short)f2bf_bits(vs[2]), (short)f2bf_bits(vs[3])};
        size_t row = (size_t)b * L_SEQ + t0 + tl;
        *(s16x4*)((unsigned short*)y + ((size_t)p * MROWS + row) * DIN + d2) = pk;
    }
}

extern "C" void kernel_launch(void* const* d_in, const int* in_sizes, int n_in,
                              void* d_out, int out_size, void* d_ws, size_t ws_size,
                              hipStream_t stream) {
    const float* x = (const float*)d_in[0];
    const float* norm_g = (const float*)d_in[1];
    const float* norm_b = (const float*)d_in[2];
    const float* Wp[2] = {(const float*)d_in[3], (const float*)d_in[11]};
    const float* cw[2] = {(const float*)d_in[4], (const float*)d_in[12]};
    const float* cb[2] = {(const float*)d_in[5], (const float*)d_in[13]};
    const float* Ab[2] = {(const float*)d_in[6], (const float*)d_in[14]};
    const float* Dpb[2] = {(const float*)d_in[7], (const float*)d_in[15]};
    const float* Wo[2] = {(const float*)d_in[8], (const float*)d_in[16]};
    const float* lng[2] = {(const float*)d_in[9], (const float*)d_in[17]};
    const float* lnb[2] = {(const float*)d_in[10], (const float*)d_in[18]};
    const float* Wf = (const float*)d_in[19];
    const float* bfv = (const float*)d_in[20];
    const float* W1 = (const float*)d_in[21];
    const float* b1 = (const float*)d_in[22];
    const float* W2 = (const float*)d_in[23];
    const float* b2 = (const float*)d_in[24];
    float* out = (float*)d_out;

    char* base = (char*)d_ws;
    size_t off = 0;
    auto alloc = [&](size_t bytes) { void* p = base + off; off += (bytes + 255) & ~(size_t)255; return p; };
    __hip_bfloat16* xpw = (__hip_bfloat16*)alloc((size_t)MROWS * XPW2 * 2);
    const size_t csz = (size_t)2 * 2 * NST * DIN * NCHUNK;
    float* Pc = (float*)alloc(csz * 4);
    float* Hfc = (float*)alloc(csz * 4);
    float* Gbc = (float*)alloc(csz * 4);
    float* Hinf = (float*)alloc(csz * 4);
    float* Hinb = (float*)alloc(csz * 4);
    __hip_bfloat16* xn_bf = (__hip_bfloat16*)alloc((size_t)MROWS * 96 * 2);
    __hip_bfloat16* yb_bf = (__hip_bfloat16*)alloc((size_t)2 * MROWS * DIN * 2);
    __hip_bfloat16* cat_bf = (__hip_bfloat16*)alloc((size_t)MROWS * DIN * 2);
    __hip_bfloat16* fc_bf = (__hip_bfloat16*)alloc((size_t)MROWS * 96 * 2);
    __hip_bfloat16* h1_bf = (__hip_bfloat16*)alloc((size_t)MROWS * 384 * 2);
    __hip_bfloat16* wpT = (__hip_bfloat16*)alloc((size_t)XPW2 * 96 * 2);
    __hip_bfloat16* woT[2] = {(__hip_bfloat16*)alloc(96 * 192 * 2),
                              (__hip_bfloat16*)alloc(96 * 192 * 2)};
    __hip_bfloat16* wfT = (__hip_bfloat16*)alloc(96 * 1728 * 2);
    __hip_bfloat16* w1T = (__hip_bfloat16*)alloc(384 * 96 * 2);
    __hip_bfloat16* w2T = (__hip_bfloat16*)alloc(96 * 384 * 2);
    (void)ws_size; (void)in_sizes; (void)n_in; (void)out_size;

    // 1. weights convert/transpose + input LN (one launch)
    prep_kernel<<<dim3(CVT_BLOCKS + 2048), dim3(256), 0, stream>>>(
        Wp[0], Wp[1], Wo[0], Wo[1], Wf, W1, W2,
        wpT, woT[0], woT[1], wfT, w1T, w2T, x, norm_g, norm_b, xn_bf);
    // 2. xp(both branches, bf16) = xn @ [Wp1|Wp2]
    gemm_direct<2, 3, 2, 2, 96, 1, 0, __hip_bfloat16><<<dim3(10, 128), dim3(256), 0, stream>>>(
        xn_bf, 96, wpT, xpw, XPW2, XPW2, nullptr, nullptr);
    // 3-5. bidirectional selective scan, both branches
    scan_pass1f<<<dim3(SCAN_GRID), dim3(256), 0, stream>>>(
        xpw, cw[0], cw[1], cb[0], cb[1], Ab[0], Ab[1], Pc, Hfc, Gbc);
    scan_pass2<<<dim3(48), dim3(256), 0, stream>>>(Pc, Hfc, Gbc, Hinf, Hinb);
    scan_pass3f<<<dim3(SCAN_GRID), dim3(256), 0, stream>>>(
        xpw, cw[0], cw[1], cb[0], cb[1], Ab[0], Ab[1], Hinf, Hinb, Dpb[0], Dpb[1], yb_bf);
    // 6. f1/f2 = LN(y@Wo), cosine fuse -> cat
    gemm_wo_ln_fuse<<<dim3(256), dim3(256), 0, stream>>>(
        yb_bf, woT[0], woT[1], lng[0], lnb[0], lng[1], lnb[1], cat_bf);
    // 7. fc = gelu(conv3x3(cat) + bf)  (K-split, 8 waves)
    conv3x3_direct<<<dim3(256), dim3(512), 0, stream>>>(cat_bf, wfT, bfv, fc_bf);
    // 8. h1 = gelu(fc @ W1 + b1)
    gemm_direct<2, 3, 2, 2, 96, 1, 1, __hip_bfloat16><<<dim3(4, 128), dim3(256), 0, stream>>>(
        fc_bf, 96, w1T, h1_bf, 384, 384, b1, nullptr);
    // 9. out = h1 @ W2 + b2 + res  (K-split, 8 waves)
    gemm_direct<1, 3, 2, 2, 384, 2, 2, float><<<dim3(1, 256), dim3(512), 0, stream>>>(
        h1_bf, 384, w2T, out, 96, 96, b2, x);
}